// Round 1
// baseline (6142.491 us; speedup 1.0000x reference)
//
#include <hip/hip_runtime.h>

constexpr int L = 2048;   // sequence length
constexpr int V = 2048;   // vocab / channel width
constexpr int NB = 4;     // batch

// ---------------- precompute kernels ----------------

// ksum[t] = sum_j W[j*V + t]  (column sums)
__global__ __launch_bounds__(256) void colsum_kernel(const float* __restrict__ W,
                                                     float* __restrict__ out) {
    int t = blockIdx.x * blockDim.x + threadIdx.x;
    if (t >= V) return;
    float s = 0.f;
    for (int j = 0; j < V; ++j) s += W[j * V + t];
    out[t] = s;
}

// At = A^T, A is [V,V] row-major
__global__ void transpose_kernel(const float* __restrict__ A, float* __restrict__ At) {
    __shared__ float tile[32][33];
    int x = blockIdx.x * 32 + threadIdx.x;
    int y0 = blockIdx.y * 32;
    for (int r = threadIdx.y; r < 32; r += 8)
        tile[r][threadIdx.x] = A[(y0 + r) * V + x];
    __syncthreads();
    int xo = blockIdx.y * 32 + threadIdx.x;
    int yo0 = blockIdx.x * 32;
    for (int r = threadIdx.y; r < 32; r += 8)
        At[(yo0 + r) * V + xo] = tile[threadIdx.x][r];
}

// C[i,j] = sum_k A[k,i] * B[k,j]   (A^T B), all [V,V]
__global__ __launch_bounds__(256) void gemm_tn_kernel(const float* __restrict__ A,
                                                      const float* __restrict__ B,
                                                      float* __restrict__ C) {
    __shared__ float As[16][64];
    __shared__ float Bs[16][64];
    int tid = threadIdx.x;
    int tx = tid & 15, ty = tid >> 4;
    int i0 = blockIdx.y * 64, j0 = blockIdx.x * 64;
    float acc[4][4] = {};
    for (int k0 = 0; k0 < V; k0 += 16) {
        __syncthreads();
        #pragma unroll
        for (int t = 0; t < 4; ++t) {
            int e = tid + t * 256;
            int kk = e >> 6, c = e & 63;
            As[kk][c] = A[(k0 + kk) * V + i0 + c];
            Bs[kk][c] = B[(k0 + kk) * V + j0 + c];
        }
        __syncthreads();
        #pragma unroll
        for (int kk = 0; kk < 16; ++kk) {
            float a[4], b[4];
            #pragma unroll
            for (int ii = 0; ii < 4; ++ii) a[ii] = As[kk][ty * 4 + ii];
            #pragma unroll
            for (int jj = 0; jj < 4; ++jj) b[jj] = Bs[kk][tx * 4 + jj];
            #pragma unroll
            for (int ii = 0; ii < 4; ++ii)
                #pragma unroll
                for (int jj = 0; jj < 4; ++jj)
                    acc[ii][jj] += a[ii] * b[jj];
        }
    }
    for (int ii = 0; ii < 4; ++ii) {
        float4 v = make_float4(acc[ii][0], acc[ii][1], acc[ii][2], acc[ii][3]);
        *reinterpret_cast<float4*>(&C[(i0 + ty * 4 + ii) * V + j0 + tx * 4]) = v;
    }
}

// C[i,j] = sum_k A[i,k] * B[j,k]   (A B^T); A [Mdim,V], B [V,V], C [Mdim,V]
__global__ __launch_bounds__(256) void gemm_nt_kernel(const float* __restrict__ A,
                                                      const float* __restrict__ B,
                                                      float* __restrict__ C) {
    __shared__ float As[16][65];
    __shared__ float Bs[16][65];
    int tid = threadIdx.x;
    int tx = tid & 15, ty = tid >> 4;
    int i0 = blockIdx.y * 64, j0 = blockIdx.x * 64;
    float acc[4][4] = {};
    for (int k0 = 0; k0 < V; k0 += 16) {
        __syncthreads();
        #pragma unroll
        for (int t = 0; t < 4; ++t) {
            int e = tid + t * 256;
            int kk = e & 15, r = e >> 4;
            As[kk][r] = A[(i0 + r) * V + k0 + kk];
            Bs[kk][r] = B[(j0 + r) * V + k0 + kk];
        }
        __syncthreads();
        #pragma unroll
        for (int kk = 0; kk < 16; ++kk) {
            float a[4], b[4];
            #pragma unroll
            for (int ii = 0; ii < 4; ++ii) a[ii] = As[kk][ty * 4 + ii];
            #pragma unroll
            for (int jj = 0; jj < 4; ++jj) b[jj] = Bs[kk][tx * 4 + jj];
            #pragma unroll
            for (int ii = 0; ii < 4; ++ii)
                #pragma unroll
                for (int jj = 0; jj < 4; ++jj)
                    acc[ii][jj] += a[ii] * b[jj];
        }
    }
    for (int ii = 0; ii < 4; ++ii) {
        float4 v = make_float4(acc[ii][0], acc[ii][1], acc[ii][2], acc[ii][3]);
        *reinterpret_cast<float4*>(&C[(i0 + ty * 4 + ii) * V + j0 + tx * 4]) = v;
    }
}

// Per batch b: C[i,j] = sum_u A[u,i] * B[j,u]
// A = M [V,V] (ld V), B = l1+b*L*V [L,V] (ld V), C = T2t+b*V*L [V,L] (ld L)
__global__ __launch_bounds__(256) void gemm_tt_kernel(const float* __restrict__ A,
                                                      const float* __restrict__ Bfull,
                                                      float* __restrict__ Cfull) {
    const float* Bl = Bfull + (size_t)blockIdx.z * L * V;
    float* C = Cfull + (size_t)blockIdx.z * V * L;
    __shared__ float As[16][64];
    __shared__ float Bs[16][65];
    int tid = threadIdx.x;
    int tx = tid & 15, ty = tid >> 4;
    int i0 = blockIdx.y * 64, j0 = blockIdx.x * 64;
    float acc[4][4] = {};
    for (int u0 = 0; u0 < V; u0 += 16) {
        __syncthreads();
        #pragma unroll
        for (int t = 0; t < 4; ++t) {
            int e = tid + t * 256;
            int uu1 = e >> 6, c = e & 63;
            As[uu1][c] = A[(u0 + uu1) * V + i0 + c];
            int uu2 = e & 15, r = e >> 4;
            Bs[uu2][r] = Bl[(j0 + r) * V + u0 + uu2];
        }
        __syncthreads();
        #pragma unroll
        for (int uu = 0; uu < 16; ++uu) {
            float a[4], b[4];
            #pragma unroll
            for (int ii = 0; ii < 4; ++ii) a[ii] = As[uu][ty * 4 + ii];
            #pragma unroll
            for (int jj = 0; jj < 4; ++jj) b[jj] = Bs[uu][tx * 4 + jj];
            #pragma unroll
            for (int ii = 0; ii < 4; ++ii)
                #pragma unroll
                for (int jj = 0; jj < 4; ++jj)
                    acc[ii][jj] += a[ii] * b[jj];
        }
    }
    for (int ii = 0; ii < 4; ++ii) {
        float4 v = make_float4(acc[ii][0], acc[ii][1], acc[ii][2], acc[ii][3]);
        *reinterpret_cast<float4*>(&C[(i0 + ty * 4 + ii) * L + j0 + tx * 4]) = v;
    }
}

// ---------------- stage kernels (causal score @ V) ----------------

// l0[b,q,:] = sum_{k<=q} (G0[iq,ik] + ksum0[iq]*v0[q-k]) * Wv0T[ik,:]
__global__ __launch_bounds__(256) void stageA_kernel(const int* __restrict__ idx,
                                                     const float* __restrict__ G0,
                                                     const float* __restrict__ ksum0,
                                                     const float* __restrict__ v0,
                                                     const float* __restrict__ Wv0T,
                                                     float* __restrict__ l0) {
    int b = blockIdx.z, qt = blockIdx.y;
    int j0 = blockIdx.x * 64, q0 = qt * 64;
    int tid = threadIdx.x;
    int tx = tid & 15, ty = tid >> 4;
    __shared__ float Ss[64][65];
    __shared__ float Vs[64][64];
    __shared__ int iqs[64], iks[64];
    __shared__ float kqs[64];
    if (tid < 64) {
        int iq = idx[b * L + q0 + tid];
        iqs[tid] = iq;
        kqs[tid] = ksum0[iq];
    }
    float acc[4][4] = {};
    for (int kt = 0; kt <= qt; ++kt) {
        int k0 = kt * 64;
        __syncthreads();
        if (tid < 64) iks[tid] = idx[b * L + k0 + tid];
        __syncthreads();
        #pragma unroll
        for (int t = 0; t < 16; ++t) {
            int e = tid + t * 256;
            int qq = e >> 6, kk = e & 63;
            int q = q0 + qq, k = k0 + kk;
            float s = 0.f;
            if (k <= q) s = G0[iqs[qq] * V + iks[kk]] + kqs[qq] * v0[q - k];
            Ss[qq][kk] = s;
        }
        #pragma unroll
        for (int t = 0; t < 16; ++t) {
            int e = tid + t * 256;
            int kk = e >> 6, j = e & 63;
            Vs[kk][j] = Wv0T[iks[kk] * V + j0 + j];
        }
        __syncthreads();
        #pragma unroll
        for (int kk = 0; kk < 64; ++kk) {
            float a[4], bb[4];
            #pragma unroll
            for (int ii = 0; ii < 4; ++ii) a[ii] = Ss[ty * 4 + ii][kk];
            #pragma unroll
            for (int jj = 0; jj < 4; ++jj) bb[jj] = Vs[kk][tx * 4 + jj];
            #pragma unroll
            for (int ii = 0; ii < 4; ++ii)
                #pragma unroll
                for (int jj = 0; jj < 4; ++jj)
                    acc[ii][jj] += a[ii] * bb[jj];
        }
    }
    float* out = l0 + (size_t)b * L * V;
    for (int ii = 0; ii < 4; ++ii) {
        float4 vv = make_float4(acc[ii][0], acc[ii][1], acc[ii][2], acc[ii][3]);
        *reinterpret_cast<float4*>(&out[(q0 + ty * 4 + ii) * V + j0 + tx * 4]) = vv;
    }
}

// l1[b,q,:] = ksum1[iq] * sum_{k<=q} v1[q-k] * V1[b,k,:]
__global__ __launch_bounds__(256) void stageB_kernel(const int* __restrict__ idx,
                                                     const float* __restrict__ ksum1,
                                                     const float* __restrict__ v1,
                                                     const float* __restrict__ V1,
                                                     float* __restrict__ l1) {
    int b = blockIdx.z, qt = blockIdx.y;
    int j0 = blockIdx.x * 64, q0 = qt * 64;
    int tid = threadIdx.x;
    int tx = tid & 15, ty = tid >> 4;
    __shared__ float Ss[64][65];
    __shared__ float Vs[64][64];
    __shared__ float kqs[64];
    if (tid < 64) kqs[tid] = ksum1[idx[b * L + q0 + tid]];
    const float* Vb = V1 + (size_t)b * L * V;
    float acc[4][4] = {};
    for (int kt = 0; kt <= qt; ++kt) {
        int k0 = kt * 64;
        __syncthreads();
        #pragma unroll
        for (int t = 0; t < 16; ++t) {
            int e = tid + t * 256;
            int qq = e >> 6, kk = e & 63;
            int q = q0 + qq, k = k0 + kk;
            Ss[qq][kk] = (k <= q) ? v1[q - k] : 0.f;
        }
        #pragma unroll
        for (int t = 0; t < 16; ++t) {
            int e = tid + t * 256;
            int kk = e >> 6, j = e & 63;
            Vs[kk][j] = Vb[(k0 + kk) * V + j0 + j];
        }
        __syncthreads();
        #pragma unroll
        for (int kk = 0; kk < 64; ++kk) {
            float a[4], bb[4];
            #pragma unroll
            for (int ii = 0; ii < 4; ++ii) a[ii] = Ss[ty * 4 + ii][kk];
            #pragma unroll
            for (int jj = 0; jj < 4; ++jj) bb[jj] = Vs[kk][tx * 4 + jj];
            #pragma unroll
            for (int ii = 0; ii < 4; ++ii)
                #pragma unroll
                for (int jj = 0; jj < 4; ++jj)
                    acc[ii][jj] += a[ii] * bb[jj];
        }
    }
    float* out = l1 + (size_t)b * L * V;
    for (int ii = 0; ii < 4; ++ii) {
        float kq = kqs[ty * 4 + ii];
        float4 vv = make_float4(acc[ii][0] * kq, acc[ii][1] * kq,
                                acc[ii][2] * kq, acc[ii][3] * kq);
        *reinterpret_cast<float4*>(&out[(q0 + ty * 4 + ii) * V + j0 + tx * 4]) = vv;
    }
}

// logits[b,q,:] = sum_{k<=q} T2t[b][iq,k] * Wv2T[ik,:]
__global__ __launch_bounds__(256) void stageC_kernel(const int* __restrict__ idx,
                                                     const float* __restrict__ T2t,
                                                     const float* __restrict__ Wv2T,
                                                     float* __restrict__ outF) {
    int b = blockIdx.z, qt = blockIdx.y;
    int j0 = blockIdx.x * 64, q0 = qt * 64;
    int tid = threadIdx.x;
    int tx = tid & 15, ty = tid >> 4;
    __shared__ float Ss[64][65];
    __shared__ float Vs[64][64];
    __shared__ int iqs[64], iks[64];
    if (tid < 64) iqs[tid] = idx[b * L + q0 + tid];
    const float* Tb = T2t + (size_t)b * V * L;
    float acc[4][4] = {};
    for (int kt = 0; kt <= qt; ++kt) {
        int k0 = kt * 64;
        __syncthreads();
        if (tid < 64) iks[tid] = idx[b * L + k0 + tid];
        __syncthreads();
        #pragma unroll
        for (int t = 0; t < 16; ++t) {
            int e = tid + t * 256;
            int qq = e >> 6, kk = e & 63;
            int q = q0 + qq, k = k0 + kk;
            Ss[qq][kk] = (k <= q) ? Tb[iqs[qq] * L + k0 + kk] : 0.f;
        }
        #pragma unroll
        for (int t = 0; t < 16; ++t) {
            int e = tid + t * 256;
            int kk = e >> 6, j = e & 63;
            Vs[kk][j] = Wv2T[iks[kk] * V + j0 + j];
        }
        __syncthreads();
        #pragma unroll
        for (int kk = 0; kk < 64; ++kk) {
            float a[4], bb[4];
            #pragma unroll
            for (int ii = 0; ii < 4; ++ii) a[ii] = Ss[ty * 4 + ii][kk];
            #pragma unroll
            for (int jj = 0; jj < 4; ++jj) bb[jj] = Vs[kk][tx * 4 + jj];
            #pragma unroll
            for (int ii = 0; ii < 4; ++ii)
                #pragma unroll
                for (int jj = 0; jj < 4; ++jj)
                    acc[ii][jj] += a[ii] * bb[jj];
        }
    }
    float* out = outF + (size_t)b * L * V;
    for (int ii = 0; ii < 4; ++ii) {
        float4 vv = make_float4(acc[ii][0], acc[ii][1], acc[ii][2], acc[ii][3]);
        *reinterpret_cast<float4*>(&out[(q0 + ty * 4 + ii) * V + j0 + tx * 4]) = vv;
    }
}

// ---------------- launcher ----------------

extern "C" void kernel_launch(void* const* d_in, const int* in_sizes, int n_in,
                              void* d_out, int out_size, void* d_ws, size_t ws_size,
                              hipStream_t stream) {
    (void)in_sizes; (void)n_in; (void)out_size; (void)ws_size;
    const int*   idx = (const int*)d_in[0];
    const float* Wq0 = (const float*)d_in[1];
    const float* Wk0 = (const float*)d_in[2];
    const float* Wv0 = (const float*)d_in[3];
    const float* Wk1 = (const float*)d_in[4];
    const float* Wv1 = (const float*)d_in[5];
    const float* Wq2 = (const float*)d_in[6];
    const float* Wk2 = (const float*)d_in[7];
    const float* Wv2 = (const float*)d_in[8];
    const float* v0  = (const float*)d_in[9];
    const float* v1  = (const float*)d_in[10];
    float* out = (float*)d_out;

    float* ws = (float*)d_ws;
    const size_t BLV = (size_t)NB * L * V;
    const size_t VV  = (size_t)V * V;
    float* bufA = ws;                 // l0, then l1
    float* bufB = bufA + BLV;         // V1, then T2t
    float* Gbuf = bufB + BLV;         // G0, then M
    float* WvT  = Gbuf + VV;          // Wv0T, then Wv2T
    float* ks0  = WvT + VV;
    float* ks1  = ks0 + V;

    // precompute for layer 0
    colsum_kernel<<<dim3(V / 256), 256, 0, stream>>>(Wk0, ks0);
    colsum_kernel<<<dim3(V / 256), 256, 0, stream>>>(Wk1, ks1);
    transpose_kernel<<<dim3(V / 32, V / 32), dim3(32, 8), 0, stream>>>(Wv0, WvT);
    gemm_tn_kernel<<<dim3(V / 64, V / 64), 256, 0, stream>>>(Wq0, Wk0, Gbuf);

    // stage A: l0 -> bufA
    stageA_kernel<<<dim3(V / 64, L / 64, NB), 256, 0, stream>>>(idx, Gbuf, ks0, v0, WvT, bufA);

    // V1 = l0 @ Wv1^T -> bufB  (flatten batch: Mdim = NB*L)
    gemm_nt_kernel<<<dim3(V / 64, (NB * L) / 64), 256, 0, stream>>>(bufA, Wv1, bufB);

    // stage B: l1 -> bufA (l0 dead)
    stageB_kernel<<<dim3(V / 64, L / 64, NB), 256, 0, stream>>>(idx, ks1, v1, bufB, bufA);

    // precompute for layer 2 (reuse buffers: G0, Wv0T dead)
    gemm_tn_kernel<<<dim3(V / 64, V / 64), 256, 0, stream>>>(Wk2, Wq2, Gbuf);
    transpose_kernel<<<dim3(V / 32, V / 32), dim3(32, 8), 0, stream>>>(Wv2, WvT);

    // T2t[b] = M^T @ l1[b]^T -> bufB (V1 dead)
    gemm_tt_kernel<<<dim3(L / 64, V / 64, NB), 256, 0, stream>>>(Gbuf, bufA, bufB);

    // stage C -> d_out
    stageC_kernel<<<dim3(V / 64, L / 64, NB), 256, 0, stream>>>(idx, bufB, WvT, out);
}

// Round 2
// 1544.283 us; speedup vs baseline: 3.9776x; 3.9776x over previous
//
#include <hip/hip_runtime.h>

typedef float f32x4 __attribute__((ext_vector_type(4)));
typedef short s16x8 __attribute__((ext_vector_type(8)));

constexpr int L = 2048;
constexpr int V = 2048;
constexpr int NB = 4;
constexpr int BL = NB * L;               // 8192
constexpr size_t VV  = (size_t)V * V;    // 4194304
constexpr size_t BLV = (size_t)BL * V;   // 16777216
constexpr size_t LV  = (size_t)L * V;    // 4194304

// ---------- bf16 helpers (bit-level, RNE) ----------
__device__ __forceinline__ unsigned short f2bf(float f) {
    unsigned u = __float_as_uint(f);
    u = (u + 0x7FFFu + ((u >> 16) & 1u)) >> 16;
    return (unsigned short)u;
}
__device__ __forceinline__ float bf2f(unsigned short s) {
    return __uint_as_float(((unsigned)s) << 16);
}

// ---------- async global->LDS 16B ----------
__device__ __forceinline__ void gload16(const unsigned short* g, unsigned short* l) {
    auto gp = (const __attribute__((address_space(1))) unsigned int*)g;
    auto lp = (__attribute__((address_space(3))) unsigned int*)l;
    __builtin_amdgcn_global_load_lds(gp, lp, 16, 0, 0);
}

// stage one 128x32 bf16 tile (hi or lo array) into LDS, XOR-swizzled chunks.
// g0: array base (incl. batch offset), r0: first global row, rowStride = 2048.
__device__ __forceinline__ void stage_tile(const unsigned short* g0, int r0, int k0,
                                           unsigned short* lds, int wave, int lane) {
    #pragma unroll
    for (int i = 0; i < 2; ++i) {
        int r  = i * 64 + wave * 16 + (lane >> 2);
        int cs = (lane & 3) ^ ((r >> 1) & 3);
        const unsigned short* g = g0 + (size_t)(r0 + r) * 2048 + k0 + cs * 8;
        gload16(g, lds + (size_t)(i * 256 + wave * 64) * 8);
    }
}

// ---------------- unified split-bf16 MFMA GEMM ----------------
// OUT[m][n] (+= over k) = sum_k A[m][k] * Bt[n][k], K = 2048 (or causal over k<=m).
// AMODE: 0 = A from global split arrays; 1 = Toeplitz from Tf table (stage B scores)
// OUTM:  0 = f32; 1 = split pair
// CAUSAL: k-tiles limited to 4*(blockIdx.y+1)
// RSC: multiply row m by ksum[idx[bz*L+m]]
template<int AMODE, int OUTM, bool CAUSAL, bool RSC>
__global__ __launch_bounds__(256, 2) void gemm_core(
    const unsigned short* __restrict__ Ah, const unsigned short* __restrict__ Al, size_t sA,
    const unsigned short* __restrict__ Bth, const unsigned short* __restrict__ Btl, size_t sB,
    float* __restrict__ outF, unsigned short* __restrict__ outH,
    unsigned short* __restrict__ outL, size_t sO,
    const float* __restrict__ Tf,
    const int* __restrict__ idxp, const float* __restrict__ ksum)
{
    constexpr int BM = 128, BN = 128, BK = 32;
    __shared__ __align__(16) unsigned short AsH[BM * BK], AsL[BM * BK];
    __shared__ __align__(16) unsigned short BsH[BM * BK], BsL[BM * BK];

    const int tid  = threadIdx.x;
    const int lane = tid & 63, wave = tid >> 6;
    const int wr = wave >> 1, wc = wave & 1;
    const int bz = blockIdx.z;
    const int m0 = blockIdx.y * BM, n0 = blockIdx.x * BN;
    const int r15 = lane & 15, kc = lane >> 4;

    f32x4 acc[4][4];
    const f32x4 zf = {0.f, 0.f, 0.f, 0.f};
    #pragma unroll
    for (int i = 0; i < 4; ++i)
        #pragma unroll
        for (int j = 0; j < 4; ++j) acc[i][j] = zf;

    const unsigned short* Abase  = (AMODE == 0) ? (Ah + (size_t)bz * sA) : nullptr;
    const unsigned short* Abase2 = (AMODE == 0) ? (Al + (size_t)bz * sA) : nullptr;
    const unsigned short* Bbase  = Bth + (size_t)bz * sB;
    const unsigned short* Bbase2 = Btl + (size_t)bz * sB;

    const int ktiles = CAUSAL ? 4 * (blockIdx.y + 1) : (2048 / BK);

    for (int kt = 0; kt < ktiles; ++kt) {
        const int k0 = kt * BK;

        // ---- stage B tiles ----
        stage_tile(Bbase,  n0, k0, BsH, wave, lane);
        stage_tile(Bbase2, n0, k0, BsL, wave, lane);

        // ---- stage A tiles ----
        if constexpr (AMODE == 0) {
            stage_tile(Abase,  m0, k0, AsH, wave, lane);
            stage_tile(Abase2, m0, k0, AsL, wave, lane);
        } else {
            #pragma unroll
            for (int it = 0; it < 2; ++it) {
                int task = tid + it * 256;          // 0..511
                int row = task >> 2, ch = task & 3;
                int x0 = 2047 - (m0 + row) + k0 + ch * 8;
                s16x8 hv, lv;
                #pragma unroll
                for (int i = 0; i < 8; ++i) {
                    float f = Tf[x0 + i];
                    unsigned short h = f2bf(f);
                    unsigned short lo = f2bf(f - bf2f(h));
                    hv[i] = (short)h; lv[i] = (short)lo;
                }
                int cs = ch ^ ((row >> 1) & 3);
                *(s16x8*)&AsH[row * BK + cs * 8] = hv;
                *(s16x8*)&AsL[row * BK + cs * 8] = lv;
            }
        }
        __syncthreads();

        // ---- fragments + MFMA ----
        s16x8 bh[4], blo[4];
        #pragma unroll
        for (int ns = 0; ns < 4; ++ns) {
            int rrow = wc * 64 + ns * 16 + r15;
            int ch = kc ^ ((rrow >> 1) & 3);
            bh[ns]  = *(const s16x8*)&BsH[rrow * BK + ch * 8];
            blo[ns] = *(const s16x8*)&BsL[rrow * BK + ch * 8];
        }
        #pragma unroll
        for (int ms = 0; ms < 4; ++ms) {
            int arow = wr * 64 + ms * 16 + r15;
            int ch = kc ^ ((arow >> 1) & 3);
            s16x8 ah = *(const s16x8*)&AsH[arow * BK + ch * 8];
            s16x8 al = *(const s16x8*)&AsL[arow * BK + ch * 8];
            #pragma unroll
            for (int ns = 0; ns < 4; ++ns) {
                acc[ms][ns] = __builtin_amdgcn_mfma_f32_16x16x32_bf16(ah, bh[ns],  acc[ms][ns], 0, 0, 0);
                acc[ms][ns] = __builtin_amdgcn_mfma_f32_16x16x32_bf16(ah, blo[ns], acc[ms][ns], 0, 0, 0);
                acc[ms][ns] = __builtin_amdgcn_mfma_f32_16x16x32_bf16(al, bh[ns],  acc[ms][ns], 0, 0, 0);
            }
        }
        __syncthreads();
    }

    // ---- epilogue ----
    #pragma unroll
    for (int ms = 0; ms < 4; ++ms) {
        #pragma unroll
        for (int r = 0; r < 4; ++r) {
            int grow = m0 + wr * 64 + ms * 16 + (lane >> 4) * 4 + r;
            float sc = 1.f;
            if constexpr (RSC) sc = ksum[idxp[bz * L + grow]];
            #pragma unroll
            for (int ns = 0; ns < 4; ++ns) {
                float v = acc[ms][ns][r];
                if constexpr (RSC) v *= sc;
                int gcol = n0 + wc * 64 + ns * 16 + r15;
                size_t o = (size_t)bz * sO + (size_t)grow * 2048 + gcol;
                if constexpr (OUTM == 0) {
                    outF[o] = v;
                } else {
                    unsigned short h = f2bf(v);
                    outH[o] = h;
                    outL[o] = f2bf(v - bf2f(h));
                }
            }
        }
    }
}

// ---------------- precompute kernels ----------------

__global__ __launch_bounds__(256) void colsum_kernel(const float* __restrict__ W,
                                                     float* __restrict__ out) {
    int t = blockIdx.x * blockDim.x + threadIdx.x;
    if (t >= V) return;
    float s = 0.f;
    for (int j = 0; j < V; ++j) s += W[(size_t)j * V + t];
    out[t] = s;
}

// out(hi/lo)[i][j] = split(A[j][i])
__global__ void transpose_split_kernel(const float* __restrict__ A,
                                       unsigned short* __restrict__ Th,
                                       unsigned short* __restrict__ Tl) {
    __shared__ float tile[32][33];
    int x = blockIdx.x * 32 + threadIdx.x;
    int y0 = blockIdx.y * 32;
    for (int r = threadIdx.y; r < 32; r += 8)
        tile[r][threadIdx.x] = A[(size_t)(y0 + r) * V + x];
    __syncthreads();
    int xo = blockIdx.y * 32 + threadIdx.x;
    int yo0 = blockIdx.x * 32;
    for (int r = threadIdx.y; r < 32; r += 8) {
        float f = tile[threadIdx.x][r];
        unsigned short h = f2bf(f);
        Th[(size_t)(yo0 + r) * V + xo] = h;
        Tl[(size_t)(yo0 + r) * V + xo] = f2bf(f - bf2f(h));
    }
}

__global__ __launch_bounds__(256) void split_kernel(const float* __restrict__ A,
                                                    unsigned short* __restrict__ H,
                                                    unsigned short* __restrict__ Lo,
                                                    int n4) {
    int i = blockIdx.x * 256 + threadIdx.x;
    if (i >= n4) return;
    float4 f = ((const float4*)A)[i];
    ushort4 h, l;
    h.x = f2bf(f.x); l.x = f2bf(f.x - bf2f(h.x));
    h.y = f2bf(f.y); l.y = f2bf(f.y - bf2f(h.y));
    h.z = f2bf(f.z); l.z = f2bf(f.z - bf2f(h.z));
    h.w = f2bf(f.w); l.w = f2bf(f.w - bf2f(h.w));
    ((ushort4*)H)[i] = h;
    ((ushort4*)Lo)[i] = l;
}

// Tf[x] = v1[2047-x] for x<=2047 else 0   (size 2304)
__global__ void tf_kernel(const float* __restrict__ v1, float* __restrict__ Tf) {
    int x = blockIdx.x * 256 + threadIdx.x;
    if (x < 2304) Tf[x] = (x <= 2047) ? v1[2047 - x] : 0.f;
}

// ---------------- scatter kernels (token bucketing) ----------------
// block: 8 q-rows; LDS buckets [8][V] f32; write split pairs.

__global__ __launch_bounds__(256) void scatterA_kernel(const int* __restrict__ idx,
                                                       const float* __restrict__ G0,
                                                       const float* __restrict__ ks0,
                                                       const float* __restrict__ v0,
                                                       unsigned short* __restrict__ Th,
                                                       unsigned short* __restrict__ Tl) {
    __shared__ float buck[8 * 2048];
    int tid = threadIdx.x;
    const float4 z4 = make_float4(0.f, 0.f, 0.f, 0.f);
    for (int i = tid; i < 8 * 2048 / 4; i += 256) ((float4*)buck)[i] = z4;
    __syncthreads();

    int b = blockIdx.y, q0 = blockIdx.x * 8;
    int qr = tid >> 5, kl = tid & 31;
    int q = q0 + qr;
    int iq = idx[b * L + q];
    float kq = ks0[iq];
    const float* Grow = G0 + (size_t)iq * V;
    for (int k = kl; k <= q; k += 32) {
        int ik = idx[b * L + k];
        float val = Grow[ik] + kq * v0[q - k];
        atomicAdd(&buck[qr * 2048 + ik], val);
    }
    __syncthreads();
    size_t base = ((size_t)b * L + q0) * V;
    for (int i = tid; i < 8 * 2048; i += 256) {
        float v = buck[i];
        unsigned short h = f2bf(v);
        Th[base + i] = h;
        Tl[base + i] = f2bf(v - bf2f(h));
    }
}

__global__ __launch_bounds__(256) void scatterC_kernel(const int* __restrict__ idx,
                                                       const float* __restrict__ T2t,
                                                       unsigned short* __restrict__ Th,
                                                       unsigned short* __restrict__ Tl) {
    __shared__ float buck[8 * 2048];
    int tid = threadIdx.x;
    const float4 z4 = make_float4(0.f, 0.f, 0.f, 0.f);
    for (int i = tid; i < 8 * 2048 / 4; i += 256) ((float4*)buck)[i] = z4;
    __syncthreads();

    int b = blockIdx.y, q0 = blockIdx.x * 8;
    int qr = tid >> 5, kl = tid & 31;
    int q = q0 + qr;
    int iq = idx[b * L + q];
    const float* Trow = T2t + ((size_t)b * V + iq) * L;
    for (int k = kl; k <= q; k += 32) {
        int ik = idx[b * L + k];
        atomicAdd(&buck[qr * 2048 + ik], Trow[k]);
    }
    __syncthreads();
    size_t base = ((size_t)b * L + q0) * V;
    for (int i = tid; i < 8 * 2048; i += 256) {
        float v = buck[i];
        unsigned short h = f2bf(v);
        Th[base + i] = h;
        Tl[base + i] = f2bf(v - bf2f(h));
    }
}

// ---------------- launcher ----------------

extern "C" void kernel_launch(void* const* d_in, const int* in_sizes, int n_in,
                              void* d_out, int out_size, void* d_ws, size_t ws_size,
                              hipStream_t stream) {
    (void)in_sizes; (void)n_in; (void)out_size; (void)ws_size;
    const int*   idx = (const int*)d_in[0];
    const float* Wq0 = (const float*)d_in[1];
    const float* Wk0 = (const float*)d_in[2];
    const float* Wv0 = (const float*)d_in[3];
    const float* Wk1 = (const float*)d_in[4];
    const float* Wv1 = (const float*)d_in[5];
    const float* Wq2 = (const float*)d_in[6];
    const float* Wk2 = (const float*)d_in[7];
    const float* Wv2 = (const float*)d_in[8];
    const float* v0  = (const float*)d_in[9];
    const float* v1  = (const float*)d_in[10];
    float* out = (float*)d_out;

    char* W = (char*)d_ws;
    const size_t MB = 1024 * 1024;
    unsigned short* R1 = (unsigned short*)(W);             // 64 MiB region
    unsigned short* R2 = (unsigned short*)(W + 64 * MB);   // 64 MiB region
    unsigned short* R3 = (unsigned short*)(W + 128 * MB);  // 64 MiB region
    unsigned short* SW = (unsigned short*)(W + 192 * MB);  // 16 MiB region
    float* Tf  = (float*)(W + 208 * MB);
    float* ks0 = (float*)(W + 208 * MB + 64 * 1024);
    float* ks1 = (float*)(W + 208 * MB + 128 * 1024);

    dim3 blk(256);

    // 1) transposes+splits for G0, column sums, v1 table
    transpose_split_kernel<<<dim3(64, 64), dim3(32, 8), 0, stream>>>(Wq0, R1, R1 + VV);
    transpose_split_kernel<<<dim3(64, 64), dim3(32, 8), 0, stream>>>(Wk0, R1 + 2 * VV, R1 + 3 * VV);
    colsum_kernel<<<dim3(8), blk, 0, stream>>>(Wk0, ks0);
    colsum_kernel<<<dim3(8), blk, 0, stream>>>(Wk1, ks1);
    tf_kernel<<<dim3(9), blk, 0, stream>>>(v1, Tf);

    // 2) G0 = Wq0^T Wk0  (f32) -> R3
    gemm_core<0, 0, false, false><<<dim3(16, 16, 1), blk, 0, stream>>>(
        R1, R1 + VV, 0, R1 + 2 * VV, R1 + 3 * VV, 0,
        (float*)R3, nullptr, nullptr, 0, nullptr, nullptr, nullptr);

    // 3) scatter A -> Tacc pair in R2
    scatterA_kernel<<<dim3(L / 8, NB), blk, 0, stream>>>(idx, (const float*)R3, ks0, v0,
                                                         R2, R2 + BLV);

    // 4) split Wv0 -> SW
    split_kernel<<<dim3((int)(VV / 4 / 256)), blk, 0, stream>>>(Wv0, SW, SW + VV, (int)(VV / 4));

    // 5) l0 = TaccA . Wv0rows -> pair in R1   (M = 8192)
    gemm_core<0, 1, false, false><<<dim3(16, 64, 1), blk, 0, stream>>>(
        R2, R2 + BLV, 0, SW, SW + VV, 0,
        nullptr, R1, R1 + BLV, 0, nullptr, nullptr, nullptr);

    // 6) split Wv1 -> SW
    split_kernel<<<dim3((int)(VV / 4 / 256)), blk, 0, stream>>>(Wv1, SW, SW + VV, (int)(VV / 4));

    // 7) V1t[b] = Wv1 . l0[b]^T -> pair in R2
    gemm_core<0, 1, false, false><<<dim3(16, 16, NB), blk, 0, stream>>>(
        SW, SW + VV, 0, R1, R1 + BLV, LV,
        nullptr, R2, R2 + BLV, LV, nullptr, nullptr, nullptr);

    // 8) l1[b] = causal Toeplitz(v1) . V1t[b] (rowscale ksum1) -> pair in R3
    gemm_core<1, 1, true, true><<<dim3(16, 16, NB), blk, 0, stream>>>(
        nullptr, nullptr, 0, R2, R2 + BLV, LV,
        nullptr, R3, R3 + BLV, LV, Tf, idx, ks1);

    // 9) Mt = Wq2^T Wk2 -> pair in SW (transposes into R1 first)
    transpose_split_kernel<<<dim3(64, 64), dim3(32, 8), 0, stream>>>(Wq2, R1, R1 + VV);
    transpose_split_kernel<<<dim3(64, 64), dim3(32, 8), 0, stream>>>(Wk2, R1 + 2 * VV, R1 + 3 * VV);
    gemm_core<0, 1, false, false><<<dim3(16, 16, 1), blk, 0, stream>>>(
        R1, R1 + VV, 0, R1 + 2 * VV, R1 + 3 * VV, 0,
        nullptr, SW, SW + VV, 0, nullptr, nullptr, nullptr);

    // 10) T2t[b] = Mt . l1[b]^T (f32) -> R2
    gemm_core<0, 0, false, false><<<dim3(16, 16, NB), blk, 0, stream>>>(
        SW, SW + VV, 0, R3, R3 + BLV, LV,
        (float*)R2, nullptr, nullptr, LV, nullptr, nullptr, nullptr);

    // 11) scatter C -> Tacc pair in R1
    scatterC_kernel<<<dim3(L / 8, NB), blk, 0, stream>>>(idx, (const float*)R2, R1, R1 + BLV);

    // 12) split Wv2 -> SW
    split_kernel<<<dim3((int)(VV / 4 / 256)), blk, 0, stream>>>(Wv2, SW, SW + VV, (int)(VV / 4));

    // 13) logits = TaccC . Wv2rows (f32) -> d_out  (M = 8192)
    gemm_core<0, 0, false, false><<<dim3(16, 64, 1), blk, 0, stream>>>(
        R1, R1 + BLV, 0, SW, SW + VV, 0,
        out, nullptr, nullptr, 0, nullptr, nullptr, nullptr);
}

// Round 3
// 1058.148 us; speedup vs baseline: 5.8049x; 1.4594x over previous
//
#include <hip/hip_runtime.h>

typedef float f32x4 __attribute__((ext_vector_type(4)));
typedef short s16x8 __attribute__((ext_vector_type(8)));

constexpr int L = 2048;
constexpr int V = 2048;
constexpr int NB = 4;
constexpr size_t VV  = (size_t)V * V;    // 4194304
constexpr size_t BLV = (size_t)NB * L * V; // 16777216
constexpr size_t LV  = (size_t)L * V;    // 4194304

// ---------- bf16 helpers (bit-level, RNE) ----------
__device__ __forceinline__ unsigned short f2bf(float f) {
    unsigned u = __float_as_uint(f);
    u = (u + 0x7FFFu + ((u >> 16) & 1u)) >> 16;
    return (unsigned short)u;
}
__device__ __forceinline__ float bf2f(unsigned short s) {
    return __uint_as_float(((unsigned)s) << 16);
}

// ---------- async global->LDS 16B ----------
__device__ __forceinline__ void gload16(const unsigned short* g, unsigned short* l) {
    auto gp = (const __attribute__((address_space(1))) unsigned int*)g;
    auto lp = (__attribute__((address_space(3))) unsigned int*)l;
    __builtin_amdgcn_global_load_lds(gp, lp, 16, 0, 0);
}

// stage one 128x32 bf16 tile into LDS, XOR-swizzled chunks. ld = 2048.
__device__ __forceinline__ void stage_tile(const unsigned short* g0, int r0, int k0,
                                           unsigned short* lds, int wave, int lane) {
    #pragma unroll
    for (int i = 0; i < 2; ++i) {
        int r  = i * 64 + wave * 16 + (lane >> 2);
        int cs = (lane & 3) ^ ((r >> 1) & 3);
        const unsigned short* g = g0 + (size_t)(r0 + r) * 2048 + k0 + cs * 8;
        gload16(g, lds + (size_t)(i * 256 + wave * 64) * 8);
    }
}

// ---------- shared MFMA fragment step (one 128x128x32 K-step, split-bf16 3x) ----------
__device__ __forceinline__ void frag_mfma(const unsigned short* AsH, const unsigned short* AsL,
                                          const unsigned short* BsH, const unsigned short* BsL,
                                          f32x4 (&acc)[4][4], int lane, int wr, int wc) {
    const int r15 = lane & 15, kc = lane >> 4;
    s16x8 bh[4], blo[4];
    #pragma unroll
    for (int ns = 0; ns < 4; ++ns) {
        int rrow = wc * 64 + ns * 16 + r15;
        int ch = kc ^ ((rrow >> 1) & 3);
        bh[ns]  = *(const s16x8*)&BsH[rrow * 32 + ch * 8];
        blo[ns] = *(const s16x8*)&BsL[rrow * 32 + ch * 8];
    }
    #pragma unroll
    for (int ms = 0; ms < 4; ++ms) {
        int arow = wr * 64 + ms * 16 + r15;
        int ch = kc ^ ((arow >> 1) & 3);
        s16x8 ah = *(const s16x8*)&AsH[arow * 32 + ch * 8];
        s16x8 al = *(const s16x8*)&AsL[arow * 32 + ch * 8];
        #pragma unroll
        for (int ns = 0; ns < 4; ++ns) {
            acc[ms][ns] = __builtin_amdgcn_mfma_f32_16x16x32_bf16(ah, bh[ns],  acc[ms][ns], 0, 0, 0);
            acc[ms][ns] = __builtin_amdgcn_mfma_f32_16x16x32_bf16(ah, blo[ns], acc[ms][ns], 0, 0, 0);
            acc[ms][ns] = __builtin_amdgcn_mfma_f32_16x16x32_bf16(al, bh[ns],  acc[ms][ns], 0, 0, 0);
        }
    }
}

// ---------------- fused precompute GEMM: up to 3 independent [V,V] NT GEMMs ----------------
struct GemmDesc {
    const unsigned short *Ah, *Al, *Bh, *Bl;
    float* oF;                  // if set: f32 out, else split pair
    unsigned short *oH, *oL;
};

__global__ __launch_bounds__(256, 2) void gemm_pre3(GemmDesc d0, GemmDesc d1, GemmDesc d2) {
    GemmDesc d = (blockIdx.z == 0) ? d0 : (blockIdx.z == 1) ? d1 : d2;
    __shared__ __align__(16) unsigned short AsH[128 * 32], AsL[128 * 32];
    __shared__ __align__(16) unsigned short BsH[128 * 32], BsL[128 * 32];
    const int tid  = threadIdx.x;
    const int lane = tid & 63, wave = tid >> 6;
    const int wr = wave >> 1, wc = wave & 1;
    const int m0 = blockIdx.y * 128, n0 = blockIdx.x * 128;
    const int r15 = lane & 15;

    f32x4 acc[4][4];
    const f32x4 zf = {0.f, 0.f, 0.f, 0.f};
    #pragma unroll
    for (int i = 0; i < 4; ++i)
        #pragma unroll
        for (int j = 0; j < 4; ++j) acc[i][j] = zf;

    for (int kt = 0; kt < 64; ++kt) {
        const int k0 = kt * 32;
        stage_tile(d.Bh, n0, k0, BsH, wave, lane);
        stage_tile(d.Bl, n0, k0, BsL, wave, lane);
        stage_tile(d.Ah, m0, k0, AsH, wave, lane);
        stage_tile(d.Al, m0, k0, AsL, wave, lane);
        __syncthreads();
        frag_mfma(AsH, AsL, BsH, BsL, acc, lane, wr, wc);
        __syncthreads();
    }

    const bool isF = (d.oF != nullptr);
    #pragma unroll
    for (int ms = 0; ms < 4; ++ms) {
        #pragma unroll
        for (int r = 0; r < 4; ++r) {
            int grow = m0 + wr * 64 + ms * 16 + (lane >> 4) * 4 + r;
            #pragma unroll
            for (int ns = 0; ns < 4; ++ns) {
                float v = acc[ms][ns][r];
                int gcol = n0 + wc * 64 + ns * 16 + r15;
                size_t o = (size_t)grow * 2048 + gcol;
                if (isF) {
                    d.oF[o] = v;
                } else {
                    unsigned short h = f2bf(v);
                    d.oH[o] = h;
                    d.oL[o] = f2bf(v - bf2f(h));
                }
            }
        }
    }
}

// ---------------- main GEMM: OUT[m][n] = sum_k A[m][k]*Bt[n][k] ----------------
// TOEP: Bt[n][k] = v1[n-k] (causal, k<=n), ktiles = 4*(bx+1), col-scale ks[idx[bz*L+n]]
template<int OUTM, bool TOEP>
__global__ __launch_bounds__(256, 2) void gemm_core(
    const unsigned short* __restrict__ Ah, const unsigned short* __restrict__ Al, size_t sA,
    const unsigned short* __restrict__ Bth, const unsigned short* __restrict__ Btl, size_t sB,
    float* __restrict__ outF, unsigned short* __restrict__ outH,
    unsigned short* __restrict__ outL, size_t sO,
    const float* __restrict__ Tf,
    const int* __restrict__ idxp, const float* __restrict__ ks)
{
    __shared__ __align__(16) unsigned short AsH[128 * 32], AsL[128 * 32];
    __shared__ __align__(16) unsigned short BsH[128 * 32], BsL[128 * 32];
    const int tid  = threadIdx.x;
    const int lane = tid & 63, wave = tid >> 6;
    const int wr = wave >> 1, wc = wave & 1;
    const int bz = blockIdx.z;
    const int m0 = blockIdx.y * 128, n0 = blockIdx.x * 128;
    const int r15 = lane & 15;

    f32x4 acc[4][4];
    const f32x4 zf = {0.f, 0.f, 0.f, 0.f};
    #pragma unroll
    for (int i = 0; i < 4; ++i)
        #pragma unroll
        for (int j = 0; j < 4; ++j) acc[i][j] = zf;

    const unsigned short* Abase  = Ah + (size_t)bz * sA;
    const unsigned short* Abase2 = Al + (size_t)bz * sA;
    const unsigned short* Bbase  = TOEP ? nullptr : (Bth + (size_t)bz * sB);
    const unsigned short* Bbase2 = TOEP ? nullptr : (Btl + (size_t)bz * sB);

    const int ktiles = TOEP ? 4 * (blockIdx.x + 1) : 64;

    for (int kt = 0; kt < ktiles; ++kt) {
        const int k0 = kt * 32;
        if constexpr (!TOEP) {
            stage_tile(Bbase,  n0, k0, BsH, wave, lane);
            stage_tile(Bbase2, n0, k0, BsL, wave, lane);
        }
        stage_tile(Abase,  m0, k0, AsH, wave, lane);
        stage_tile(Abase2, m0, k0, AsL, wave, lane);
        if constexpr (TOEP) {
            #pragma unroll
            for (int it = 0; it < 2; ++it) {
                int task = tid + it * 256;          // 0..511
                int row = task >> 2, ch = task & 3;
                int x0 = 2047 - (n0 + row) + k0 + ch * 8;
                s16x8 hv, lv;
                #pragma unroll
                for (int i = 0; i < 8; ++i) {
                    float f = Tf[x0 + i];
                    unsigned short h = f2bf(f);
                    unsigned short lo = f2bf(f - bf2f(h));
                    hv[i] = (short)h; lv[i] = (short)lo;
                }
                int cs = ch ^ ((row >> 1) & 3);
                *(s16x8*)&BsH[row * 32 + cs * 8] = hv;
                *(s16x8*)&BsL[row * 32 + cs * 8] = lv;
            }
        }
        __syncthreads();
        frag_mfma(AsH, AsL, BsH, BsL, acc, lane, wr, wc);
        __syncthreads();
    }

    float csc[4];
    if constexpr (TOEP) {
        #pragma unroll
        for (int ns = 0; ns < 4; ++ns) {
            int gcol = n0 + wc * 64 + ns * 16 + r15;
            csc[ns] = ks[idxp[bz * L + gcol]];
        }
    }

    #pragma unroll
    for (int ms = 0; ms < 4; ++ms) {
        #pragma unroll
        for (int r = 0; r < 4; ++r) {
            int grow = m0 + wr * 64 + ms * 16 + (lane >> 4) * 4 + r;
            #pragma unroll
            for (int ns = 0; ns < 4; ++ns) {
                float v = acc[ms][ns][r];
                if constexpr (TOEP) v *= csc[ns];
                int gcol = n0 + wc * 64 + ns * 16 + r15;
                size_t o = (size_t)bz * sO + (size_t)grow * 2048 + gcol;
                if constexpr (OUTM == 0) {
                    outF[o] = v;
                } else {
                    unsigned short h = f2bf(v);
                    outH[o] = h;
                    outL[o] = f2bf(v - bf2f(h));
                }
            }
        }
    }
}

// ---------------- prep kernels ----------------

// grid 256: block b sums rows [8b,8b+8) of W, atomicAdd into out[2048] (pre-zeroed)
__global__ __launch_bounds__(256) void colsum_atomic(const float* __restrict__ W,
                                                     float* __restrict__ out) {
    int r0 = blockIdx.x * 8;
    int c = threadIdx.x;
    float s[8];
    #pragma unroll
    for (int i = 0; i < 8; ++i) s[i] = 0.f;
    for (int r = 0; r < 8; ++r) {
        const float* row = W + (size_t)(r0 + r) * V;
        #pragma unroll
        for (int i = 0; i < 8; ++i) s[i] += row[c + i * 256];
    }
    #pragma unroll
    for (int i = 0; i < 8; ++i) atomicAdd(&out[c + i * 256], s[i]);
}

// zero ks0/ks1, fill Tf[x] = v1[2047-x] (x<=2047) else 0; grid 9x256
__global__ void init_kernel(const float* __restrict__ v1, float* __restrict__ Tf,
                            float* __restrict__ ks0, float* __restrict__ ks1) {
    int i = blockIdx.x * 256 + threadIdx.x;
    if (i < 2048) { ks0[i] = 0.f; ks1[i] = 0.f; }
    if (i < 2304) Tf[i] = (i <= 2047) ? v1[2047 - i] : 0.f;
}

struct TDesc { const float* A; unsigned short *Th, *Tl; };

// 5 fused transpose+split: out[i][j] = split(A[j][i]); grid (64,64,5), block (32,8)
__global__ void transpose_split_multi(TDesc d0, TDesc d1, TDesc d2, TDesc d3, TDesc d4) {
    TDesc d;
    switch (blockIdx.z) {
        case 0: d = d0; break;
        case 1: d = d1; break;
        case 2: d = d2; break;
        case 3: d = d3; break;
        default: d = d4; break;
    }
    __shared__ float tile[32][33];
    int x = blockIdx.x * 32 + threadIdx.x;
    int y0 = blockIdx.y * 32;
    for (int r = threadIdx.y; r < 32; r += 8)
        tile[r][threadIdx.x] = d.A[(size_t)(y0 + r) * V + x];
    __syncthreads();
    int xo = blockIdx.y * 32 + threadIdx.x;
    int yo0 = blockIdx.x * 32;
    for (int r = threadIdx.y; r < 32; r += 8) {
        float f = tile[threadIdx.x][r];
        unsigned short h = f2bf(f);
        d.Th[(size_t)(yo0 + r) * V + xo] = h;
        d.Tl[(size_t)(yo0 + r) * V + xo] = f2bf(f - bf2f(h));
    }
}

__global__ __launch_bounds__(256) void split_kernel(const float* __restrict__ A,
                                                    unsigned short* __restrict__ H,
                                                    unsigned short* __restrict__ Lo,
                                                    int n4) {
    int i = blockIdx.x * 256 + threadIdx.x;
    if (i >= n4) return;
    float4 f = ((const float4*)A)[i];
    ushort4 h, l;
    h.x = f2bf(f.x); l.x = f2bf(f.x - bf2f(h.x));
    h.y = f2bf(f.y); l.y = f2bf(f.y - bf2f(h.y));
    h.z = f2bf(f.z); l.z = f2bf(f.z - bf2f(h.z));
    h.w = f2bf(f.w); l.w = f2bf(f.w - bf2f(h.w));
    ((ushort4*)H)[i] = h;
    ((ushort4*)Lo)[i] = l;
}

// ---------------- scatter kernels (token bucketing) ----------------

__global__ __launch_bounds__(256) void scatterA_kernel(const int* __restrict__ idx,
                                                       const float* __restrict__ G0,
                                                       const float* __restrict__ ks0,
                                                       const float* __restrict__ v0,
                                                       unsigned short* __restrict__ Th,
                                                       unsigned short* __restrict__ Tl) {
    __shared__ float buck[8 * 2048];
    int tid = threadIdx.x;
    const float4 z4 = make_float4(0.f, 0.f, 0.f, 0.f);
    for (int i = tid; i < 8 * 2048 / 4; i += 256) ((float4*)buck)[i] = z4;
    __syncthreads();

    int b = blockIdx.y, q0 = blockIdx.x * 8;
    int qr = tid >> 5, kl = tid & 31;
    int q = q0 + qr;
    int iq = idx[b * L + q];
    float kq = ks0[iq];
    const float* Grow = G0 + (size_t)iq * V;
    for (int k = kl; k <= q; k += 32) {
        int ik = idx[b * L + k];
        float val = Grow[ik] + kq * v0[q - k];
        atomicAdd(&buck[qr * 2048 + ik], val);
    }
    __syncthreads();
    size_t base = ((size_t)b * L + q0) * V;
    for (int i = tid; i < 8 * 2048; i += 256) {
        float v = buck[i];
        unsigned short h = f2bf(v);
        Th[base + i] = h;
        Tl[base + i] = f2bf(v - bf2f(h));
    }
}

__global__ __launch_bounds__(256) void scatterC_kernel(const int* __restrict__ idx,
                                                       const float* __restrict__ T2t,
                                                       unsigned short* __restrict__ Th,
                                                       unsigned short* __restrict__ Tl) {
    __shared__ float buck[8 * 2048];
    int tid = threadIdx.x;
    const float4 z4 = make_float4(0.f, 0.f, 0.f, 0.f);
    for (int i = tid; i < 8 * 2048 / 4; i += 256) ((float4*)buck)[i] = z4;
    __syncthreads();

    int b = blockIdx.y, q0 = blockIdx.x * 8;
    int qr = tid >> 5, kl = tid & 31;
    int q = q0 + qr;
    int iq = idx[b * L + q];
    const float* Trow = T2t + ((size_t)b * V + iq) * L;
    for (int k = kl; k <= q; k += 32) {
        int ik = idx[b * L + k];
        atomicAdd(&buck[qr * 2048 + ik], Trow[k]);
    }
    __syncthreads();
    size_t base = ((size_t)b * L + q0) * V;
    for (int i = tid; i < 8 * 2048; i += 256) {
        float v = buck[i];
        unsigned short h = f2bf(v);
        Th[base + i] = h;
        Tl[base + i] = f2bf(v - bf2f(h));
    }
}

// ---------------- launcher ----------------

extern "C" void kernel_launch(void* const* d_in, const int* in_sizes, int n_in,
                              void* d_out, int out_size, void* d_ws, size_t ws_size,
                              hipStream_t stream) {
    (void)in_sizes; (void)n_in; (void)out_size; (void)ws_size;
    const int*   idx = (const int*)d_in[0];
    const float* Wq0 = (const float*)d_in[1];
    const float* Wk0 = (const float*)d_in[2];
    const float* Wv0 = (const float*)d_in[3];
    const float* Wk1 = (const float*)d_in[4];
    const float* Wv1 = (const float*)d_in[5];
    const float* Wq2 = (const float*)d_in[6];
    const float* Wk2 = (const float*)d_in[7];
    const float* Wv2 = (const float*)d_in[8];
    const float* v0  = (const float*)d_in[9];
    const float* v1  = (const float*)d_in[10];
    float* out = (float*)d_out;

    char* W = (char*)d_ws;
    const size_t MiB = 1024 * 1024;

    // A0 region [0, 64 MiB): TA pair, later T2t f32. PPT pair parked at its head early.
    unsigned short* TAh = (unsigned short*)W;
    unsigned short* TAl = TAh + BLV;
    float*          T2f = (float*)W;
    unsigned short* PPT = (unsigned short*)W;          // pair, 16 MiB, pre-scatterA only
    // AU region [64, 128 MiB): Y-slots early, then U pair, then TC pair.
    unsigned short* Y1 = (unsigned short*)(W + 64 * MiB);   // Wv0T pair
    unsigned short* Y2 = (unsigned short*)(W + 80 * MiB);   // Wv1 split pair
    float*          Gf = (float*)(W + 96 * MiB);            // G0 f32
    unsigned short* Y4 = (unsigned short*)(W + 112 * MiB);  // M pair
    unsigned short* Uh = (unsigned short*)(W + 64 * MiB);
    unsigned short* Ul = Uh + BLV;
    unsigned short* TCh = Uh;
    unsigned short* TCl = Ul;
    // X slots
    unsigned short* X1 = (unsigned short*)(W + 128 * MiB);  // Wq0T, then R pair
    unsigned short* X2 = (unsigned short*)(W + 144 * MiB);  // Wk0T, then Wv2 split
    unsigned short* X3 = (unsigned short*)(W + 160 * MiB);  // Wq2T pair
    unsigned short* X4 = (unsigned short*)(W + 176 * MiB);  // Wk2T pair
    float* Tf  = (float*)(W + 192 * MiB);
    float* ks0 = (float*)(W + 192 * MiB + 16 * 1024);
    float* ks1 = (float*)(W + 192 * MiB + 32 * 1024);

    dim3 blk(256);

    // prep: transposes/splits, tables, column sums
    {
        TDesc t0{Wq0, X1, X1 + VV}, t1{Wk0, X2, X2 + VV}, t2{Wq2, X3, X3 + VV},
              t3{Wk2, X4, X4 + VV}, t4{Wv0, Y1, Y1 + VV};
        transpose_split_multi<<<dim3(64, 64, 5), dim3(32, 8), 0, stream>>>(t0, t1, t2, t3, t4);
    }
    split_kernel<<<dim3((int)(VV / 4 / 256)), blk, 0, stream>>>(Wv1, Y2, Y2 + VV, (int)(VV / 4));
    init_kernel<<<dim3(9), blk, 0, stream>>>(v1, Tf, ks0, ks1);
    colsum_atomic<<<dim3(256), blk, 0, stream>>>(Wk0, ks0);
    colsum_atomic<<<dim3(256), blk, 0, stream>>>(Wk1, ks1);

    // fused precomputes: G0 = Wq0^T Wk0 (f32), M = Wq2^T Wk2 (pair), PPT (pair)
    {
        GemmDesc dG{X1, X1 + VV, X2, X2 + VV, Gf, nullptr, nullptr};
        GemmDesc dM{X3, X3 + VV, X4, X4 + VV, nullptr, Y4, Y4 + VV};
        GemmDesc dP{Y1, Y1 + VV, Y2, Y2 + VV, nullptr, PPT, PPT + VV};
        gemm_pre3<<<dim3(16, 16, 3), blk, 0, stream>>>(dG, dM, dP);
    }
    // R = M . PPT -> X1 (pair)
    {
        GemmDesc dR{Y4, Y4 + VV, PPT, PPT + VV, nullptr, X1, X1 + VV};
        gemm_pre3<<<dim3(16, 16, 1), blk, 0, stream>>>(dR, dR, dR);
    }

    // scatter A (token buckets of layer-0 scores) -> TA pair (overwrites PPT region)
    scatterA_kernel<<<dim3(L / 8, NB), blk, 0, stream>>>(idx, Gf, ks0, v0, TAh, TAl);

    // U[b] = R . TA[b]^T  -> pair in AU
    gemm_core<1, false><<<dim3(16, 16, NB), blk, 0, stream>>>(
        X1, X1 + VV, 0, TAh, TAl, LV,
        nullptr, Uh, Ul, LV, nullptr, nullptr, nullptr);

    // T2t[b][v,q] = ks1[iq_q] * sum_{k<=q} v1[q-k] * U[b][v,k]  -> f32 in A0
    gemm_core<0, true><<<dim3(16, 16, NB), blk, 0, stream>>>(
        Uh, Ul, LV, nullptr, nullptr, 0,
        T2f, nullptr, nullptr, LV, Tf, idx, ks1);

    // scatter C -> TC pair (overwrites U)
    scatterC_kernel<<<dim3(L / 8, NB), blk, 0, stream>>>(idx, T2f, TCh, TCl);

    // split Wv2 -> X2
    split_kernel<<<dim3((int)(VV / 4 / 256)), blk, 0, stream>>>(Wv2, X2, X2 + VV, (int)(VV / 4));

    // logits = TC . Wv2^T-rows -> d_out (M = 8192)
    gemm_core<0, false><<<dim3(16, 64, 1), blk, 0, stream>>>(
        TCh, TCl, 0, X2, X2 + VV, 0,
        out, nullptr, nullptr, 0, nullptr, nullptr, nullptr);
}

// Round 4
// 1026.190 us; speedup vs baseline: 5.9857x; 1.0311x over previous
//
#include <hip/hip_runtime.h>

typedef float f32x4 __attribute__((ext_vector_type(4)));
typedef short s16x8 __attribute__((ext_vector_type(8)));

constexpr int L = 2048;
constexpr int V = 2048;
constexpr int NB = 4;
constexpr size_t VV  = (size_t)V * V;      // 4194304
constexpr size_t BLV = (size_t)NB * L * V; // 16777216
constexpr size_t LV  = (size_t)L * V;      // 4194304

// ---------- bf16 helpers (bit-level, RNE) ----------
__device__ __forceinline__ unsigned short f2bf(float f) {
    unsigned u = __float_as_uint(f);
    u = (u + 0x7FFFu + ((u >> 16) & 1u)) >> 16;
    return (unsigned short)u;
}
__device__ __forceinline__ float bf2f(unsigned short s) {
    return __uint_as_float(((unsigned)s) << 16);
}

// ---------- async global->LDS 16B ----------
__device__ __forceinline__ void gload16(const unsigned short* g, unsigned short* l) {
    auto gp = (const __attribute__((address_space(1))) unsigned int*)g;
    auto lp = (__attribute__((address_space(3))) unsigned int*)l;
    __builtin_amdgcn_global_load_lds(gp, lp, 16, 0, 0);
}

// ================= 128x128 split-fused kernel (precomputes; proven) =================

__device__ __forceinline__ void stage_tile(const unsigned short* g0, int r0, int k0,
                                           unsigned short* lds, int wave, int lane) {
    #pragma unroll
    for (int i = 0; i < 2; ++i) {
        int r  = i * 64 + wave * 16 + (lane >> 2);
        int cs = (lane & 3) ^ ((r >> 1) & 3);
        const unsigned short* g = g0 + (size_t)(r0 + r) * 2048 + k0 + cs * 8;
        gload16(g, lds + (size_t)(i * 256 + wave * 64) * 8);
    }
}

__device__ __forceinline__ void frag_mfma(const unsigned short* AsH, const unsigned short* AsL,
                                          const unsigned short* BsH, const unsigned short* BsL,
                                          f32x4 (&acc)[4][4], int lane, int wr, int wc) {
    const int r15 = lane & 15, kc = lane >> 4;
    s16x8 bh[4], blo[4];
    #pragma unroll
    for (int ns = 0; ns < 4; ++ns) {
        int rrow = wc * 64 + ns * 16 + r15;
        int ch = kc ^ ((rrow >> 1) & 3);
        bh[ns]  = *(const s16x8*)&BsH[rrow * 32 + ch * 8];
        blo[ns] = *(const s16x8*)&BsL[rrow * 32 + ch * 8];
    }
    #pragma unroll
    for (int ms = 0; ms < 4; ++ms) {
        int arow = wr * 64 + ms * 16 + r15;
        int ch = kc ^ ((arow >> 1) & 3);
        s16x8 ah = *(const s16x8*)&AsH[arow * 32 + ch * 8];
        s16x8 al = *(const s16x8*)&AsL[arow * 32 + ch * 8];
        #pragma unroll
        for (int ns = 0; ns < 4; ++ns) {
            acc[ms][ns] = __builtin_amdgcn_mfma_f32_16x16x32_bf16(ah, bh[ns],  acc[ms][ns], 0, 0, 0);
            acc[ms][ns] = __builtin_amdgcn_mfma_f32_16x16x32_bf16(ah, blo[ns], acc[ms][ns], 0, 0, 0);
            acc[ms][ns] = __builtin_amdgcn_mfma_f32_16x16x32_bf16(al, bh[ns],  acc[ms][ns], 0, 0, 0);
        }
    }
}

struct GemmDesc {
    const unsigned short *Ah, *Al, *Bh, *Bl;
    float* oF;                  // if set: f32 out, else split pair
    unsigned short *oH, *oL;
};

__global__ __launch_bounds__(256, 2) void gemm_pre3(GemmDesc d0, GemmDesc d1, GemmDesc d2) {
    GemmDesc d = (blockIdx.z == 0) ? d0 : (blockIdx.z == 1) ? d1 : d2;
    __shared__ __align__(16) unsigned short AsH[128 * 32], AsL[128 * 32];
    __shared__ __align__(16) unsigned short BsH[128 * 32], BsL[128 * 32];
    const int tid  = threadIdx.x;
    const int lane = tid & 63, wave = tid >> 6;
    const int wr = wave >> 1, wc = wave & 1;
    const int m0 = blockIdx.y * 128, n0 = blockIdx.x * 128;
    const int r15 = lane & 15;

    f32x4 acc[4][4];
    const f32x4 zf = {0.f, 0.f, 0.f, 0.f};
    #pragma unroll
    for (int i = 0; i < 4; ++i)
        #pragma unroll
        for (int j = 0; j < 4; ++j) acc[i][j] = zf;

    for (int kt = 0; kt < 64; ++kt) {
        const int k0 = kt * 32;
        stage_tile(d.Bh, n0, k0, BsH, wave, lane);
        stage_tile(d.Bl, n0, k0, BsL, wave, lane);
        stage_tile(d.Ah, m0, k0, AsH, wave, lane);
        stage_tile(d.Al, m0, k0, AsL, wave, lane);
        __syncthreads();
        frag_mfma(AsH, AsL, BsH, BsL, acc, lane, wr, wc);
        __syncthreads();
    }

    const bool isF = (d.oF != nullptr);
    #pragma unroll
    for (int ms = 0; ms < 4; ++ms) {
        #pragma unroll
        for (int r = 0; r < 4; ++r) {
            int grow = m0 + wr * 64 + ms * 16 + (lane >> 4) * 4 + r;
            #pragma unroll
            for (int ns = 0; ns < 4; ++ns) {
                float v = acc[ms][ns][r];
                int gcol = n0 + wc * 64 + ns * 16 + r15;
                size_t o = (size_t)grow * 2048 + gcol;
                if (isF) {
                    d.oF[o] = v;
                } else {
                    unsigned short h = f2bf(v);
                    d.oH[o] = h;
                    d.oL[o] = f2bf(v - bf2f(h));
                }
            }
        }
    }
}

// ================= 256x256 deep-pipelined kernel (unified K'' = 3*2048) =================
// OUT[m][n] = sum_k A[m][k]*Bt[n][k] via 3 interleaved bf16 streams per 32-K block:
//   kt%3==0: Ah*Bh, ==1: Ah*Bl, ==2: Al*Bh   (same accumulation order as split-fused)
// TOEP: causal ktile cutoff 24*(bx+1) + epilogue col-scale ks[idx[bz*L+col]]

__device__ __forceinline__ void stage3(const unsigned short* Ah, const unsigned short* Al,
                                       const unsigned short* Bh, const unsigned short* Bl,
                                       int m0, int n0, int kt, unsigned short* lbuf,
                                       int wave, int lane) {
    int kb = kt / 3;
    int s  = kt - 3 * kb;
    int k0 = kb * 32;
    const unsigned short* As = (s < 2) ? Ah : Al;
    const unsigned short* Bs = (s == 1) ? Bl : Bh;
    int rl = lane >> 2, csl = lane & 3;
    #pragma unroll
    for (int h = 0; h < 2; ++h) {
        int r0 = wave * 32 + h * 16;
        int row = r0 + rl;
        int ch = csl ^ ((row >> 1) & 3);
        gload16(As + (size_t)(m0 + row) * 2048 + k0 + ch * 8, lbuf + r0 * 32);
        gload16(Bs + (size_t)(n0 + row) * 2048 + k0 + ch * 8, lbuf + 8192 + r0 * 32);
    }
}

template<int OUTM, bool TOEP>
__global__ __launch_bounds__(512, 2) void gemm_big(
    const unsigned short* __restrict__ Ah, const unsigned short* __restrict__ Al, size_t sA,
    const unsigned short* __restrict__ Bh, const unsigned short* __restrict__ Bl, size_t sB,
    float* __restrict__ outF, unsigned short* __restrict__ outH,
    unsigned short* __restrict__ outL, size_t sO,
    const int* __restrict__ idxp, const float* __restrict__ ks)
{
    __shared__ __align__(16) unsigned short lds[4 * 16384];   // 4 bufs x (A 8192 + B 8192) ushorts

    const int tid  = threadIdx.x;
    const int lane = tid & 63, wave = tid >> 6;
    const int wr = wave >> 2, wc = wave & 3;        // 2 x 4 wave grid
    const int bz = blockIdx.z;
    const int m0 = blockIdx.y * 256, n0 = blockIdx.x * 256;
    const int r15 = lane & 15, kc = lane >> 4;

    const unsigned short* Abh = Ah + (size_t)bz * sA;
    const unsigned short* Abl = Al + (size_t)bz * sA;
    const unsigned short* Bbh = Bh + (size_t)bz * sB;
    const unsigned short* Bbl = Bl + (size_t)bz * sB;

    const int NT = TOEP ? 24 * (blockIdx.x + 1) : 192;

    f32x4 acc[8][4];
    const f32x4 zf = {0.f, 0.f, 0.f, 0.f};
    #pragma unroll
    for (int i = 0; i < 8; ++i)
        #pragma unroll
        for (int j = 0; j < 4; ++j) acc[i][j] = zf;

    // prologue: issue tiles 0..2
    #pragma unroll
    for (int p = 0; p < 3; ++p)
        stage3(Abh, Abl, Bbh, Bbl, m0, n0, p, lds + p * 16384, wave, lane);

    for (int t = 0; t < NT; ++t) {
        if (t + 3 < NT)
            stage3(Abh, Abl, Bbh, Bbl, m0, n0, t + 3, lds + ((t + 3) & 3) * 16384, wave, lane);
        __builtin_amdgcn_sched_barrier(0);
        int ahead = NT - 1 - t;
        if (ahead >= 3)      asm volatile("s_waitcnt vmcnt(12)" ::: "memory");
        else if (ahead == 2) asm volatile("s_waitcnt vmcnt(8)" ::: "memory");
        else if (ahead == 1) asm volatile("s_waitcnt vmcnt(4)" ::: "memory");
        else                 asm volatile("s_waitcnt vmcnt(0)" ::: "memory");
        __builtin_amdgcn_s_barrier();
        __builtin_amdgcn_sched_barrier(0);

        const unsigned short* As = lds + (t & 3) * 16384;
        const unsigned short* Bs = As + 8192;

        s16x8 bfr[4];
        #pragma unroll
        for (int nf = 0; nf < 4; ++nf) {
            int row = wc * 64 + nf * 16 + r15;
            int cs = kc ^ ((row >> 1) & 3);
            bfr[nf] = *(const s16x8*)&Bs[row * 32 + cs * 8];
        }
        __builtin_amdgcn_s_setprio(1);
        #pragma unroll
        for (int mf = 0; mf < 8; ++mf) {
            int row = wr * 128 + mf * 16 + r15;
            int cs = kc ^ ((row >> 1) & 3);
            s16x8 a = *(const s16x8*)&As[row * 32 + cs * 8];
            #pragma unroll
            for (int nf = 0; nf < 4; ++nf)
                acc[mf][nf] = __builtin_amdgcn_mfma_f32_16x16x32_bf16(a, bfr[nf], acc[mf][nf], 0, 0, 0);
        }
        __builtin_amdgcn_s_setprio(0);
        __builtin_amdgcn_sched_barrier(0);
        __builtin_amdgcn_s_barrier();
    }

    // epilogue
    float csc[4];
    if constexpr (TOEP) {
        #pragma unroll
        for (int nf = 0; nf < 4; ++nf) {
            int gcol = n0 + wc * 64 + nf * 16 + r15;
            csc[nf] = ks[idxp[bz * L + gcol]];
        }
    }
    #pragma unroll
    for (int mf = 0; mf < 8; ++mf) {
        #pragma unroll
        for (int r = 0; r < 4; ++r) {
            int grow = m0 + wr * 128 + mf * 16 + kc * 4 + r;
            #pragma unroll
            for (int nf = 0; nf < 4; ++nf) {
                float v = acc[mf][nf][r];
                if constexpr (TOEP) v *= csc[nf];
                int gcol = n0 + wc * 64 + nf * 16 + r15;
                size_t o = (size_t)bz * sO + (size_t)grow * 2048 + gcol;
                if constexpr (OUTM == 0) {
                    outF[o] = v;
                } else {
                    unsigned short h = f2bf(v);
                    outH[o] = h;
                    outL[o] = f2bf(v - bf2f(h));
                }
            }
        }
    }
}

// ---------------- prep kernels ----------------

__global__ __launch_bounds__(256) void colsum_atomic(const float* __restrict__ W,
                                                     float* __restrict__ out) {
    int r0 = blockIdx.x * 8;
    int c = threadIdx.x;
    float s[8];
    #pragma unroll
    for (int i = 0; i < 8; ++i) s[i] = 0.f;
    for (int r = 0; r < 8; ++r) {
        const float* row = W + (size_t)(r0 + r) * V;
        #pragma unroll
        for (int i = 0; i < 8; ++i) s[i] += row[c + i * 256];
    }
    #pragma unroll
    for (int i = 0; i < 8; ++i) atomicAdd(&out[c + i * 256], s[i]);
}

__global__ void init_kernel(float* __restrict__ ks0, float* __restrict__ ks1) {
    int i = blockIdx.x * 256 + threadIdx.x;
    if (i < 2048) { ks0[i] = 0.f; ks1[i] = 0.f; }
}

// materialize split Toeplitz: TB[n][k] = (k<=n) ? v1[n-k] : 0; grid 2048 x 256 thr
__global__ __launch_bounds__(256) void tb_fill(const float* __restrict__ v1,
                                               unsigned short* __restrict__ TBh,
                                               unsigned short* __restrict__ TBl) {
    int n = blockIdx.x;
    int c0 = threadIdx.x * 8;
    s16x8 hv, lv;
    #pragma unroll
    for (int i = 0; i < 8; ++i) {
        int k = c0 + i;
        float f = (k <= n) ? v1[n - k] : 0.f;
        unsigned short h = f2bf(f);
        hv[i] = (short)h; lv[i] = (short)f2bf(f - bf2f(h));
    }
    *(s16x8*)&TBh[(size_t)n * 2048 + c0] = hv;
    *(s16x8*)&TBl[(size_t)n * 2048 + c0] = lv;
}

struct TDesc { const float* A; unsigned short *Th, *Tl; };

__global__ void transpose_split_multi(TDesc d0, TDesc d1, TDesc d2, TDesc d3, TDesc d4) {
    TDesc d;
    switch (blockIdx.z) {
        case 0: d = d0; break;
        case 1: d = d1; break;
        case 2: d = d2; break;
        case 3: d = d3; break;
        default: d = d4; break;
    }
    __shared__ float tile[32][33];
    int x = blockIdx.x * 32 + threadIdx.x;
    int y0 = blockIdx.y * 32;
    for (int r = threadIdx.y; r < 32; r += 8)
        tile[r][threadIdx.x] = d.A[(size_t)(y0 + r) * V + x];
    __syncthreads();
    int xo = blockIdx.y * 32 + threadIdx.x;
    int yo0 = blockIdx.x * 32;
    for (int r = threadIdx.y; r < 32; r += 8) {
        float f = tile[threadIdx.x][r];
        unsigned short h = f2bf(f);
        d.Th[(size_t)(yo0 + r) * V + xo] = h;
        d.Tl[(size_t)(yo0 + r) * V + xo] = f2bf(f - bf2f(h));
    }
}

__global__ __launch_bounds__(256) void split_kernel(const float* __restrict__ A,
                                                    unsigned short* __restrict__ H,
                                                    unsigned short* __restrict__ Lo,
                                                    int n4) {
    int i = blockIdx.x * 256 + threadIdx.x;
    if (i >= n4) return;
    float4 f = ((const float4*)A)[i];
    ushort4 h, l;
    h.x = f2bf(f.x); l.x = f2bf(f.x - bf2f(h.x));
    h.y = f2bf(f.y); l.y = f2bf(f.y - bf2f(h.y));
    h.z = f2bf(f.z); l.z = f2bf(f.z - bf2f(h.z));
    h.w = f2bf(f.w); l.w = f2bf(f.w - bf2f(h.w));
    ((ushort4*)H)[i] = h;
    ((ushort4*)Lo)[i] = l;
}

// ---------------- scatter kernels ----------------

__global__ __launch_bounds__(256) void scatterA_kernel(const int* __restrict__ idx,
                                                       const float* __restrict__ G0,
                                                       const float* __restrict__ ks0,
                                                       const float* __restrict__ v0,
                                                       unsigned short* __restrict__ Th,
                                                       unsigned short* __restrict__ Tl) {
    __shared__ float buck[8 * 2048];
    int tid = threadIdx.x;
    const float4 z4 = make_float4(0.f, 0.f, 0.f, 0.f);
    for (int i = tid; i < 8 * 2048 / 4; i += 256) ((float4*)buck)[i] = z4;
    __syncthreads();

    int b = blockIdx.y, q0 = blockIdx.x * 8;
    int qr = tid >> 5, kl = tid & 31;
    int q = q0 + qr;
    int iq = idx[b * L + q];
    float kq = ks0[iq];
    const float* Grow = G0 + (size_t)iq * V;
    for (int k = kl; k <= q; k += 32) {
        int ik = idx[b * L + k];
        float val = Grow[ik] + kq * v0[q - k];
        atomicAdd(&buck[qr * 2048 + ik], val);
    }
    __syncthreads();
    size_t base = ((size_t)b * L + q0) * V;
    for (int i = tid; i < 8 * 2048; i += 256) {
        float v = buck[i];
        unsigned short h = f2bf(v);
        Th[base + i] = h;
        Tl[base + i] = f2bf(v - bf2f(h));
    }
}

__global__ __launch_bounds__(256) void scatterC_kernel(const int* __restrict__ idx,
                                                       const float* __restrict__ T2t,
                                                       unsigned short* __restrict__ Th,
                                                       unsigned short* __restrict__ Tl) {
    __shared__ float buck[8 * 2048];
    int tid = threadIdx.x;
    const float4 z4 = make_float4(0.f, 0.f, 0.f, 0.f);
    for (int i = tid; i < 8 * 2048 / 4; i += 256) ((float4*)buck)[i] = z4;
    __syncthreads();

    int b = blockIdx.y, q0 = blockIdx.x * 8;
    int qr = tid >> 5, kl = tid & 31;
    int q = q0 + qr;
    int iq = idx[b * L + q];
    const float* Trow = T2t + ((size_t)b * V + iq) * L;
    for (int k = kl; k <= q; k += 32) {
        int ik = idx[b * L + k];
        atomicAdd(&buck[qr * 2048 + ik], Trow[k]);
    }
    __syncthreads();
    size_t base = ((size_t)b * L + q0) * V;
    for (int i = tid; i < 8 * 2048; i += 256) {
        float v = buck[i];
        unsigned short h = f2bf(v);
        Th[base + i] = h;
        Tl[base + i] = f2bf(v - bf2f(h));
    }
}

// ---------------- launcher ----------------

extern "C" void kernel_launch(void* const* d_in, const int* in_sizes, int n_in,
                              void* d_out, int out_size, void* d_ws, size_t ws_size,
                              hipStream_t stream) {
    (void)in_sizes; (void)n_in; (void)out_size; (void)ws_size;
    const int*   idx = (const int*)d_in[0];
    const float* Wq0 = (const float*)d_in[1];
    const float* Wk0 = (const float*)d_in[2];
    const float* Wv0 = (const float*)d_in[3];
    const float* Wk1 = (const float*)d_in[4];
    const float* Wv1 = (const float*)d_in[5];
    const float* Wq2 = (const float*)d_in[6];
    const float* Wk2 = (const float*)d_in[7];
    const float* Wv2 = (const float*)d_in[8];
    const float* v0  = (const float*)d_in[9];
    const float* v1  = (const float*)d_in[10];
    float* out = (float*)d_out;

    char* W = (char*)d_ws;
    const size_t MiB = 1024 * 1024;

    // A0 region [0, 64 MiB): TA pair, later T2t f32. PPT pair parked at its head early.
    unsigned short* TAh = (unsigned short*)W;
    unsigned short* TAl = TAh + BLV;
    float*          T2f = (float*)W;
    unsigned short* PPT = (unsigned short*)W;
    // AU region [64, 128 MiB): Y-slots early, then U pair, then TC pair.
    unsigned short* Y1 = (unsigned short*)(W + 64 * MiB);   // Wv0T pair
    unsigned short* Y2 = (unsigned short*)(W + 80 * MiB);   // Wv1 split pair
    float*          Gf = (float*)(W + 96 * MiB);            // G0 f32
    unsigned short* Y4 = (unsigned short*)(W + 112 * MiB);  // M pair
    unsigned short* Uh = (unsigned short*)(W + 64 * MiB);
    unsigned short* Ul = Uh + BLV;
    unsigned short* TCh = Uh;
    unsigned short* TCl = Ul;
    // X slots [128, 192 MiB)
    unsigned short* X1 = (unsigned short*)(W + 128 * MiB);  // Wq0T, then R pair
    unsigned short* X2 = (unsigned short*)(W + 144 * MiB);  // Wk0T, then Wv2 split
    unsigned short* X3 = (unsigned short*)(W + 160 * MiB);  // Wq2T pair, then TB pair
    unsigned short* X4 = (unsigned short*)(W + 176 * MiB);  // Wk2T pair
    unsigned short* TBh = X3;
    unsigned short* TBl = X3 + VV;
    float* ks0 = (float*)(W + 192 * MiB);
    float* ks1 = (float*)(W + 192 * MiB + 16 * 1024);

    dim3 blk(256);

    // prep: transposes/splits, column sums
    {
        TDesc t0{Wq0, X1, X1 + VV}, t1{Wk0, X2, X2 + VV}, t2{Wq2, X3, X3 + VV},
              t3{Wk2, X4, X4 + VV}, t4{Wv0, Y1, Y1 + VV};
        transpose_split_multi<<<dim3(64, 64, 5), dim3(32, 8), 0, stream>>>(t0, t1, t2, t3, t4);
    }
    split_kernel<<<dim3((int)(VV / 4 / 256)), blk, 0, stream>>>(Wv1, Y2, Y2 + VV, (int)(VV / 4));
    init_kernel<<<dim3(8), blk, 0, stream>>>(ks0, ks1);
    colsum_atomic<<<dim3(256), blk, 0, stream>>>(Wk0, ks0);
    colsum_atomic<<<dim3(256), blk, 0, stream>>>(Wk1, ks1);

    // fused precomputes: G0 = Wq0^T Wk0 (f32), M = Wq2^T Wk2 (pair), PPT = Wv0^T Wv1^Trows (pair)
    {
        GemmDesc dG{X1, X1 + VV, X2, X2 + VV, Gf, nullptr, nullptr};
        GemmDesc dM{X3, X3 + VV, X4, X4 + VV, nullptr, Y4, Y4 + VV};
        GemmDesc dP{Y1, Y1 + VV, Y2, Y2 + VV, nullptr, PPT, PPT + VV};
        gemm_pre3<<<dim3(16, 16, 3), blk, 0, stream>>>(dG, dM, dP);
    }
    // TB materialization (X3's Wq2T is dead after pre3)
    tb_fill<<<dim3(2048), blk, 0, stream>>>(v1, TBh, TBl);
    // R = M . PPT -> X1 (pair)
    {
        GemmDesc dR{Y4, Y4 + VV, PPT, PPT + VV, nullptr, X1, X1 + VV};
        gemm_pre3<<<dim3(16, 16, 1), blk, 0, stream>>>(dR, dR, dR);
    }

    // scatter A -> TA pair (overwrites PPT region)
    scatterA_kernel<<<dim3(L / 8, NB), blk, 0, stream>>>(idx, Gf, ks0, v0, TAh, TAl);

    // U[b] = R . TA[b]^T -> pair in AU
    gemm_big<1, false><<<dim3(8, 8, NB), dim3(512), 0, stream>>>(
        X1, X1 + VV, 0, TAh, TAl, LV,
        nullptr, Uh, Ul, LV, nullptr, nullptr);

    // T2t[b][v,q] = ks1[iq_q] * sum_{k<=q} v1[q-k] * U[b][v,k] -> f32 in A0
    gemm_big<0, true><<<dim3(8, 8, NB), dim3(512), 0, stream>>>(
        Uh, Ul, LV, TBh, TBl, 0,
        T2f, nullptr, nullptr, LV, idx, ks1);

    // scatter C -> TC pair (overwrites U)
    scatterC_kernel<<<dim3(L / 8, NB), blk, 0, stream>>>(idx, T2f, TCh, TCl);

    // split Wv2 -> X2
    split_kernel<<<dim3((int)(VV / 4 / 256)), blk, 0, stream>>>(Wv2, X2, X2 + VV, (int)(VV / 4));

    // logits = TC . Wv2rows -> d_out (M = 8192)
    gemm_big<0, false><<<dim3(8, 32, 1), dim3(512), 0, stream>>>(
        TCh, TCl, 0, X2, X2 + VV, 0,
        out, nullptr, nullptr, 0, nullptr, nullptr);
}

// Round 5
// 1016.026 us; speedup vs baseline: 6.0456x; 1.0100x over previous
//
#include <hip/hip_runtime.h>

typedef float f32x4 __attribute__((ext_vector_type(4)));
typedef short s16x8 __attribute__((ext_vector_type(8)));

constexpr int L = 2048;
constexpr int V = 2048;
constexpr int NB = 4;
constexpr size_t VV  = (size_t)V * V;      // 4194304
constexpr size_t BLV = (size_t)NB * L * V; // 16777216
constexpr size_t LV  = (size_t)L * V;      // 4194304

// ---------- bf16 helpers (bit-level, RNE) ----------
__device__ __forceinline__ unsigned short f2bf(float f) {
    unsigned u = __float_as_uint(f);
    u = (u + 0x7FFFu + ((u >> 16) & 1u)) >> 16;
    return (unsigned short)u;
}
__device__ __forceinline__ float bf2f(unsigned short s) {
    return __uint_as_float(((unsigned)s) << 16);
}

// ---------- async global->LDS 16B ----------
__device__ __forceinline__ void gload16(const unsigned short* g, unsigned short* l) {
    auto gp = (const __attribute__((address_space(1))) unsigned int*)g;
    auto lp = (__attribute__((address_space(3))) unsigned int*)l;
    __builtin_amdgcn_global_load_lds(gp, lp, 16, 0, 0);
}

// ================= 128x128 split-fused kernel (precomputes; proven) =================

__device__ __forceinline__ void stage_tile(const unsigned short* g0, int r0, int k0,
                                           unsigned short* lds, int wave, int lane) {
    #pragma unroll
    for (int i = 0; i < 2; ++i) {
        int r  = i * 64 + wave * 16 + (lane >> 2);
        int cs = (lane & 3) ^ ((r >> 1) & 3);
        const unsigned short* g = g0 + (size_t)(r0 + r) * 2048 + k0 + cs * 8;
        gload16(g, lds + (size_t)(i * 256 + wave * 64) * 8);
    }
}

__device__ __forceinline__ void frag_mfma(const unsigned short* AsH, const unsigned short* AsL,
                                          const unsigned short* BsH, const unsigned short* BsL,
                                          f32x4 (&acc)[4][4], int lane, int wr, int wc) {
    const int r15 = lane & 15, kc = lane >> 4;
    s16x8 bh[4], blo[4];
    #pragma unroll
    for (int ns = 0; ns < 4; ++ns) {
        int rrow = wc * 64 + ns * 16 + r15;
        int ch = kc ^ ((rrow >> 1) & 3);
        bh[ns]  = *(const s16x8*)&BsH[rrow * 32 + ch * 8];
        blo[ns] = *(const s16x8*)&BsL[rrow * 32 + ch * 8];
    }
    #pragma unroll
    for (int ms = 0; ms < 4; ++ms) {
        int arow = wr * 64 + ms * 16 + r15;
        int ch = kc ^ ((arow >> 1) & 3);
        s16x8 ah = *(const s16x8*)&AsH[arow * 32 + ch * 8];
        s16x8 al = *(const s16x8*)&AsL[arow * 32 + ch * 8];
        #pragma unroll
        for (int ns = 0; ns < 4; ++ns) {
            acc[ms][ns] = __builtin_amdgcn_mfma_f32_16x16x32_bf16(ah, bh[ns],  acc[ms][ns], 0, 0, 0);
            acc[ms][ns] = __builtin_amdgcn_mfma_f32_16x16x32_bf16(ah, blo[ns], acc[ms][ns], 0, 0, 0);
            acc[ms][ns] = __builtin_amdgcn_mfma_f32_16x16x32_bf16(al, bh[ns],  acc[ms][ns], 0, 0, 0);
        }
    }
}

struct GemmDesc {
    const unsigned short *Ah, *Al, *Bh, *Bl;
    float* oF;                  // if set: f32 out, else split pair
    unsigned short *oH, *oL;
};

__global__ __launch_bounds__(256, 2) void gemm_pre3(GemmDesc d0, GemmDesc d1, GemmDesc d2) {
    GemmDesc d = (blockIdx.z == 0) ? d0 : (blockIdx.z == 1) ? d1 : d2;
    __shared__ __align__(16) unsigned short AsH[128 * 32], AsL[128 * 32];
    __shared__ __align__(16) unsigned short BsH[128 * 32], BsL[128 * 32];
    const int tid  = threadIdx.x;
    const int lane = tid & 63, wave = tid >> 6;
    const int wr = wave >> 1, wc = wave & 1;
    const int m0 = blockIdx.y * 128, n0 = blockIdx.x * 128;
    const int r15 = lane & 15;

    f32x4 acc[4][4];
    const f32x4 zf = {0.f, 0.f, 0.f, 0.f};
    #pragma unroll
    for (int i = 0; i < 4; ++i)
        #pragma unroll
        for (int j = 0; j < 4; ++j) acc[i][j] = zf;

    for (int kt = 0; kt < 64; ++kt) {
        const int k0 = kt * 32;
        stage_tile(d.Bh, n0, k0, BsH, wave, lane);
        stage_tile(d.Bl, n0, k0, BsL, wave, lane);
        stage_tile(d.Ah, m0, k0, AsH, wave, lane);
        stage_tile(d.Al, m0, k0, AsL, wave, lane);
        __syncthreads();
        frag_mfma(AsH, AsL, BsH, BsL, acc, lane, wr, wc);
        __syncthreads();
    }

    const bool isF = (d.oF != nullptr);
    #pragma unroll
    for (int ms = 0; ms < 4; ++ms) {
        #pragma unroll
        for (int r = 0; r < 4; ++r) {
            int grow = m0 + wr * 64 + ms * 16 + (lane >> 4) * 4 + r;
            #pragma unroll
            for (int ns = 0; ns < 4; ++ns) {
                float v = acc[ms][ns][r];
                int gcol = n0 + wc * 64 + ns * 16 + r15;
                size_t o = (size_t)grow * 2048 + gcol;
                if (isF) {
                    d.oF[o] = v;
                } else {
                    unsigned short h = f2bf(v);
                    d.oH[o] = h;
                    d.oL[o] = f2bf(v - bf2f(h));
                }
            }
        }
    }
}

// ================= 256x256 phased-pipeline kernel (unified K'' = 3*2048) =================
// OUT[m][n] = sum_k A[m][k]*Bt[n][k] via 3 interleaved bf16 streams per 32-K block:
//   kt%3==0: Ah*Bh, ==1: Ah*Bl, ==2: Al*Bh   (same accumulation order as split-fused)
// TOEP: causal ktile cutoff 24*(bx+1) + epilogue col-scale ks[idx[bz*L+col]]
// Schedule: per tile 2 phases x {ds_read subtile | 2 prefetch gloads | barrier |
// setprio(1) 16 MFMA setprio(0) | barrier}; counted vmcnt ladder (8/4/0), never
// drained mid-loop; depth-3 prefetch in 4 rotating 32KB LDS buffers.

__device__ __forceinline__ void stage_chunk(const unsigned short* As, const unsigned short* Bs,
                                            int m0, int n0, int k0, int chunk,
                                            unsigned short* lbuf, int wave, int lane) {
    int rl = lane >> 2, csl = lane & 3;
    int h = chunk & 1;
    int r0 = wave * 32 + h * 16;
    int row = r0 + rl;
    int ch = csl ^ ((row >> 1) & 3);
    if (chunk < 2)
        gload16(As + (size_t)(m0 + row) * 2048 + k0 + ch * 8, lbuf + r0 * 32);
    else
        gload16(Bs + (size_t)(n0 + row) * 2048 + k0 + ch * 8, lbuf + 8192 + r0 * 32);
}

template<int OUTM, bool TOEP>
__global__ __launch_bounds__(512, 2) void gemm_big(
    const unsigned short* __restrict__ Ah, const unsigned short* __restrict__ Al, size_t sA,
    const unsigned short* __restrict__ Bh, const unsigned short* __restrict__ Bl, size_t sB,
    float* __restrict__ outF, unsigned short* __restrict__ outH,
    unsigned short* __restrict__ outL, size_t sO,
    const int* __restrict__ idxp, const float* __restrict__ ks)
{
    __shared__ __align__(16) unsigned short lds[4 * 16384];   // 4 bufs x (A 8192 + B 8192) ushorts

    const int tid  = threadIdx.x;
    const int lane = tid & 63, wave = tid >> 6;
    const int wr = wave >> 2, wc = wave & 3;        // 2 x 4 wave grid
    const int bz = blockIdx.z;
    const int m0 = blockIdx.y * 256, n0 = blockIdx.x * 256;
    const int r15 = lane & 15, kc = lane >> 4;

    const unsigned short* Abh = Ah + (size_t)bz * sA;
    const unsigned short* Abl = Al + (size_t)bz * sA;
    const unsigned short* Bbh = Bh + (size_t)bz * sB;
    const unsigned short* Bbl = Bl + (size_t)bz * sB;

    const int NT = TOEP ? 24 * (blockIdx.x + 1) : 192;

    f32x4 acc[8][4];
    const f32x4 zf = {0.f, 0.f, 0.f, 0.f};
    #pragma unroll
    for (int i = 0; i < 8; ++i)
        #pragma unroll
        for (int j = 0; j < 4; ++j) acc[i][j] = zf;

    // prologue: stage tiles 0..2 (k0 = 0 for all; streams 0,1,2)
    #pragma unroll
    for (int p = 0; p < 3; ++p) {
        const unsigned short* SA = (p < 2) ? Abh : Abl;
        const unsigned short* SB = (p == 1) ? Bbl : Bbh;
        #pragma unroll
        for (int c = 0; c < 4; ++c)
            stage_chunk(SA, SB, m0, n0, 0, c, lds + p * 16384, wave, lane);
    }
    asm volatile("s_waitcnt vmcnt(8)" ::: "memory");
    __builtin_amdgcn_sched_barrier(0);
    __builtin_amdgcn_s_barrier();
    __builtin_amdgcn_sched_barrier(0);

    int s3 = 0, k03 = 32;   // stream / k-base for tile t+3 (tile 3: stream 0, k0 = 32)

    for (int t = 0; t < NT; ++t) {
        const unsigned short* As = lds + (t & 3) * 16384;
        const unsigned short* Bs = As + 8192;
        unsigned short* stbuf = lds + ((t + 3) & 3) * 16384;
        const int rem = NT - 1 - t;
        const bool pre = (rem >= 3);
        const unsigned short* SA = (s3 < 2) ? Abh : Abl;
        const unsigned short* SB = (s3 == 1) ? Bbl : Bbh;

        // ---------------- phase 0 ----------------
        s16x8 bfr[4], afr[4];
        #pragma unroll
        for (int nf = 0; nf < 4; ++nf) {
            int row = wc * 64 + nf * 16 + r15;
            int cs = kc ^ ((row >> 1) & 3);
            bfr[nf] = *(const s16x8*)&Bs[row * 32 + cs * 8];
        }
        #pragma unroll
        for (int mf = 0; mf < 4; ++mf) {
            int row = wr * 128 + mf * 16 + r15;
            int cs = kc ^ ((row >> 1) & 3);
            afr[mf] = *(const s16x8*)&As[row * 32 + cs * 8];
        }
        if (pre) {
            stage_chunk(SA, SB, m0, n0, k03, 0, stbuf, wave, lane);
            stage_chunk(SA, SB, m0, n0, k03, 1, stbuf, wave, lane);
        }
        __builtin_amdgcn_sched_barrier(0);
        __builtin_amdgcn_s_barrier();
        __builtin_amdgcn_sched_barrier(0);
        __builtin_amdgcn_s_setprio(1);
        #pragma unroll
        for (int mf = 0; mf < 4; ++mf)
            #pragma unroll
            for (int nf = 0; nf < 4; ++nf)
                acc[mf][nf] = __builtin_amdgcn_mfma_f32_16x16x32_bf16(afr[mf], bfr[nf], acc[mf][nf], 0, 0, 0);
        __builtin_amdgcn_s_setprio(0);
        __builtin_amdgcn_sched_barrier(0);
        __builtin_amdgcn_s_barrier();
        __builtin_amdgcn_sched_barrier(0);

        // ---------------- phase 1 ----------------
        s16x8 afr2[4];
        #pragma unroll
        for (int mf = 0; mf < 4; ++mf) {
            int row = wr * 128 + (mf + 4) * 16 + r15;
            int cs = kc ^ ((row >> 1) & 3);
            afr2[mf] = *(const s16x8*)&As[row * 32 + cs * 8];
        }
        if (pre) {
            stage_chunk(SA, SB, m0, n0, k03, 2, stbuf, wave, lane);
            stage_chunk(SA, SB, m0, n0, k03, 3, stbuf, wave, lane);
        }
        if (pre)           { asm volatile("s_waitcnt vmcnt(8)" ::: "memory"); }
        else if (rem == 2) { asm volatile("s_waitcnt vmcnt(4)" ::: "memory"); }
        else if (rem == 1) { asm volatile("s_waitcnt vmcnt(0)" ::: "memory"); }
        __builtin_amdgcn_sched_barrier(0);
        __builtin_amdgcn_s_barrier();
        __builtin_amdgcn_sched_barrier(0);
        __builtin_amdgcn_s_setprio(1);
        #pragma unroll
        for (int mf = 0; mf < 4; ++mf)
            #pragma unroll
            for (int nf = 0; nf < 4; ++nf)
                acc[mf + 4][nf] = __builtin_amdgcn_mfma_f32_16x16x32_bf16(afr2[mf], bfr[nf], acc[mf + 4][nf], 0, 0, 0);
        __builtin_amdgcn_s_setprio(0);
        __builtin_amdgcn_sched_barrier(0);
        __builtin_amdgcn_s_barrier();
        __builtin_amdgcn_sched_barrier(0);

        if (++s3 == 3) { s3 = 0; k03 += 32; }
    }

    // epilogue
    float csc[4];
    if constexpr (TOEP) {
        #pragma unroll
        for (int nf = 0; nf < 4; ++nf) {
            int gcol = n0 + wc * 64 + nf * 16 + r15;
            csc[nf] = ks[idxp[bz * L + gcol]];
        }
    }
    #pragma unroll
    for (int mf = 0; mf < 8; ++mf) {
        #pragma unroll
        for (int r = 0; r < 4; ++r) {
            int grow = m0 + wr * 128 + mf * 16 + kc * 4 + r;
            #pragma unroll
            for (int nf = 0; nf < 4; ++nf) {
                float v = acc[mf][nf][r];
                if constexpr (TOEP) v *= csc[nf];
                int gcol = n0 + wc * 64 + nf * 16 + r15;
                size_t o = (size_t)bz * sO + (size_t)grow * 2048 + gcol;
                if constexpr (OUTM == 0) {
                    outF[o] = v;
                } else {
                    unsigned short h = f2bf(v);
                    outH[o] = h;
                    outL[o] = f2bf(v - bf2f(h));
                }
            }
        }
    }
}

// ---------------- prep kernels ----------------

__global__ __launch_bounds__(256) void colsum_atomic(const float* __restrict__ W,
                                                     float* __restrict__ out) {
    int r0 = blockIdx.x * 8;
    int c = threadIdx.x;
    float s[8];
    #pragma unroll
    for (int i = 0; i < 8; ++i) s[i] = 0.f;
    for (int r = 0; r < 8; ++r) {
        const float* row = W + (size_t)(r0 + r) * V;
        #pragma unroll
        for (int i = 0; i < 8; ++i) s[i] += row[c + i * 256];
    }
    #pragma unroll
    for (int i = 0; i < 8; ++i) atomicAdd(&out[c + i * 256], s[i]);
}

__global__ void init_kernel(float* __restrict__ ks0, float* __restrict__ ks1) {
    int i = blockIdx.x * 256 + threadIdx.x;
    if (i < 2048) { ks0[i] = 0.f; ks1[i] = 0.f; }
}

// materialize split Toeplitz: TB[n][k] = (k<=n) ? v1[n-k] : 0; grid 2048 x 256 thr
__global__ __launch_bounds__(256) void tb_fill(const float* __restrict__ v1,
                                               unsigned short* __restrict__ TBh,
                                               unsigned short* __restrict__ TBl) {
    int n = blockIdx.x;
    int c0 = threadIdx.x * 8;
    s16x8 hv, lv;
    #pragma unroll
    for (int i = 0; i < 8; ++i) {
        int k = c0 + i;
        float f = (k <= n) ? v1[n - k] : 0.f;
        unsigned short h = f2bf(f);
        hv[i] = (short)h; lv[i] = (short)f2bf(f - bf2f(h));
    }
    *(s16x8*)&TBh[(size_t)n * 2048 + c0] = hv;
    *(s16x8*)&TBl[(size_t)n * 2048 + c0] = lv;
}

struct TDesc { const float* A; unsigned short *Th, *Tl; };

__global__ void transpose_split_multi(TDesc d0, TDesc d1, TDesc d2, TDesc d3, TDesc d4) {
    TDesc d;
    switch (blockIdx.z) {
        case 0: d = d0; break;
        case 1: d = d1; break;
        case 2: d = d2; break;
        case 3: d = d3; break;
        default: d = d4; break;
    }
    __shared__ float tile[32][33];
    int x = blockIdx.x * 32 + threadIdx.x;
    int y0 = blockIdx.y * 32;
    for (int r = threadIdx.y; r < 32; r += 8)
        tile[r][threadIdx.x] = d.A[(size_t)(y0 + r) * V + x];
    __syncthreads();
    int xo = blockIdx.y * 32 + threadIdx.x;
    int yo0 = blockIdx.x * 32;
    for (int r = threadIdx.y; r < 32; r += 8) {
        float f = tile[threadIdx.x][r];
        unsigned short h = f2bf(f);
        d.Th[(size_t)(yo0 + r) * V + xo] = h;
        d.Tl[(size_t)(yo0 + r) * V + xo] = f2bf(f - bf2f(h));
    }
}

__global__ __launch_bounds__(256) void split_kernel(const float* __restrict__ A,
                                                    unsigned short* __restrict__ H,
                                                    unsigned short* __restrict__ Lo,
                                                    int n4) {
    int i = blockIdx.x * 256 + threadIdx.x;
    if (i >= n4) return;
    float4 f = ((const float4*)A)[i];
    ushort4 h, l;
    h.x = f2bf(f.x); l.x = f2bf(f.x - bf2f(h.x));
    h.y = f2bf(f.y); l.y = f2bf(f.y - bf2f(h.y));
    h.z = f2bf(f.z); l.z = f2bf(f.z - bf2f(h.z));
    h.w = f2bf(f.w); l.w = f2bf(f.w - bf2f(h.w));
    ((ushort4*)H)[i] = h;
    ((ushort4*)Lo)[i] = l;
}

// ---------------- scatter kernels ----------------

__global__ __launch_bounds__(256) void scatterA_kernel(const int* __restrict__ idx,
                                                       const float* __restrict__ G0,
                                                       const float* __restrict__ ks0,
                                                       const float* __restrict__ v0,
                                                       unsigned short* __restrict__ Th,
                                                       unsigned short* __restrict__ Tl) {
    __shared__ float buck[8 * 2048];
    int tid = threadIdx.x;
    const float4 z4 = make_float4(0.f, 0.f, 0.f, 0.f);
    for (int i = tid; i < 8 * 2048 / 4; i += 256) ((float4*)buck)[i] = z4;
    __syncthreads();

    int b = blockIdx.y, q0 = blockIdx.x * 8;
    int qr = tid >> 5, kl = tid & 31;
    int q = q0 + qr;
    int iq = idx[b * L + q];
    float kq = ks0[iq];
    const float* Grow = G0 + (size_t)iq * V;
    for (int k = kl; k <= q; k += 32) {
        int ik = idx[b * L + k];
        float val = Grow[ik] + kq * v0[q - k];
        atomicAdd(&buck[qr * 2048 + ik], val);
    }
    __syncthreads();
    size_t base = ((size_t)b * L + q0) * V;
    for (int i = tid; i < 8 * 2048; i += 256) {
        float v = buck[i];
        unsigned short h = f2bf(v);
        Th[base + i] = h;
        Tl[base + i] = f2bf(v - bf2f(h));
    }
}

__global__ __launch_bounds__(256) void scatterC_kernel(const int* __restrict__ idx,
                                                       const float* __restrict__ T2t,
                                                       unsigned short* __restrict__ Th,
                                                       unsigned short* __restrict__ Tl) {
    __shared__ float buck[8 * 2048];
    int tid = threadIdx.x;
    const float4 z4 = make_float4(0.f, 0.f, 0.f, 0.f);
    for (int i = tid; i < 8 * 2048 / 4; i += 256) ((float4*)buck)[i] = z4;
    __syncthreads();

    int b = blockIdx.y, q0 = blockIdx.x * 8;
    int qr = tid >> 5, kl = tid & 31;
    int q = q0 + qr;
    int iq = idx[b * L + q];
    const float* Trow = T2t + ((size_t)b * V + iq) * L;
    for (int k = kl; k <= q; k += 32) {
        int ik = idx[b * L + k];
        atomicAdd(&buck[qr * 2048 + ik], Trow[k]);
    }
    __syncthreads();
    size_t base = ((size_t)b * L + q0) * V;
    for (int i = tid; i < 8 * 2048; i += 256) {
        float v = buck[i];
        unsigned short h = f2bf(v);
        Th[base + i] = h;
        Tl[base + i] = f2bf(v - bf2f(h));
    }
}

// ---------------- launcher ----------------

extern "C" void kernel_launch(void* const* d_in, const int* in_sizes, int n_in,
                              void* d_out, int out_size, void* d_ws, size_t ws_size,
                              hipStream_t stream) {
    (void)in_sizes; (void)n_in; (void)out_size; (void)ws_size;
    const int*   idx = (const int*)d_in[0];
    const float* Wq0 = (const float*)d_in[1];
    const float* Wk0 = (const float*)d_in[2];
    const float* Wv0 = (const float*)d_in[3];
    const float* Wk1 = (const float*)d_in[4];
    const float* Wv1 = (const float*)d_in[5];
    const float* Wq2 = (const float*)d_in[6];
    const float* Wk2 = (const float*)d_in[7];
    const float* Wv2 = (const float*)d_in[8];
    const float* v0  = (const float*)d_in[9];
    const float* v1  = (const float*)d_in[10];
    float* out = (float*)d_out;

    char* W = (char*)d_ws;
    const size_t MiB = 1024 * 1024;

    // A0 region [0, 64 MiB): TA pair, later T2t f32. PPT pair parked at its head early.
    unsigned short* TAh = (unsigned short*)W;
    unsigned short* TAl = TAh + BLV;
    float*          T2f = (float*)W;
    unsigned short* PPT = (unsigned short*)W;
    // AU region [64, 128 MiB): Y-slots early, then U pair, then TC pair.
    unsigned short* Y1 = (unsigned short*)(W + 64 * MiB);   // Wv0T pair
    unsigned short* Y2 = (unsigned short*)(W + 80 * MiB);   // Wv1 split pair
    float*          Gf = (float*)(W + 96 * MiB);            // G0 f32
    unsigned short* Y4 = (unsigned short*)(W + 112 * MiB);  // M pair
    unsigned short* Uh = (unsigned short*)(W + 64 * MiB);
    unsigned short* Ul = Uh + BLV;
    unsigned short* TCh = Uh;
    unsigned short* TCl = Ul;
    // X slots [128, 192 MiB)
    unsigned short* X1 = (unsigned short*)(W + 128 * MiB);  // Wq0T, then R pair
    unsigned short* X2 = (unsigned short*)(W + 144 * MiB);  // Wk0T, then Wv2 split
    unsigned short* X3 = (unsigned short*)(W + 160 * MiB);  // Wq2T pair, then TB pair
    unsigned short* X4 = (unsigned short*)(W + 176 * MiB);  // Wk2T pair
    unsigned short* TBh = X3;
    unsigned short* TBl = X3 + VV;
    float* ks0 = (float*)(W + 192 * MiB);
    float* ks1 = (float*)(W + 192 * MiB + 16 * 1024);

    dim3 blk(256);

    // prep: transposes/splits, column sums
    {
        TDesc t0{Wq0, X1, X1 + VV}, t1{Wk0, X2, X2 + VV}, t2{Wq2, X3, X3 + VV},
              t3{Wk2, X4, X4 + VV}, t4{Wv0, Y1, Y1 + VV};
        transpose_split_multi<<<dim3(64, 64, 5), dim3(32, 8), 0, stream>>>(t0, t1, t2, t3, t4);
    }
    split_kernel<<<dim3((int)(VV / 4 / 256)), blk, 0, stream>>>(Wv1, Y2, Y2 + VV, (int)(VV / 4));
    init_kernel<<<dim3(8), blk, 0, stream>>>(ks0, ks1);
    colsum_atomic<<<dim3(256), blk, 0, stream>>>(Wk0, ks0);
    colsum_atomic<<<dim3(256), blk, 0, stream>>>(Wk1, ks1);

    // fused precomputes: G0 = Wq0^T Wk0 (f32), M = Wq2^T Wk2 (pair), PPT = Wv0^T Wv1^Trows (pair)
    {
        GemmDesc dG{X1, X1 + VV, X2, X2 + VV, Gf, nullptr, nullptr};
        GemmDesc dM{X3, X3 + VV, X4, X4 + VV, nullptr, Y4, Y4 + VV};
        GemmDesc dP{Y1, Y1 + VV, Y2, Y2 + VV, nullptr, PPT, PPT + VV};
        gemm_pre3<<<dim3(16, 16, 3), blk, 0, stream>>>(dG, dM, dP);
    }
    // TB materialization (X3's Wq2T is dead after pre3)
    tb_fill<<<dim3(2048), blk, 0, stream>>>(v1, TBh, TBl);
    // R = M . PPT -> X1 (pair)
    {
        GemmDesc dR{Y4, Y4 + VV, PPT, PPT + VV, nullptr, X1, X1 + VV};
        gemm_pre3<<<dim3(16, 16, 1), blk, 0, stream>>>(dR, dR, dR);
    }

    // scatter A -> TA pair (overwrites PPT region)
    scatterA_kernel<<<dim3(L / 8, NB), blk, 0, stream>>>(idx, Gf, ks0, v0, TAh, TAl);

    // U[b] = R . TA[b]^T -> pair in AU
    gemm_big<1, false><<<dim3(8, 8, NB), dim3(512), 0, stream>>>(
        X1, X1 + VV, 0, TAh, TAl, LV,
        nullptr, Uh, Ul, LV, nullptr, nullptr);

    // T2t[b][v,q] = ks1[iq_q] * sum_{k<=q} v1[q-k] * U[b][v,k] -> f32 in A0
    gemm_big<0, true><<<dim3(8, 8, NB), dim3(512), 0, stream>>>(
        Uh, Ul, LV, TBh, TBl, 0,
        T2f, nullptr, nullptr, LV, idx, ks1);

    // scatter C -> TC pair (overwrites U)
    scatterC_kernel<<<dim3(L / 8, NB), blk, 0, stream>>>(idx, T2f, TCh, TCl);

    // split Wv2 -> X2
    split_kernel<<<dim3((int)(VV / 4 / 256)), blk, 0, stream>>>(Wv2, X2, X2 + VV, (int)(VV / 4));

    // logits = TC . Wv2rows -> d_out (M = 8192)
    gemm_big<0, false><<<dim3(8, 32, 1), dim3(512), 0, stream>>>(
        TCh, TCl, 0, X2, X2 + VV, 0,
        out, nullptr, nullptr, 0, nullptr, nullptr);
}

// Round 6
// 968.878 us; speedup vs baseline: 6.3398x; 1.0487x over previous
//
#include <hip/hip_runtime.h>

typedef float f32x4 __attribute__((ext_vector_type(4)));
typedef short s16x8 __attribute__((ext_vector_type(8)));

constexpr int L = 2048;
constexpr int V = 2048;
constexpr int NB = 4;
constexpr size_t VV  = (size_t)V * V;      // 4194304
constexpr size_t BLV = (size_t)NB * L * V; // 16777216
constexpr size_t LV  = (size_t)L * V;      // 4194304

// ---------- bf16 helpers (bit-level, RNE) ----------
__device__ __forceinline__ unsigned short f2bf(float f) {
    unsigned u = __float_as_uint(f);
    u = (u + 0x7FFFu + ((u >> 16) & 1u)) >> 16;
    return (unsigned short)u;
}
__device__ __forceinline__ float bf2f(unsigned short s) {
    return __uint_as_float(((unsigned)s) << 16);
}

// ---------- async global->LDS 16B ----------
__device__ __forceinline__ void gload16(const unsigned short* g, unsigned short* l) {
    auto gp = (const __attribute__((address_space(1))) unsigned int*)g;
    auto lp = (__attribute__((address_space(3))) unsigned int*)l;
    __builtin_amdgcn_global_load_lds(gp, lp, 16, 0, 0);
}

// ================= 128x128 split-fused kernel (precomputes; proven) =================

__device__ __forceinline__ void stage_tile(const unsigned short* g0, int r0, int k0,
                                           unsigned short* lds, int wave, int lane) {
    #pragma unroll
    for (int i = 0; i < 2; ++i) {
        int r  = i * 64 + wave * 16 + (lane >> 2);
        int cs = (lane & 3) ^ ((r >> 1) & 3);
        const unsigned short* g = g0 + (size_t)(r0 + r) * 2048 + k0 + cs * 8;
        gload16(g, lds + (size_t)(i * 256 + wave * 64) * 8);
    }
}

__device__ __forceinline__ void frag_mfma(const unsigned short* AsH, const unsigned short* AsL,
                                          const unsigned short* BsH, const unsigned short* BsL,
                                          f32x4 (&acc)[4][4], int lane, int wr, int wc) {
    const int r15 = lane & 15, kc = lane >> 4;
    s16x8 bh[4], blo[4];
    #pragma unroll
    for (int ns = 0; ns < 4; ++ns) {
        int rrow = wc * 64 + ns * 16 + r15;
        int ch = kc ^ ((rrow >> 1) & 3);
        bh[ns]  = *(const s16x8*)&BsH[rrow * 32 + ch * 8];
        blo[ns] = *(const s16x8*)&BsL[rrow * 32 + ch * 8];
    }
    #pragma unroll
    for (int ms = 0; ms < 4; ++ms) {
        int arow = wr * 64 + ms * 16 + r15;
        int ch = kc ^ ((arow >> 1) & 3);
        s16x8 ah = *(const s16x8*)&AsH[arow * 32 + ch * 8];
        s16x8 al = *(const s16x8*)&AsL[arow * 32 + ch * 8];
        #pragma unroll
        for (int ns = 0; ns < 4; ++ns) {
            acc[ms][ns] = __builtin_amdgcn_mfma_f32_16x16x32_bf16(ah, bh[ns],  acc[ms][ns], 0, 0, 0);
            acc[ms][ns] = __builtin_amdgcn_mfma_f32_16x16x32_bf16(ah, blo[ns], acc[ms][ns], 0, 0, 0);
            acc[ms][ns] = __builtin_amdgcn_mfma_f32_16x16x32_bf16(al, bh[ns],  acc[ms][ns], 0, 0, 0);
        }
    }
}

struct GemmDesc {
    const unsigned short *Ah, *Al, *Bh, *Bl;
    float* oF;                  // if set: f32 out, else split pair
    unsigned short *oH, *oL;
};

__global__ __launch_bounds__(256, 2) void gemm_pre3(GemmDesc d0, GemmDesc d1, GemmDesc d2) {
    GemmDesc d = (blockIdx.z == 0) ? d0 : (blockIdx.z == 1) ? d1 : d2;
    __shared__ __align__(16) unsigned short AsH[128 * 32], AsL[128 * 32];
    __shared__ __align__(16) unsigned short BsH[128 * 32], BsL[128 * 32];
    const int tid  = threadIdx.x;
    const int lane = tid & 63, wave = tid >> 6;
    const int wr = wave >> 1, wc = wave & 1;
    const int m0 = blockIdx.y * 128, n0 = blockIdx.x * 128;
    const int r15 = lane & 15;

    f32x4 acc[4][4];
    const f32x4 zf = {0.f, 0.f, 0.f, 0.f};
    #pragma unroll
    for (int i = 0; i < 4; ++i)
        #pragma unroll
        for (int j = 0; j < 4; ++j) acc[i][j] = zf;

    for (int kt = 0; kt < 64; ++kt) {
        const int k0 = kt * 32;
        stage_tile(d.Bh, n0, k0, BsH, wave, lane);
        stage_tile(d.Bl, n0, k0, BsL, wave, lane);
        stage_tile(d.Ah, m0, k0, AsH, wave, lane);
        stage_tile(d.Al, m0, k0, AsL, wave, lane);
        __syncthreads();
        frag_mfma(AsH, AsL, BsH, BsL, acc, lane, wr, wc);
        __syncthreads();
    }

    const bool isF = (d.oF != nullptr);
    #pragma unroll
    for (int ms = 0; ms < 4; ++ms) {
        #pragma unroll
        for (int r = 0; r < 4; ++r) {
            int grow = m0 + wr * 64 + ms * 16 + (lane >> 4) * 4 + r;
            #pragma unroll
            for (int ns = 0; ns < 4; ++ns) {
                float v = acc[ms][ns][r];
                int gcol = n0 + wc * 64 + ns * 16 + r15;
                size_t o = (size_t)grow * 2048 + gcol;
                if (isF) {
                    d.oF[o] = v;
                } else {
                    unsigned short h = f2bf(v);
                    d.oH[o] = h;
                    d.oL[o] = f2bf(v - bf2f(h));
                }
            }
        }
    }
}

// ================= 256x256 4-stream pipelined kernel =================
// OUT[m][n] = sum_k A[m][k]*Bt[n][k], split-bf16: per 32-K block stage Ah,Al,Bh,Bl
// ONCE (64KB), then 3 register-product phases: P0 ah*bh, P1 ah*bl, P2 al*bh
// (per-accumulator order identical to gemm_pre3 -> bit-exact).
// Double-buffered (2x64KB); 8 gloads/wave issued in P0 for block t+1; boundary
// vmcnt(0)+barrier with a full block of latency slack.
// TOEP: causal K-block cutoff 8*(bx+1) + epilogue col-scale ks[idx[bz*L+col]]

__device__ __forceinline__ void stage4(const unsigned short* A_h, const unsigned short* A_l,
                                       const unsigned short* B_h, const unsigned short* B_l,
                                       int m0, int n0, int k0, unsigned short* buf,
                                       int wave, int lane) {
    int rl = lane >> 2, csl = lane & 3;
    #pragma unroll
    for (int h = 0; h < 2; ++h) {
        int rr = wave * 32 + h * 16;               // LDS row base (wave-uniform)
        int row = rr + rl;
        int ch = csl ^ ((row >> 1) & 3);
        size_t ga = (size_t)row * 2048 + k0 + ch * 8;
        gload16(A_h + (size_t)m0 * 2048 + ga, buf + rr * 32);
        gload16(A_l + (size_t)m0 * 2048 + ga, buf + 8192 + rr * 32);
        gload16(B_h + (size_t)n0 * 2048 + ga, buf + 16384 + rr * 32);
        gload16(B_l + (size_t)n0 * 2048 + ga, buf + 24576 + rr * 32);
    }
}

__device__ __forceinline__ s16x8 frag(const unsigned short* arr, int row, int kc) {
    int cs = kc ^ ((row >> 1) & 3);
    return *(const s16x8*)&arr[row * 32 + cs * 8];
}

template<int OUTM, bool TOEP>
__global__ __launch_bounds__(512, 2) void gemm_big(
    const unsigned short* __restrict__ Ah, const unsigned short* __restrict__ Al, size_t sA,
    const unsigned short* __restrict__ Bh, const unsigned short* __restrict__ Bl, size_t sB,
    float* __restrict__ outF, unsigned short* __restrict__ outH,
    unsigned short* __restrict__ outL, size_t sO,
    const int* __restrict__ idxp, const float* __restrict__ ks)
{
    __shared__ __align__(16) unsigned short lds[2 * 32768];   // 2 bufs x {Ah,Al,Bh,Bl} x 8192

    const int tid  = threadIdx.x;
    const int lane = tid & 63, wave = tid >> 6;
    const int wr = wave >> 2, wc = wave & 3;        // 2 x 4 wave grid
    const int bz = blockIdx.z;
    const int m0 = blockIdx.y * 256, n0 = blockIdx.x * 256;
    const int r15 = lane & 15, kc = lane >> 4;

    const unsigned short* Abh = Ah + (size_t)bz * sA;
    const unsigned short* Abl = Al + (size_t)bz * sA;
    const unsigned short* Bbh = Bh + (size_t)bz * sB;
    const unsigned short* Bbl = Bl + (size_t)bz * sB;

    const int NKB = TOEP ? 8 * (blockIdx.x + 1) : 64;

    f32x4 acc[8][4];
    const f32x4 zf = {0.f, 0.f, 0.f, 0.f};
    #pragma unroll
    for (int i = 0; i < 8; ++i)
        #pragma unroll
        for (int j = 0; j < 4; ++j) acc[i][j] = zf;

    // prologue: stage block 0 into buf0, drain, barrier
    stage4(Abh, Abl, Bbh, Bbl, m0, n0, 0, lds, wave, lane);
    asm volatile("s_waitcnt vmcnt(0)" ::: "memory");
    __builtin_amdgcn_sched_barrier(0);
    __builtin_amdgcn_s_barrier();
    __builtin_amdgcn_sched_barrier(0);

    for (int t = 0; t < NKB; ++t) {
        const unsigned short* cur = lds + (t & 1) * 32768;
        unsigned short* nxt = lds + ((t + 1) & 1) * 32768;

        // ---------------- P0: read ah,bh; issue next-block stage; ah*bh ----------------
        s16x8 bh4[4], ah8[8], bl4[4], al8[8];
        #pragma unroll
        for (int nf = 0; nf < 4; ++nf)
            bh4[nf] = frag(cur + 16384, wc * 64 + nf * 16 + r15, kc);
        #pragma unroll
        for (int mf = 0; mf < 8; ++mf)
            ah8[mf] = frag(cur, wr * 128 + mf * 16 + r15, kc);
        if (t + 1 < NKB)
            stage4(Abh, Abl, Bbh, Bbl, m0, n0, (t + 1) * 32, nxt, wave, lane);
        __builtin_amdgcn_sched_barrier(0);
        __builtin_amdgcn_s_barrier();
        __builtin_amdgcn_sched_barrier(0);
        __builtin_amdgcn_s_setprio(1);
        #pragma unroll
        for (int mf = 0; mf < 8; ++mf)
            #pragma unroll
            for (int nf = 0; nf < 4; ++nf)
                acc[mf][nf] = __builtin_amdgcn_mfma_f32_16x16x32_bf16(ah8[mf], bh4[nf], acc[mf][nf], 0, 0, 0);
        __builtin_amdgcn_s_setprio(0);
        __builtin_amdgcn_sched_barrier(0);
        __builtin_amdgcn_s_barrier();
        __builtin_amdgcn_sched_barrier(0);

        // ---------------- P1: read bl; ah*bl ----------------
        #pragma unroll
        for (int nf = 0; nf < 4; ++nf)
            bl4[nf] = frag(cur + 24576, wc * 64 + nf * 16 + r15, kc);
        __builtin_amdgcn_sched_barrier(0);
        __builtin_amdgcn_s_barrier();
        __builtin_amdgcn_sched_barrier(0);
        __builtin_amdgcn_s_setprio(1);
        #pragma unroll
        for (int mf = 0; mf < 8; ++mf)
            #pragma unroll
            for (int nf = 0; nf < 4; ++nf)
                acc[mf][nf] = __builtin_amdgcn_mfma_f32_16x16x32_bf16(ah8[mf], bl4[nf], acc[mf][nf], 0, 0, 0);
        __builtin_amdgcn_s_setprio(0);
        __builtin_amdgcn_sched_barrier(0);
        __builtin_amdgcn_s_barrier();
        __builtin_amdgcn_sched_barrier(0);

        // ---------------- P2: read al; al*bh ----------------
        #pragma unroll
        for (int mf = 0; mf < 8; ++mf)
            al8[mf] = frag(cur + 8192, wr * 128 + mf * 16 + r15, kc);
        __builtin_amdgcn_sched_barrier(0);
        __builtin_amdgcn_s_barrier();
        __builtin_amdgcn_sched_barrier(0);
        __builtin_amdgcn_s_setprio(1);
        #pragma unroll
        for (int mf = 0; mf < 8; ++mf)
            #pragma unroll
            for (int nf = 0; nf < 4; ++nf)
                acc[mf][nf] = __builtin_amdgcn_mfma_f32_16x16x32_bf16(al8[mf], bh4[nf], acc[mf][nf], 0, 0, 0);
        __builtin_amdgcn_s_setprio(0);
        __builtin_amdgcn_sched_barrier(0);
        // boundary: next block's buffer must be fully landed (all waves), then barrier
        asm volatile("s_waitcnt vmcnt(0)" ::: "memory");
        __builtin_amdgcn_s_barrier();
        __builtin_amdgcn_sched_barrier(0);
    }

    // epilogue
    float csc[4];
    if constexpr (TOEP) {
        #pragma unroll
        for (int nf = 0; nf < 4; ++nf) {
            int gcol = n0 + wc * 64 + nf * 16 + r15;
            csc[nf] = ks[idxp[bz * L + gcol]];
        }
    }
    #pragma unroll
    for (int mf = 0; mf < 8; ++mf) {
        #pragma unroll
        for (int r = 0; r < 4; ++r) {
            int grow = m0 + wr * 128 + mf * 16 + kc * 4 + r;
            #pragma unroll
            for (int nf = 0; nf < 4; ++nf) {
                float v = acc[mf][nf][r];
                if constexpr (TOEP) v *= csc[nf];
                int gcol = n0 + wc * 64 + nf * 16 + r15;
                size_t o = (size_t)bz * sO + (size_t)grow * 2048 + gcol;
                if constexpr (OUTM == 0) {
                    outF[o] = v;
                } else {
                    unsigned short h = f2bf(v);
                    outH[o] = h;
                    outL[o] = f2bf(v - bf2f(h));
                }
            }
        }
    }
}

// ---------------- prep kernels ----------------

__global__ __launch_bounds__(256) void colsum_atomic(const float* __restrict__ W,
                                                     float* __restrict__ out) {
    int r0 = blockIdx.x * 8;
    int c = threadIdx.x;
    float s[8];
    #pragma unroll
    for (int i = 0; i < 8; ++i) s[i] = 0.f;
    for (int r = 0; r < 8; ++r) {
        const float* row = W + (size_t)(r0 + r) * V;
        #pragma unroll
        for (int i = 0; i < 8; ++i) s[i] += row[c + i * 256];
    }
    #pragma unroll
    for (int i = 0; i < 8; ++i) atomicAdd(&out[c + i * 256], s[i]);
}

__global__ void init_kernel(float* __restrict__ ks0, float* __restrict__ ks1) {
    int i = blockIdx.x * 256 + threadIdx.x;
    if (i < 2048) { ks0[i] = 0.f; ks1[i] = 0.f; }
}

// materialize split Toeplitz: TB[n][k] = (k<=n) ? v1[n-k] : 0; grid 2048 x 256 thr
__global__ __launch_bounds__(256) void tb_fill(const float* __restrict__ v1,
                                               unsigned short* __restrict__ TBh,
                                               unsigned short* __restrict__ TBl) {
    int n = blockIdx.x;
    int c0 = threadIdx.x * 8;
    s16x8 hv, lv;
    #pragma unroll
    for (int i = 0; i < 8; ++i) {
        int k = c0 + i;
        float f = (k <= n) ? v1[n - k] : 0.f;
        unsigned short h = f2bf(f);
        hv[i] = (short)h; lv[i] = (short)f2bf(f - bf2f(h));
    }
    *(s16x8*)&TBh[(size_t)n * 2048 + c0] = hv;
    *(s16x8*)&TBl[(size_t)n * 2048 + c0] = lv;
}

struct TDesc { const float* A; unsigned short *Th, *Tl; };

__global__ void transpose_split_multi(TDesc d0, TDesc d1, TDesc d2, TDesc d3, TDesc d4) {
    TDesc d;
    switch (blockIdx.z) {
        case 0: d = d0; break;
        case 1: d = d1; break;
        case 2: d = d2; break;
        case 3: d = d3; break;
        default: d = d4; break;
    }
    __shared__ float tile[32][33];
    int x = blockIdx.x * 32 + threadIdx.x;
    int y0 = blockIdx.y * 32;
    for (int r = threadIdx.y; r < 32; r += 8)
        tile[r][threadIdx.x] = d.A[(size_t)(y0 + r) * V + x];
    __syncthreads();
    int xo = blockIdx.y * 32 + threadIdx.x;
    int yo0 = blockIdx.x * 32;
    for (int r = threadIdx.y; r < 32; r += 8) {
        float f = tile[threadIdx.x][r];
        unsigned short h = f2bf(f);
        d.Th[(size_t)(yo0 + r) * V + xo] = h;
        d.Tl[(size_t)(yo0 + r) * V + xo] = f2bf(f - bf2f(h));
    }
}

__global__ __launch_bounds__(256) void split_kernel(const float* __restrict__ A,
                                                    unsigned short* __restrict__ H,
                                                    unsigned short* __restrict__ Lo,
                                                    int n4) {
    int i = blockIdx.x * 256 + threadIdx.x;
    if (i >= n4) return;
    float4 f = ((const float4*)A)[i];
    ushort4 h, l;
    h.x = f2bf(f.x); l.x = f2bf(f.x - bf2f(h.x));
    h.y = f2bf(f.y); l.y = f2bf(f.y - bf2f(h.y));
    h.z = f2bf(f.z); l.z = f2bf(f.z - bf2f(h.z));
    h.w = f2bf(f.w); l.w = f2bf(f.w - bf2f(h.w));
    ((ushort4*)H)[i] = h;
    ((ushort4*)Lo)[i] = l;
}

// ---------------- scatter kernels ----------------

__global__ __launch_bounds__(256) void scatterA_kernel(const int* __restrict__ idx,
                                                       const float* __restrict__ G0,
                                                       const float* __restrict__ ks0,
                                                       const float* __restrict__ v0,
                                                       unsigned short* __restrict__ Th,
                                                       unsigned short* __restrict__ Tl) {
    __shared__ float buck[8 * 2048];
    int tid = threadIdx.x;
    const float4 z4 = make_float4(0.f, 0.f, 0.f, 0.f);
    for (int i = tid; i < 8 * 2048 / 4; i += 256) ((float4*)buck)[i] = z4;
    __syncthreads();

    int b = blockIdx.y, q0 = blockIdx.x * 8;
    int qr = tid >> 5, kl = tid & 31;
    int q = q0 + qr;
    int iq = idx[b * L + q];
    float kq = ks0[iq];
    const float* Grow = G0 + (size_t)iq * V;
    for (int k = kl; k <= q; k += 32) {
        int ik = idx[b * L + k];
        float val = Grow[ik] + kq * v0[q - k];
        atomicAdd(&buck[qr * 2048 + ik], val);
    }
    __syncthreads();
    size_t base = ((size_t)b * L + q0) * V;
    for (int i = tid; i < 8 * 2048; i += 256) {
        float v = buck[i];
        unsigned short h = f2bf(v);
        Th[base + i] = h;
        Tl[base + i] = f2bf(v - bf2f(h));
    }
}

__global__ __launch_bounds__(256) void scatterC_kernel(const int* __restrict__ idx,
                                                       const float* __restrict__ T2t,
                                                       unsigned short* __restrict__ Th,
                                                       unsigned short* __restrict__ Tl) {
    __shared__ float buck[8 * 2048];
    int tid = threadIdx.x;
    const float4 z4 = make_float4(0.f, 0.f, 0.f, 0.f);
    for (int i = tid; i < 8 * 2048 / 4; i += 256) ((float4*)buck)[i] = z4;
    __syncthreads();

    int b = blockIdx.y, q0 = blockIdx.x * 8;
    int qr = tid >> 5, kl = tid & 31;
    int q = q0 + qr;
    int iq = idx[b * L + q];
    const float* Trow = T2t + ((size_t)b * V + iq) * L;
    for (int k = kl; k <= q; k += 32) {
        int ik = idx[b * L + k];
        atomicAdd(&buck[qr * 2048 + ik], Trow[k]);
    }
    __syncthreads();
    size_t base = ((size_t)b * L + q0) * V;
    for (int i = tid; i < 8 * 2048; i += 256) {
        float v = buck[i];
        unsigned short h = f2bf(v);
        Th[base + i] = h;
        Tl[base + i] = f2bf(v - bf2f(h));
    }
}

// ---------------- launcher ----------------

extern "C" void kernel_launch(void* const* d_in, const int* in_sizes, int n_in,
                              void* d_out, int out_size, void* d_ws, size_t ws_size,
                              hipStream_t stream) {
    (void)in_sizes; (void)n_in; (void)out_size; (void)ws_size;
    const int*   idx = (const int*)d_in[0];
    const float* Wq0 = (const float*)d_in[1];
    const float* Wk0 = (const float*)d_in[2];
    const float* Wv0 = (const float*)d_in[3];
    const float* Wk1 = (const float*)d_in[4];
    const float* Wv1 = (const float*)d_in[5];
    const float* Wq2 = (const float*)d_in[6];
    const float* Wk2 = (const float*)d_in[7];
    const float* Wv2 = (const float*)d_in[8];
    const float* v0  = (const float*)d_in[9];
    const float* v1  = (const float*)d_in[10];
    float* out = (float*)d_out;

    char* W = (char*)d_ws;
    const size_t MiB = 1024 * 1024;

    // A0 region [0, 64 MiB): TA pair, later T2t f32. PPT pair parked at its head early.
    unsigned short* TAh = (unsigned short*)W;
    unsigned short* TAl = TAh + BLV;
    float*          T2f = (float*)W;
    unsigned short* PPT = (unsigned short*)W;
    // AU region [64, 128 MiB): Y-slots early, then U pair, then TC pair.
    unsigned short* Y1 = (unsigned short*)(W + 64 * MiB);   // Wv0T pair
    unsigned short* Y2 = (unsigned short*)(W + 80 * MiB);   // Wv1 split pair
    float*          Gf = (float*)(W + 96 * MiB);            // G0 f32
    unsigned short* Y4 = (unsigned short*)(W + 112 * MiB);  // M pair
    unsigned short* Uh = (unsigned short*)(W + 64 * MiB);
    unsigned short* Ul = Uh + BLV;
    unsigned short* TCh = Uh;
    unsigned short* TCl = Ul;
    // X slots [128, 192 MiB)
    unsigned short* X1 = (unsigned short*)(W + 128 * MiB);  // Wq0T, then R pair
    unsigned short* X2 = (unsigned short*)(W + 144 * MiB);  // Wk0T, then Wv2 split
    unsigned short* X3 = (unsigned short*)(W + 160 * MiB);  // Wq2T pair, then TB pair
    unsigned short* X4 = (unsigned short*)(W + 176 * MiB);  // Wk2T pair
    unsigned short* TBh = X3;
    unsigned short* TBl = X3 + VV;
    float* ks0 = (float*)(W + 192 * MiB);
    float* ks1 = (float*)(W + 192 * MiB + 16 * 1024);

    dim3 blk(256);

    // prep: transposes/splits, column sums
    {
        TDesc t0{Wq0, X1, X1 + VV}, t1{Wk0, X2, X2 + VV}, t2{Wq2, X3, X3 + VV},
              t3{Wk2, X4, X4 + VV}, t4{Wv0, Y1, Y1 + VV};
        transpose_split_multi<<<dim3(64, 64, 5), dim3(32, 8), 0, stream>>>(t0, t1, t2, t3, t4);
    }
    split_kernel<<<dim3((int)(VV / 4 / 256)), blk, 0, stream>>>(Wv1, Y2, Y2 + VV, (int)(VV / 4));
    init_kernel<<<dim3(8), blk, 0, stream>>>(ks0, ks1);
    colsum_atomic<<<dim3(256), blk, 0, stream>>>(Wk0, ks0);
    colsum_atomic<<<dim3(256), blk, 0, stream>>>(Wk1, ks1);

    // fused precomputes: G0 = Wq0^T Wk0 (f32), M = Wq2^T Wk2 (pair), PPT = Wv0^T Wv1^Trows (pair)
    {
        GemmDesc dG{X1, X1 + VV, X2, X2 + VV, Gf, nullptr, nullptr};
        GemmDesc dM{X3, X3 + VV, X4, X4 + VV, nullptr, Y4, Y4 + VV};
        GemmDesc dP{Y1, Y1 + VV, Y2, Y2 + VV, nullptr, PPT, PPT + VV};
        gemm_pre3<<<dim3(16, 16, 3), blk, 0, stream>>>(dG, dM, dP);
    }
    // TB materialization (X3's Wq2T is dead after pre3)
    tb_fill<<<dim3(2048), blk, 0, stream>>>(v1, TBh, TBl);
    // R = M . PPT -> X1 (pair)
    {
        GemmDesc dR{Y4, Y4 + VV, PPT, PPT + VV, nullptr, X1, X1 + VV};
        gemm_pre3<<<dim3(16, 16, 1), blk, 0, stream>>>(dR, dR, dR);
    }

    // scatter A -> TA pair (overwrites PPT region)
    scatterA_kernel<<<dim3(L / 8, NB), blk, 0, stream>>>(idx, Gf, ks0, v0, TAh, TAl);

    // U[b] = R . TA[b]^T -> pair in AU
    gemm_big<1, false><<<dim3(8, 8, NB), dim3(512), 0, stream>>>(
        X1, X1 + VV, 0, TAh, TAl, LV,
        nullptr, Uh, Ul, LV, nullptr, nullptr);

    // T2t[b][v,q] = ks1[iq_q] * sum_{k<=q} v1[q-k] * U[b][v,k] -> f32 in A0
    gemm_big<0, true><<<dim3(8, 8, NB), dim3(512), 0, stream>>>(
        Uh, Ul, LV, TBh, TBl, 0,
        T2f, nullptr, nullptr, LV, idx, ks1);

    // scatter C -> TC pair (overwrites U)
    scatterC_kernel<<<dim3(L / 8, NB), blk, 0, stream>>>(idx, T2f, TCh, TCl);

    // split Wv2 -> X2
    split_kernel<<<dim3((int)(VV / 4 / 256)), blk, 0, stream>>>(Wv2, X2, X2 + VV, (int)(VV / 4));

    // logits = TC . Wv2rows -> d_out (M = 8192)
    gemm_big<0, false><<<dim3(8, 32, 1), dim3(512), 0, stream>>>(
        TCh, TCl, 0, X2, X2 + VV, 0,
        out, nullptr, nullptr, 0, nullptr, nullptr);
}

// Round 7
// 647.593 us; speedup vs baseline: 9.4851x; 1.4961x over previous
//
#include <hip/hip_runtime.h>

typedef float f32x4 __attribute__((ext_vector_type(4)));
typedef short s16x8 __attribute__((ext_vector_type(8)));

constexpr int L = 2048;
constexpr int V = 2048;
constexpr int NB = 4;
constexpr size_t VV  = (size_t)V * V;      // 4194304
constexpr size_t BLV = (size_t)NB * L * V; // 16777216
constexpr size_t LV  = (size_t)L * V;      // 4194304

// ---------- bf16 helpers (bit-level, RNE) ----------
__device__ __forceinline__ unsigned short f2bf(float f) {
    unsigned u = __float_as_uint(f);
    u = (u + 0x7FFFu + ((u >> 16) & 1u)) >> 16;
    return (unsigned short)u;
}
__device__ __forceinline__ float bf2f(unsigned short s) {
    return __uint_as_float(((unsigned)s) << 16);
}

// ---------- async global->LDS 16B ----------
__device__ __forceinline__ void gload16(const unsigned short* g, unsigned short* l) {
    auto gp = (const __attribute__((address_space(1))) unsigned int*)g;
    auto lp = (__attribute__((address_space(3))) unsigned int*)l;
    __builtin_amdgcn_global_load_lds(gp, lp, 16, 0, 0);
}

// ================= 128x128 split-fused kernel (precomputes; proven) =================

__device__ __forceinline__ void stage_tile(const unsigned short* g0, int r0, int k0,
                                           unsigned short* lds, int wave, int lane) {
    #pragma unroll
    for (int i = 0; i < 2; ++i) {
        int r  = i * 64 + wave * 16 + (lane >> 2);
        int cs = (lane & 3) ^ ((r >> 1) & 3);
        const unsigned short* g = g0 + (size_t)(r0 + r) * 2048 + k0 + cs * 8;
        gload16(g, lds + (size_t)(i * 256 + wave * 64) * 8);
    }
}

__device__ __forceinline__ void frag_mfma(const unsigned short* AsH, const unsigned short* AsL,
                                          const unsigned short* BsH, const unsigned short* BsL,
                                          f32x4 (&acc)[4][4], int lane, int wr, int wc) {
    const int r15 = lane & 15, kc = lane >> 4;
    s16x8 bh[4], blo[4];
    #pragma unroll
    for (int ns = 0; ns < 4; ++ns) {
        int rrow = wc * 64 + ns * 16 + r15;
        int ch = kc ^ ((rrow >> 1) & 3);
        bh[ns]  = *(const s16x8*)&BsH[rrow * 32 + ch * 8];
        blo[ns] = *(const s16x8*)&BsL[rrow * 32 + ch * 8];
    }
    #pragma unroll
    for (int ms = 0; ms < 4; ++ms) {
        int arow = wr * 64 + ms * 16 + r15;
        int ch = kc ^ ((arow >> 1) & 3);
        s16x8 ah = *(const s16x8*)&AsH[arow * 32 + ch * 8];
        s16x8 al = *(const s16x8*)&AsL[arow * 32 + ch * 8];
        #pragma unroll
        for (int ns = 0; ns < 4; ++ns) {
            acc[ms][ns] = __builtin_amdgcn_mfma_f32_16x16x32_bf16(ah, bh[ns],  acc[ms][ns], 0, 0, 0);
            acc[ms][ns] = __builtin_amdgcn_mfma_f32_16x16x32_bf16(ah, blo[ns], acc[ms][ns], 0, 0, 0);
            acc[ms][ns] = __builtin_amdgcn_mfma_f32_16x16x32_bf16(al, bh[ns],  acc[ms][ns], 0, 0, 0);
        }
    }
}

struct GemmDesc {
    const unsigned short *Ah, *Al, *Bh, *Bl;
    float* oF;                  // if set: f32 out, else split pair
    unsigned short *oH, *oL;
};

__global__ __launch_bounds__(256, 2) void gemm_pre3(GemmDesc d0, GemmDesc d1, GemmDesc d2) {
    GemmDesc d = (blockIdx.z == 0) ? d0 : (blockIdx.z == 1) ? d1 : d2;
    __shared__ __align__(16) unsigned short AsH[128 * 32], AsL[128 * 32];
    __shared__ __align__(16) unsigned short BsH[128 * 32], BsL[128 * 32];
    const int tid  = threadIdx.x;
    const int lane = tid & 63, wave = tid >> 6;
    const int wr = wave >> 1, wc = wave & 1;
    const int m0 = blockIdx.y * 128, n0 = blockIdx.x * 128;
    const int r15 = lane & 15;

    f32x4 acc[4][4];
    const f32x4 zf = {0.f, 0.f, 0.f, 0.f};
    #pragma unroll
    for (int i = 0; i < 4; ++i)
        #pragma unroll
        for (int j = 0; j < 4; ++j) acc[i][j] = zf;

    for (int kt = 0; kt < 64; ++kt) {
        const int k0 = kt * 32;
        stage_tile(d.Bh, n0, k0, BsH, wave, lane);
        stage_tile(d.Bl, n0, k0, BsL, wave, lane);
        stage_tile(d.Ah, m0, k0, AsH, wave, lane);
        stage_tile(d.Al, m0, k0, AsL, wave, lane);
        __syncthreads();
        frag_mfma(AsH, AsL, BsH, BsL, acc, lane, wr, wc);
        __syncthreads();
    }

    const bool isF = (d.oF != nullptr);
    #pragma unroll
    for (int ms = 0; ms < 4; ++ms) {
        #pragma unroll
        for (int r = 0; r < 4; ++r) {
            int grow = m0 + wr * 64 + ms * 16 + (lane >> 4) * 4 + r;
            #pragma unroll
            for (int ns = 0; ns < 4; ++ns) {
                float v = acc[ms][ns][r];
                int gcol = n0 + wc * 64 + ns * 16 + r15;
                size_t o = (size_t)grow * 2048 + gcol;
                if (isF) {
                    d.oF[o] = v;
                } else {
                    unsigned short h = f2bf(v);
                    d.oH[o] = h;
                    d.oL[o] = f2bf(v - bf2f(h));
                }
            }
        }
    }
}

// ================= 256x256 plain-bf16 pipelined kernel (data GEMMs) =================
// OUT[m][n] = sum_k A[m][k]*Bt[n][k], K = 2048. Per 32-K block: stage A,B (32 KB),
// 2 phases x {ds_read subtile; prefetch issue; barrier; setprio 16 MFMA; barrier}.
// Depth-3 prefetch in 4 rotating 32KB buffers; counted vmcnt ladder 8/4/0 (never
// drained mid-loop). TOEP: causal cutoff keyed to n-tile, m/n block-swap for
// causal load balance; epilogue col-scale ks[idx[bz*L+col]].

__device__ __forceinline__ void stage2(const unsigned short* A, const unsigned short* B,
                                       int m0, int n0, int k0, unsigned short* buf,
                                       int wave, int lane) {
    int rl = lane >> 2, csl = lane & 3;
    #pragma unroll
    for (int h = 0; h < 2; ++h) {
        int rr = wave * 32 + h * 16;               // LDS row base (wave-uniform)
        int row = rr + rl;
        int ch = csl ^ ((row >> 1) & 3);
        size_t ga = (size_t)row * 2048 + k0 + ch * 8;
        gload16(A + (size_t)m0 * 2048 + ga, buf + rr * 32);
        gload16(B + (size_t)n0 * 2048 + ga, buf + 8192 + rr * 32);
    }
}

__device__ __forceinline__ s16x8 frag(const unsigned short* arr, int row, int kc) {
    int cs = kc ^ ((row >> 1) & 3);
    return *(const s16x8*)&arr[row * 32 + cs * 8];
}

template<int OUTM, bool TOEP>      // OUTM: 0 = f32 out, 1 = bf16 out
__global__ __launch_bounds__(512, 2) void gemm_big(
    const unsigned short* __restrict__ A, size_t sA,
    const unsigned short* __restrict__ B, size_t sB,
    float* __restrict__ outF, unsigned short* __restrict__ outH, size_t sO,
    const int* __restrict__ idxp, const float* __restrict__ ks)
{
    __shared__ __align__(16) unsigned short lds[4 * 16384];   // 4 bufs x (A 8192 + B 8192)

    const int tid  = threadIdx.x;
    const int lane = tid & 63, wave = tid >> 6;
    const int wr = wave >> 2, wc = wave & 3;        // 2 x 4 wave grid
    const int bz = blockIdx.z;
    int bx = blockIdx.x, by = blockIdx.y;
    if constexpr (TOEP) { int tswap = bx; bx = by; by = tswap; }  // causal balance
    const int m0 = by * 256, n0 = bx * 256;
    const int r15 = lane & 15, kc = lane >> 4;

    const unsigned short* Ab = A + (size_t)bz * sA;
    const unsigned short* Bb = B + (size_t)bz * sB;

    const int NKB = TOEP ? 8 * (bx + 1) : 64;

    f32x4 acc[8][4];
    const f32x4 zf = {0.f, 0.f, 0.f, 0.f};
    #pragma unroll
    for (int i = 0; i < 8; ++i)
        #pragma unroll
        for (int j = 0; j < 4; ++j) acc[i][j] = zf;

    // prologue: stage blocks 0..2, wait block 0 (vmcnt 8 = 2 tiles in flight)
    stage2(Ab, Bb, m0, n0, 0,  lds,         wave, lane);
    stage2(Ab, Bb, m0, n0, 32, lds + 16384, wave, lane);
    stage2(Ab, Bb, m0, n0, 64, lds + 32768, wave, lane);
    asm volatile("s_waitcnt vmcnt(8)" ::: "memory");
    __builtin_amdgcn_sched_barrier(0);
    __builtin_amdgcn_s_barrier();
    __builtin_amdgcn_sched_barrier(0);

    for (int t = 0; t < NKB; ++t) {
        const unsigned short* cur = lds + (t & 3) * 16384;
        unsigned short* nxt = lds + ((t + 3) & 3) * 16384;
        const int rem = NKB - 1 - t;

        // ---------------- P0: read B-frags + A-frags 0-3; issue prefetch ----------------
        s16x8 bfr[4], afr[4];
        #pragma unroll
        for (int nf = 0; nf < 4; ++nf)
            bfr[nf] = frag(cur + 8192, wc * 64 + nf * 16 + r15, kc);
        #pragma unroll
        for (int mf = 0; mf < 4; ++mf)
            afr[mf] = frag(cur, wr * 128 + mf * 16 + r15, kc);
        if (rem >= 3)
            stage2(Ab, Bb, m0, n0, (t + 3) * 32, nxt, wave, lane);
        __builtin_amdgcn_sched_barrier(0);
        __builtin_amdgcn_s_barrier();
        __builtin_amdgcn_sched_barrier(0);
        __builtin_amdgcn_s_setprio(1);
        #pragma unroll
        for (int mf = 0; mf < 4; ++mf)
            #pragma unroll
            for (int nf = 0; nf < 4; ++nf)
                acc[mf][nf] = __builtin_amdgcn_mfma_f32_16x16x32_bf16(afr[mf], bfr[nf], acc[mf][nf], 0, 0, 0);
        __builtin_amdgcn_s_setprio(0);
        __builtin_amdgcn_sched_barrier(0);
        __builtin_amdgcn_s_barrier();
        __builtin_amdgcn_sched_barrier(0);

        // ---------------- P1: read A-frags 4-7; counted vmcnt at close ----------------
        s16x8 afr2[4];
        #pragma unroll
        for (int mf = 0; mf < 4; ++mf)
            afr2[mf] = frag(cur, wr * 128 + (mf + 4) * 16 + r15, kc);
        __builtin_amdgcn_sched_barrier(0);
        __builtin_amdgcn_s_barrier();
        __builtin_amdgcn_sched_barrier(0);
        __builtin_amdgcn_s_setprio(1);
        #pragma unroll
        for (int mf = 0; mf < 4; ++mf)
            #pragma unroll
            for (int nf = 0; nf < 4; ++nf)
                acc[mf + 4][nf] = __builtin_amdgcn_mfma_f32_16x16x32_bf16(afr2[mf], bfr[nf], acc[mf + 4][nf], 0, 0, 0);
        __builtin_amdgcn_s_setprio(0);
        __builtin_amdgcn_sched_barrier(0);
        // closing: ensure block t+1 landed; keep 2 blocks in flight
        if (rem >= 3)      { asm volatile("s_waitcnt vmcnt(8)" ::: "memory"); }
        else if (rem == 2) { asm volatile("s_waitcnt vmcnt(4)" ::: "memory"); }
        else if (rem == 1) { asm volatile("s_waitcnt vmcnt(0)" ::: "memory"); }
        __builtin_amdgcn_s_barrier();
        __builtin_amdgcn_sched_barrier(0);
    }

    // epilogue
    float csc[4];
    if constexpr (TOEP) {
        #pragma unroll
        for (int nf = 0; nf < 4; ++nf) {
            int gcol = n0 + wc * 64 + nf * 16 + r15;
            csc[nf] = ks[idxp[bz * L + gcol]];
        }
    }
    #pragma unroll
    for (int mf = 0; mf < 8; ++mf) {
        #pragma unroll
        for (int r = 0; r < 4; ++r) {
            int grow = m0 + wr * 128 + mf * 16 + kc * 4 + r;
            #pragma unroll
            for (int nf = 0; nf < 4; ++nf) {
                float v = acc[mf][nf][r];
                if constexpr (TOEP) v *= csc[nf];
                int gcol = n0 + wc * 64 + nf * 16 + r15;
                size_t o = (size_t)bz * sO + (size_t)grow * 2048 + gcol;
                if constexpr (OUTM == 0) outF[o] = v;
                else                     outH[o] = f2bf(v);
            }
        }
    }
}

// ---------------- prep kernels ----------------

__global__ __launch_bounds__(256) void colsum_atomic(const float* __restrict__ W,
                                                     float* __restrict__ out) {
    int r0 = blockIdx.x * 8;
    int c = threadIdx.x;
    float s[8];
    #pragma unroll
    for (int i = 0; i < 8; ++i) s[i] = 0.f;
    for (int r = 0; r < 8; ++r) {
        const float* row = W + (size_t)(r0 + r) * V;
        #pragma unroll
        for (int i = 0; i < 8; ++i) s[i] += row[c + i * 256];
    }
    #pragma unroll
    for (int i = 0; i < 8; ++i) atomicAdd(&out[c + i * 256], s[i]);
}

__global__ void init_kernel(float* __restrict__ ks0, float* __restrict__ ks1) {
    int i = blockIdx.x * 256 + threadIdx.x;
    if (i < 2048) { ks0[i] = 0.f; ks1[i] = 0.f; }
}

// materialize Toeplitz: TB[n][k] = (k<=n) ? v1[n-k] : 0 (bf16); grid 2048 x 256 thr
__global__ __launch_bounds__(256) void tb_fill(const float* __restrict__ v1,
                                               unsigned short* __restrict__ TBh) {
    int n = blockIdx.x;
    int c0 = threadIdx.x * 8;
    s16x8 hv;
    #pragma unroll
    for (int i = 0; i < 8; ++i) {
        int k = c0 + i;
        float f = (k <= n) ? v1[n - k] : 0.f;
        hv[i] = (short)f2bf(f);
    }
    *(s16x8*)&TBh[(size_t)n * 2048 + c0] = hv;
}

struct TDesc { const float* A; unsigned short *Th, *Tl; };

__global__ void transpose_split_multi(TDesc d0, TDesc d1, TDesc d2, TDesc d3, TDesc d4) {
    TDesc d;
    switch (blockIdx.z) {
        case 0: d = d0; break;
        case 1: d = d1; break;
        case 2: d = d2; break;
        case 3: d = d3; break;
        default: d = d4; break;
    }
    __shared__ float tile[32][33];
    int x = blockIdx.x * 32 + threadIdx.x;
    int y0 = blockIdx.y * 32;
    for (int r = threadIdx.y; r < 32; r += 8)
        tile[r][threadIdx.x] = d.A[(size_t)(y0 + r) * V + x];
    __syncthreads();
    int xo = blockIdx.y * 32 + threadIdx.x;
    int yo0 = blockIdx.x * 32;
    for (int r = threadIdx.y; r < 32; r += 8) {
        float f = tile[threadIdx.x][r];
        unsigned short h = f2bf(f);
        d.Th[(size_t)(yo0 + r) * V + xo] = h;
        d.Tl[(size_t)(yo0 + r) * V + xo] = f2bf(f - bf2f(h));
    }
}

// split (Lo != null) or plain cast (Lo == null)
__global__ __launch_bounds__(256) void split_kernel(const float* __restrict__ A,
                                                    unsigned short* __restrict__ H,
                                                    unsigned short* __restrict__ Lo,
                                                    int n4) {
    int i = blockIdx.x * 256 + threadIdx.x;
    if (i >= n4) return;
    float4 f = ((const float4*)A)[i];
    ushort4 h, l;
    h.x = f2bf(f.x); l.x = f2bf(f.x - bf2f(h.x));
    h.y = f2bf(f.y); l.y = f2bf(f.y - bf2f(h.y));
    h.z = f2bf(f.z); l.z = f2bf(f.z - bf2f(h.z));
    h.w = f2bf(f.w); l.w = f2bf(f.w - bf2f(h.w));
    ((ushort4*)H)[i] = h;
    if (Lo) ((ushort4*)Lo)[i] = l;
}

// ---------------- scatter kernels (bf16 out) ----------------

__global__ __launch_bounds__(256) void scatterA_kernel(const int* __restrict__ idx,
                                                       const float* __restrict__ G0,
                                                       const float* __restrict__ ks0,
                                                       const float* __restrict__ v0,
                                                       unsigned short* __restrict__ Th) {
    __shared__ float buck[8 * 2048];
    int tid = threadIdx.x;
    const float4 z4 = make_float4(0.f, 0.f, 0.f, 0.f);
    for (int i = tid; i < 8 * 2048 / 4; i += 256) ((float4*)buck)[i] = z4;
    __syncthreads();

    int b = blockIdx.y, q0 = blockIdx.x * 8;
    int qr = tid >> 5, kl = tid & 31;
    int q = q0 + qr;
    int iq = idx[b * L + q];
    float kq = ks0[iq];
    const float* Grow = G0 + (size_t)iq * V;
    for (int k = kl; k <= q; k += 32) {
        int ik = idx[b * L + k];
        float val = Grow[ik] + kq * v0[q - k];
        atomicAdd(&buck[qr * 2048 + ik], val);
    }
    __syncthreads();
    size_t base = ((size_t)b * L + q0) * V;
    for (int i = tid; i < 8 * 2048; i += 256)
        Th[base + i] = f2bf(buck[i]);
}

__global__ __launch_bounds__(256) void scatterC_kernel(const int* __restrict__ idx,
                                                       const float* __restrict__ T2t,
                                                       unsigned short* __restrict__ Th) {
    __shared__ float buck[8 * 2048];
    int tid = threadIdx.x;
    const float4 z4 = make_float4(0.f, 0.f, 0.f, 0.f);
    for (int i = tid; i < 8 * 2048 / 4; i += 256) ((float4*)buck)[i] = z4;
    __syncthreads();

    int b = blockIdx.y, q0 = blockIdx.x * 8;
    int qr = tid >> 5, kl = tid & 31;
    int q = q0 + qr;
    int iq = idx[b * L + q];
    const float* Trow = T2t + ((size_t)b * V + iq) * L;
    for (int k = kl; k <= q; k += 32) {
        int ik = idx[b * L + k];
        atomicAdd(&buck[qr * 2048 + ik], Trow[k]);
    }
    __syncthreads();
    size_t base = ((size_t)b * L + q0) * V;
    for (int i = tid; i < 8 * 2048; i += 256)
        Th[base + i] = f2bf(buck[i]);
}

// ---------------- launcher ----------------

extern "C" void kernel_launch(void* const* d_in, const int* in_sizes, int n_in,
                              void* d_out, int out_size, void* d_ws, size_t ws_size,
                              hipStream_t stream) {
    (void)in_sizes; (void)n_in; (void)out_size; (void)ws_size;
    const int*   idx = (const int*)d_in[0];
    const float* Wq0 = (const float*)d_in[1];
    const float* Wk0 = (const float*)d_in[2];
    const float* Wv0 = (const float*)d_in[3];
    const float* Wk1 = (const float*)d_in[4];
    const float* Wv1 = (const float*)d_in[5];
    const float* Wq2 = (const float*)d_in[6];
    const float* Wk2 = (const float*)d_in[7];
    const float* Wv2 = (const float*)d_in[8];
    const float* v0  = (const float*)d_in[9];
    const float* v1  = (const float*)d_in[10];
    float* out = (float*)d_out;

    char* W = (char*)d_ws;
    const size_t MiB = 1024 * 1024;

    // A0 region [0, 64 MiB): TAh (bf16, 32 MiB), later T2t f32 (64 MiB). PPT pair early.
    unsigned short* TAh = (unsigned short*)W;
    float*          T2f = (float*)W;
    unsigned short* PPT = (unsigned short*)W;
    // AU region [64, 128 MiB): Y-slots early, then Uh (bf16), then TCh (bf16).
    unsigned short* Y1 = (unsigned short*)(W + 64 * MiB);   // Wv0T pair
    unsigned short* Y2 = (unsigned short*)(W + 80 * MiB);   // Wv1 split pair
    float*          Gf = (float*)(W + 96 * MiB);            // G0 f32
    unsigned short* Y4 = (unsigned short*)(W + 112 * MiB);  // M pair
    unsigned short* Uh  = (unsigned short*)(W + 64 * MiB);
    unsigned short* TCh = Uh;
    // X slots [128, 192 MiB)
    unsigned short* X1 = (unsigned short*)(W + 128 * MiB);  // Wq0T, then R pair (H used)
    unsigned short* X2 = (unsigned short*)(W + 144 * MiB);  // Wk0T, then Wv2 bf16
    unsigned short* X3 = (unsigned short*)(W + 160 * MiB);  // Wq2T pair, then TBh
    unsigned short* X4 = (unsigned short*)(W + 176 * MiB);  // Wk2T pair
    unsigned short* TBh = X3;
    float* ks0 = (float*)(W + 192 * MiB);
    float* ks1 = (float*)(W + 192 * MiB + 16 * 1024);

    dim3 blk(256);

    // prep: transposes/splits, column sums
    {
        TDesc t0{Wq0, X1, X1 + VV}, t1{Wk0, X2, X2 + VV}, t2{Wq2, X3, X3 + VV},
              t3{Wk2, X4, X4 + VV}, t4{Wv0, Y1, Y1 + VV};
        transpose_split_multi<<<dim3(64, 64, 5), dim3(32, 8), 0, stream>>>(t0, t1, t2, t3, t4);
    }
    split_kernel<<<dim3((int)(VV / 4 / 256)), blk, 0, stream>>>(Wv1, Y2, Y2 + VV, (int)(VV / 4));
    init_kernel<<<dim3(8), blk, 0, stream>>>(ks0, ks1);
    colsum_atomic<<<dim3(256), blk, 0, stream>>>(Wk0, ks0);
    colsum_atomic<<<dim3(256), blk, 0, stream>>>(Wk1, ks1);

    // fused precomputes: G0 = Wq0^T Wk0 (f32), M = Wq2^T Wk2 (pair), PPT (pair)
    {
        GemmDesc dG{X1, X1 + VV, X2, X2 + VV, Gf, nullptr, nullptr};
        GemmDesc dM{X3, X3 + VV, X4, X4 + VV, nullptr, Y4, Y4 + VV};
        GemmDesc dP{Y1, Y1 + VV, Y2, Y2 + VV, nullptr, PPT, PPT + VV};
        gemm_pre3<<<dim3(16, 16, 3), blk, 0, stream>>>(dG, dM, dP);
    }
    // TB materialization (X3's Wq2T dead after pre3)
    tb_fill<<<dim3(2048), blk, 0, stream>>>(v1, TBh);
    // R = M . PPT -> X1 pair (split for precision; only H consumed downstream)
    {
        GemmDesc dR{Y4, Y4 + VV, PPT, PPT + VV, nullptr, X1, X1 + VV};
        gemm_pre3<<<dim3(16, 16, 1), blk, 0, stream>>>(dR, dR, dR);
    }

    // scatter A -> TAh (overwrites PPT region)
    scatterA_kernel<<<dim3(L / 8, NB), blk, 0, stream>>>(idx, Gf, ks0, v0, TAh);

    // U[b] = R . TA[b]^T -> bf16 Uh
    gemm_big<1, false><<<dim3(8, 8, NB), dim3(512), 0, stream>>>(
        X1, 0, TAh, LV, nullptr, Uh, LV, nullptr, nullptr);

    // T2t[b][v,q] = ks1[iq_q] * sum_{k<=q} v1[q-k] * U[b][v,k] -> f32 in A0
    gemm_big<0, true><<<dim3(8, 8, NB), dim3(512), 0, stream>>>(
        Uh, LV, TBh, 0, T2f, nullptr, LV, idx, ks1);

    // scatter C -> TCh (overwrites U)
    scatterC_kernel<<<dim3(L / 8, NB), blk, 0, stream>>>(idx, T2f, TCh);

    // Wv2 -> bf16 X2
    split_kernel<<<dim3((int)(VV / 4 / 256)), blk, 0, stream>>>(Wv2, X2, nullptr, (int)(VV / 4));

    // logits = TC . Wv2rows -> d_out (M = 8192)
    gemm_big<0, false><<<dim3(8, 32, 1), dim3(512), 0, stream>>>(
        TCh, 0, X2, 0, out, nullptr, 0, nullptr, nullptr);
}

// Round 8
// 536.073 us; speedup vs baseline: 11.4583x; 1.2080x over previous
//
#include <hip/hip_runtime.h>

typedef float f32x4 __attribute__((ext_vector_type(4)));
typedef short s16x8 __attribute__((ext_vector_type(8)));

constexpr int L = 2048;
constexpr int V = 2048;
constexpr int NB = 4;
constexpr size_t VV  = (size_t)V * V;      // 4194304
constexpr size_t BLV = (size_t)NB * L * V; // 16777216
constexpr size_t LV  = (size_t)L * V;      // 4194304

// ---------- bf16 helpers (bit-level, RNE) ----------
__device__ __forceinline__ unsigned short f2bf(float f) {
    unsigned u = __float_as_uint(f);
    u = (u + 0x7FFFu + ((u >> 16) & 1u)) >> 16;
    return (unsigned short)u;
}
__device__ __forceinline__ float bf2f(unsigned short s) {
    return __uint_as_float(((unsigned)s) << 16);
}

// ---------- async global->LDS 16B ----------
__device__ __forceinline__ void gload16(const unsigned short* g, unsigned short* l) {
    auto gp = (const __attribute__((address_space(1))) unsigned int*)g;
    auto lp = (__attribute__((address_space(3))) unsigned int*)l;
    __builtin_amdgcn_global_load_lds(gp, lp, 16, 0, 0);
}

// ================= 256x256 bf16 pipelined GEMM machinery =================
// OUT[m][n] = sum_k A[m][k]*Bt[n][k], K = 2048. Per 32-K block: stage A,B (32 KB),
// 2 phases x {ds_read subtile; prefetch issue; barrier; setprio 16 MFMA; barrier}.
// Depth-3 prefetch in 4 rotating 32KB buffers; counted vmcnt ladder 8/4/0.

__device__ __forceinline__ void stage2(const unsigned short* A, const unsigned short* B,
                                       int m0, int n0, int k0, unsigned short* buf,
                                       int wave, int lane) {
    int rl = lane >> 2, csl = lane & 3;
    #pragma unroll
    for (int h = 0; h < 2; ++h) {
        int rr = wave * 32 + h * 16;               // LDS row base (wave-uniform)
        int row = rr + rl;
        int ch = csl ^ ((row >> 1) & 3);
        size_t ga = (size_t)row * 2048 + k0 + ch * 8;
        gload16(A + (size_t)m0 * 2048 + ga, buf + rr * 32);
        gload16(B + (size_t)n0 * 2048 + ga, buf + 8192 + rr * 32);
    }
}

__device__ __forceinline__ s16x8 frag(const unsigned short* arr, int row, int kc) {
    int cs = kc ^ ((row >> 1) & 3);
    return *(const s16x8*)&arr[row * 32 + cs * 8];
}

// ---- K-loop body shared by both kernels (macro-free via inline fn) ----
struct KLoopOut { f32x4 acc[8][4]; };

__device__ __forceinline__ void kloop(const unsigned short* Ab, const unsigned short* Bb,
                                      int m0, int n0, int NKB, unsigned short* lds,
                                      int wave, int lane, int wr, int wc,
                                      f32x4 (&acc)[8][4]) {
    const int r15 = lane & 15, kc = lane >> 4;

    // prologue: stage blocks 0..2, wait block 0 (vmcnt 8 = 2 tiles in flight)
    stage2(Ab, Bb, m0, n0, 0,  lds,         wave, lane);
    stage2(Ab, Bb, m0, n0, 32, lds + 16384, wave, lane);
    stage2(Ab, Bb, m0, n0, 64, lds + 32768, wave, lane);
    asm volatile("s_waitcnt vmcnt(8)" ::: "memory");
    __builtin_amdgcn_sched_barrier(0);
    __builtin_amdgcn_s_barrier();
    __builtin_amdgcn_sched_barrier(0);

    for (int t = 0; t < NKB; ++t) {
        const unsigned short* cur = lds + (t & 3) * 16384;
        unsigned short* nxt = lds + ((t + 3) & 3) * 16384;
        const int rem = NKB - 1 - t;

        // ---- P0: read B-frags + A-frags 0-3; issue prefetch ----
        s16x8 bfr[4], afr[4];
        #pragma unroll
        for (int nf = 0; nf < 4; ++nf)
            bfr[nf] = frag(cur + 8192, wc * 64 + nf * 16 + r15, kc);
        #pragma unroll
        for (int mf = 0; mf < 4; ++mf)
            afr[mf] = frag(cur, wr * 128 + mf * 16 + r15, kc);
        if (rem >= 3)
            stage2(Ab, Bb, m0, n0, (t + 3) * 32, nxt, wave, lane);
        __builtin_amdgcn_sched_barrier(0);
        __builtin_amdgcn_s_barrier();
        __builtin_amdgcn_sched_barrier(0);
        __builtin_amdgcn_s_setprio(1);
        #pragma unroll
        for (int mf = 0; mf < 4; ++mf)
            #pragma unroll
            for (int nf = 0; nf < 4; ++nf)
                acc[mf][nf] = __builtin_amdgcn_mfma_f32_16x16x32_bf16(afr[mf], bfr[nf], acc[mf][nf], 0, 0, 0);
        __builtin_amdgcn_s_setprio(0);
        __builtin_amdgcn_sched_barrier(0);
        __builtin_amdgcn_s_barrier();
        __builtin_amdgcn_sched_barrier(0);

        // ---- P1: read A-frags 4-7; counted vmcnt at close ----
        s16x8 afr2[4];
        #pragma unroll
        for (int mf = 0; mf < 4; ++mf)
            afr2[mf] = frag(cur, wr * 128 + (mf + 4) * 16 + r15, kc);
        __builtin_amdgcn_sched_barrier(0);
        __builtin_amdgcn_s_barrier();
        __builtin_amdgcn_sched_barrier(0);
        __builtin_amdgcn_s_setprio(1);
        #pragma unroll
        for (int mf = 0; mf < 4; ++mf)
            #pragma unroll
            for (int nf = 0; nf < 4; ++nf)
                acc[mf + 4][nf] = __builtin_amdgcn_mfma_f32_16x16x32_bf16(afr2[mf], bfr[nf], acc[mf + 4][nf], 0, 0, 0);
        __builtin_amdgcn_s_setprio(0);
        __builtin_amdgcn_sched_barrier(0);
        if (rem >= 3)      { asm volatile("s_waitcnt vmcnt(8)" ::: "memory"); }
        else if (rem == 2) { asm volatile("s_waitcnt vmcnt(4)" ::: "memory"); }
        else if (rem == 1) { asm volatile("s_waitcnt vmcnt(0)" ::: "memory"); }
        __builtin_amdgcn_s_barrier();
        __builtin_amdgcn_sched_barrier(0);
    }
}

// ---------------- data GEMM (batched; TOEP variant) ----------------
template<int OUTM, bool TOEP>      // OUTM: 0 = f32 out, 1 = bf16 out
__global__ __launch_bounds__(512, 2) void gemm_big(
    const unsigned short* __restrict__ A, size_t sA,
    const unsigned short* __restrict__ B, size_t sB,
    float* __restrict__ outF, unsigned short* __restrict__ outH, size_t sO,
    const int* __restrict__ idxp, const float* __restrict__ ks)
{
    __shared__ __align__(16) unsigned short lds[4 * 16384];

    const int tid  = threadIdx.x;
    const int lane = tid & 63, wave = tid >> 6;
    const int wr = wave >> 2, wc = wave & 3;        // 2 x 4 wave grid
    const int bz = blockIdx.z;
    int bx = blockIdx.x, by = blockIdx.y;
    if constexpr (TOEP) { int tswap = bx; bx = by; by = tswap; }  // causal balance
    const int m0 = by * 256, n0 = bx * 256;
    const int r15 = lane & 15, kc = lane >> 4;

    const unsigned short* Ab = A + (size_t)bz * sA;
    const unsigned short* Bb = B + (size_t)bz * sB;
    const int NKB = TOEP ? 8 * (bx + 1) : 64;

    f32x4 acc[8][4];
    const f32x4 zf = {0.f, 0.f, 0.f, 0.f};
    #pragma unroll
    for (int i = 0; i < 8; ++i)
        #pragma unroll
        for (int j = 0; j < 4; ++j) acc[i][j] = zf;

    kloop(Ab, Bb, m0, n0, NKB, lds, wave, lane, wr, wc, acc);

    float csc[4];
    if constexpr (TOEP) {
        #pragma unroll
        for (int nf = 0; nf < 4; ++nf) {
            int gcol = n0 + wc * 64 + nf * 16 + r15;
            csc[nf] = ks[idxp[bz * L + gcol]];
        }
    }
    #pragma unroll
    for (int mf = 0; mf < 8; ++mf) {
        #pragma unroll
        for (int r = 0; r < 4; ++r) {
            int grow = m0 + wr * 128 + mf * 16 + kc * 4 + r;
            #pragma unroll
            for (int nf = 0; nf < 4; ++nf) {
                float v = acc[mf][nf][r];
                if constexpr (TOEP) v *= csc[nf];
                int gcol = n0 + wc * 64 + nf * 16 + r15;
                size_t o = (size_t)bz * sO + (size_t)grow * 2048 + gcol;
                if constexpr (OUTM == 0) outF[o] = v;
                else                     outH[o] = f2bf(v);
            }
        }
    }
}

// ---------------- precompute GEMMs: up to 3 independent [V,V] per launch ----------------
struct PDesc { const unsigned short* A; const unsigned short* B; float* oF; unsigned short* oH; };

__global__ __launch_bounds__(512, 2) void gemm_pre_big(PDesc d0, PDesc d1, PDesc d2) {
    PDesc d = (blockIdx.z == 0) ? d0 : (blockIdx.z == 1) ? d1 : d2;
    __shared__ __align__(16) unsigned short lds[4 * 16384];

    const int tid  = threadIdx.x;
    const int lane = tid & 63, wave = tid >> 6;
    const int wr = wave >> 2, wc = wave & 3;
    const int m0 = blockIdx.y * 256, n0 = blockIdx.x * 256;
    const int r15 = lane & 15, kc = lane >> 4;

    f32x4 acc[8][4];
    const f32x4 zf = {0.f, 0.f, 0.f, 0.f};
    #pragma unroll
    for (int i = 0; i < 8; ++i)
        #pragma unroll
        for (int j = 0; j < 4; ++j) acc[i][j] = zf;

    kloop(d.A, d.B, m0, n0, 64, lds, wave, lane, wr, wc, acc);

    const bool isF = (d.oF != nullptr);
    #pragma unroll
    for (int mf = 0; mf < 8; ++mf) {
        #pragma unroll
        for (int r = 0; r < 4; ++r) {
            int grow = m0 + wr * 128 + mf * 16 + kc * 4 + r;
            #pragma unroll
            for (int nf = 0; nf < 4; ++nf) {
                float v = acc[mf][nf][r];
                int gcol = n0 + wc * 64 + nf * 16 + r15;
                size_t o = (size_t)grow * 2048 + gcol;
                if (isF) d.oF[o] = v;
                else     d.oH[o] = f2bf(v);
            }
        }
    }
}

// ---------------- prep kernels ----------------

__global__ __launch_bounds__(256) void colsum_atomic(const float* __restrict__ W,
                                                     float* __restrict__ out) {
    int r0 = blockIdx.x * 8;
    int c = threadIdx.x;
    float s[8];
    #pragma unroll
    for (int i = 0; i < 8; ++i) s[i] = 0.f;
    for (int r = 0; r < 8; ++r) {
        const float* row = W + (size_t)(r0 + r) * V;
        #pragma unroll
        for (int i = 0; i < 8; ++i) s[i] += row[c + i * 256];
    }
    #pragma unroll
    for (int i = 0; i < 8; ++i) atomicAdd(&out[c + i * 256], s[i]);
}

__global__ void init_kernel(float* __restrict__ ks0, float* __restrict__ ks1) {
    int i = blockIdx.x * 256 + threadIdx.x;
    if (i < 2048) { ks0[i] = 0.f; ks1[i] = 0.f; }
}

// materialize Toeplitz: TB[n][k] = (k<=n) ? v1[n-k] : 0 (bf16); grid 2048 x 256 thr
__global__ __launch_bounds__(256) void tb_fill(const float* __restrict__ v1,
                                               unsigned short* __restrict__ TBh) {
    int n = blockIdx.x;
    int c0 = threadIdx.x * 8;
    s16x8 hv;
    #pragma unroll
    for (int i = 0; i < 8; ++i) {
        int k = c0 + i;
        float f = (k <= n) ? v1[n - k] : 0.f;
        hv[i] = (short)f2bf(f);
    }
    *(s16x8*)&TBh[(size_t)n * 2048 + c0] = hv;
}

struct TDesc { const float* A; unsigned short* Th; };

// 5 fused transpose+cast: Th[i][j] = bf16(A[j][i]); grid (64,64,5), block (32,8)
__global__ void transpose_cast_multi(TDesc d0, TDesc d1, TDesc d2, TDesc d3, TDesc d4) {
    TDesc d;
    switch (blockIdx.z) {
        case 0: d = d0; break;
        case 1: d = d1; break;
        case 2: d = d2; break;
        case 3: d = d3; break;
        default: d = d4; break;
    }
    __shared__ float tile[32][33];
    int x = blockIdx.x * 32 + threadIdx.x;
    int y0 = blockIdx.y * 32;
    for (int r = threadIdx.y; r < 32; r += 8)
        tile[r][threadIdx.x] = d.A[(size_t)(y0 + r) * V + x];
    __syncthreads();
    int xo = blockIdx.y * 32 + threadIdx.x;
    int yo0 = blockIdx.x * 32;
    for (int r = threadIdx.y; r < 32; r += 8)
        d.Th[(size_t)(yo0 + r) * V + xo] = f2bf(tile[threadIdx.x][r]);
}

// plain cast f32 -> bf16
__global__ __launch_bounds__(256) void cast_kernel(const float* __restrict__ A,
                                                   unsigned short* __restrict__ H,
                                                   int n4) {
    int i = blockIdx.x * 256 + threadIdx.x;
    if (i >= n4) return;
    float4 f = ((const float4*)A)[i];
    ushort4 h;
    h.x = f2bf(f.x); h.y = f2bf(f.y); h.z = f2bf(f.z); h.w = f2bf(f.w);
    ((ushort4*)H)[i] = h;
}

// ---------------- scatter kernels (bf16 out) ----------------

__global__ __launch_bounds__(256) void scatterA_kernel(const int* __restrict__ idx,
                                                       const float* __restrict__ G0,
                                                       const float* __restrict__ ks0,
                                                       const float* __restrict__ v0,
                                                       unsigned short* __restrict__ Th) {
    __shared__ float buck[8 * 2048];
    int tid = threadIdx.x;
    const float4 z4 = make_float4(0.f, 0.f, 0.f, 0.f);
    for (int i = tid; i < 8 * 2048 / 4; i += 256) ((float4*)buck)[i] = z4;
    __syncthreads();

    int b = blockIdx.y, q0 = blockIdx.x * 8;
    int qr = tid >> 5, kl = tid & 31;
    int q = q0 + qr;
    int iq = idx[b * L + q];
    float kq = ks0[iq];
    const float* Grow = G0 + (size_t)iq * V;
    for (int k = kl; k <= q; k += 32) {
        int ik = idx[b * L + k];
        float val = Grow[ik] + kq * v0[q - k];
        atomicAdd(&buck[qr * 2048 + ik], val);
    }
    __syncthreads();
    size_t base = ((size_t)b * L + q0) * V;
    for (int i = tid; i < 8 * 2048; i += 256)
        Th[base + i] = f2bf(buck[i]);
}

// T2 is bf16 here
__global__ __launch_bounds__(256) void scatterC_kernel(const int* __restrict__ idx,
                                                       const unsigned short* __restrict__ T2h,
                                                       unsigned short* __restrict__ Th) {
    __shared__ float buck[8 * 2048];
    int tid = threadIdx.x;
    const float4 z4 = make_float4(0.f, 0.f, 0.f, 0.f);
    for (int i = tid; i < 8 * 2048 / 4; i += 256) ((float4*)buck)[i] = z4;
    __syncthreads();

    int b = blockIdx.y, q0 = blockIdx.x * 8;
    int qr = tid >> 5, kl = tid & 31;
    int q = q0 + qr;
    int iq = idx[b * L + q];
    const unsigned short* Trow = T2h + ((size_t)b * V + iq) * L;
    for (int k = kl; k <= q; k += 32) {
        int ik = idx[b * L + k];
        atomicAdd(&buck[qr * 2048 + ik], bf2f(Trow[k]));
    }
    __syncthreads();
    size_t base = ((size_t)b * L + q0) * V;
    for (int i = tid; i < 8 * 2048; i += 256)
        Th[base + i] = f2bf(buck[i]);
}

// ---------------- launcher ----------------

extern "C" void kernel_launch(void* const* d_in, const int* in_sizes, int n_in,
                              void* d_out, int out_size, void* d_ws, size_t ws_size,
                              hipStream_t stream) {
    (void)in_sizes; (void)n_in; (void)out_size; (void)ws_size;
    const int*   idx = (const int*)d_in[0];
    const float* Wq0 = (const float*)d_in[1];
    const float* Wk0 = (const float*)d_in[2];
    const float* Wv0 = (const float*)d_in[3];
    const float* Wk1 = (const float*)d_in[4];
    const float* Wv1 = (const float*)d_in[5];
    const float* Wq2 = (const float*)d_in[6];
    const float* Wk2 = (const float*)d_in[7];
    const float* Wv2 = (const float*)d_in[8];
    const float* v0  = (const float*)d_in[9];
    const float* v1  = (const float*)d_in[10];
    float* out = (float*)d_out;

    char* W = (char*)d_ws;
    const size_t MiB = 1024 * 1024;

    // [0, 64 MiB): PPT (8 MiB) early -> TAh (32 MiB) -> T2h (32 MiB)
    unsigned short* PPT = (unsigned short*)W;
    unsigned short* TAh = (unsigned short*)W;
    unsigned short* T2h = (unsigned short*)W;
    // [64, 96 MiB): Y1 (Wv0T) + Y2 (Wv1 bf16) early -> Uh -> TCh
    unsigned short* Y1 = (unsigned short*)(W + 64 * MiB);
    unsigned short* Y2 = (unsigned short*)(W + 72 * MiB);
    unsigned short* Uh  = (unsigned short*)(W + 64 * MiB);
    unsigned short* TCh = Uh;
    // [96, 112 MiB): G0 f32
    float* Gf = (float*)(W + 96 * MiB);
    // [112, 120): Y4 = M bf16
    unsigned short* Y4 = (unsigned short*)(W + 112 * MiB);
    // [128+): X slots, 8 MiB each (bf16 [V,V])
    unsigned short* X1 = (unsigned short*)(W + 128 * MiB);  // Wq0T, then R bf16
    unsigned short* X2 = (unsigned short*)(W + 136 * MiB);  // Wk0T, then Wv2 bf16
    unsigned short* X3 = (unsigned short*)(W + 144 * MiB);  // Wq2T, then TBh
    unsigned short* X4 = (unsigned short*)(W + 152 * MiB);  // Wk2T
    unsigned short* TBh = X3;
    float* ks0 = (float*)(W + 192 * MiB);
    float* ks1 = (float*)(W + 192 * MiB + 16 * 1024);

    dim3 blk(256);

    // prep: transposes/casts, column sums
    {
        TDesc t0{Wq0, X1}, t1{Wk0, X2}, t2{Wq2, X3}, t3{Wk2, X4}, t4{Wv0, Y1};
        transpose_cast_multi<<<dim3(64, 64, 5), dim3(32, 8), 0, stream>>>(t0, t1, t2, t3, t4);
    }
    cast_kernel<<<dim3((int)(VV / 4 / 256)), blk, 0, stream>>>(Wv1, Y2, (int)(VV / 4));
    init_kernel<<<dim3(8), blk, 0, stream>>>(ks0, ks1);
    colsum_atomic<<<dim3(256), blk, 0, stream>>>(Wk0, ks0);
    colsum_atomic<<<dim3(256), blk, 0, stream>>>(Wk1, ks1);

    // fused precomputes: G0 = Wq0^T Wk0 (f32), M = Wq2^T Wk2 (bf16), PPT (bf16)
    {
        PDesc dG{X1, X2, Gf, nullptr};
        PDesc dM{X3, X4, nullptr, Y4};
        PDesc dP{Y1, Y2, nullptr, PPT};
        gemm_pre_big<<<dim3(8, 8, 3), dim3(512), 0, stream>>>(dG, dM, dP);
    }
    // TB materialization (X3's Wq2T dead after pre)
    tb_fill<<<dim3(2048), blk, 0, stream>>>(v1, TBh);
    // R = M . PPT -> X1 bf16 (X1's Wq0T dead after pre)
    {
        PDesc dR{Y4, PPT, nullptr, X1};
        gemm_pre_big<<<dim3(8, 8, 1), dim3(512), 0, stream>>>(dR, dR, dR);
    }

    // scatter A -> TAh (overwrites PPT region; PPT dead after R)
    scatterA_kernel<<<dim3(L / 8, NB), blk, 0, stream>>>(idx, Gf, ks0, v0, TAh);

    // U[b] = R . TA[b]^T -> bf16 Uh (Y1/Y2 dead after pre)
    gemm_big<1, false><<<dim3(8, 8, NB), dim3(512), 0, stream>>>(
        X1, 0, TAh, LV, nullptr, Uh, LV, nullptr, nullptr);

    // T2[b][v,q] = ks1[iq_q] * sum_{k<=q} v1[q-k] * U[b][v,k] -> bf16 T2h (TAh dead)
    gemm_big<1, true><<<dim3(8, 8, NB), dim3(512), 0, stream>>>(
        Uh, LV, TBh, 0, nullptr, T2h, LV, idx, ks1);

    // scatter C -> TCh (overwrites Uh; Uh dead after TOEP)
    scatterC_kernel<<<dim3(L / 8, NB), blk, 0, stream>>>(idx, T2h, TCh);

    // Wv2 -> bf16 X2 (Wk0T dead after pre)
    cast_kernel<<<dim3((int)(VV / 4 / 256)), blk, 0, stream>>>(Wv2, X2, (int)(VV / 4));

    // logits = TC . Wv2rows -> d_out (M = 8192)
    gemm_big<0, false><<<dim3(8, 32, 1), dim3(512), 0, stream>>>(
        TCh, 0, X2, 0, out, nullptr, 0, nullptr, nullptr);
}

// Round 9
// 490.980 us; speedup vs baseline: 12.5107x; 1.0918x over previous
//
#include <hip/hip_runtime.h>

typedef float f32x4 __attribute__((ext_vector_type(4)));
typedef short s16x8 __attribute__((ext_vector_type(8)));

constexpr int L = 2048;
constexpr int V = 2048;
constexpr int NB = 4;
constexpr size_t VV  = (size_t)V * V;      // 4194304
constexpr size_t BLV = (size_t)NB * L * V; // 16777216
constexpr size_t LV  = (size_t)L * V;      // 4194304

// ---------- bf16 helpers (bit-level, RNE) ----------
__device__ __forceinline__ unsigned short f2bf(float f) {
    unsigned u = __float_as_uint(f);
    u = (u + 0x7FFFu + ((u >> 16) & 1u)) >> 16;
    return (unsigned short)u;
}
__device__ __forceinline__ float bf2f(unsigned short s) {
    return __uint_as_float(((unsigned)s) << 16);
}

// ---------- async global->LDS 16B ----------
__device__ __forceinline__ void gload16(const unsigned short* g, unsigned short* l) {
    auto gp = (const __attribute__((address_space(1))) unsigned int*)g;
    auto lp = (__attribute__((address_space(3))) unsigned int*)l;
    __builtin_amdgcn_global_load_lds(gp, lp, 16, 0, 0);
}

// ================= 256x256 bf16 pipelined GEMM machinery =================

__device__ __forceinline__ void stage2(const unsigned short* A, const unsigned short* B,
                                       int m0, int n0, int k0, unsigned short* buf,
                                       int wave, int lane) {
    int rl = lane >> 2, csl = lane & 3;
    #pragma unroll
    for (int h = 0; h < 2; ++h) {
        int rr = wave * 32 + h * 16;               // LDS row base (wave-uniform)
        int row = rr + rl;
        int ch = csl ^ ((row >> 1) & 3);
        size_t ga = (size_t)row * 2048 + k0 + ch * 8;
        gload16(A + (size_t)m0 * 2048 + ga, buf + rr * 32);
        gload16(B + (size_t)n0 * 2048 + ga, buf + 8192 + rr * 32);
    }
}

__device__ __forceinline__ s16x8 frag(const unsigned short* arr, int row, int kc) {
    int cs = kc ^ ((row >> 1) & 3);
    return *(const s16x8*)&arr[row * 32 + cs * 8];
}

__device__ __forceinline__ void kloop(const unsigned short* Ab, const unsigned short* Bb,
                                      int m0, int n0, int NKB, unsigned short* lds,
                                      int wave, int lane, int wr, int wc,
                                      f32x4 (&acc)[8][4]) {
    const int r15 = lane & 15, kc = lane >> 4;

    // prologue: stage blocks 0..2, wait block 0 (vmcnt 8 = 2 tiles in flight)
    stage2(Ab, Bb, m0, n0, 0,  lds,         wave, lane);
    stage2(Ab, Bb, m0, n0, 32, lds + 16384, wave, lane);
    stage2(Ab, Bb, m0, n0, 64, lds + 32768, wave, lane);
    asm volatile("s_waitcnt vmcnt(8)" ::: "memory");
    __builtin_amdgcn_sched_barrier(0);
    __builtin_amdgcn_s_barrier();
    __builtin_amdgcn_sched_barrier(0);

    for (int t = 0; t < NKB; ++t) {
        const unsigned short* cur = lds + (t & 3) * 16384;
        unsigned short* nxt = lds + ((t + 3) & 3) * 16384;
        const int rem = NKB - 1 - t;

        // ---- P0: read B-frags + A-frags 0-3; issue prefetch ----
        s16x8 bfr[4], afr[4];
        #pragma unroll
        for (int nf = 0; nf < 4; ++nf)
            bfr[nf] = frag(cur + 8192, wc * 64 + nf * 16 + r15, kc);
        #pragma unroll
        for (int mf = 0; mf < 4; ++mf)
            afr[mf] = frag(cur, wr * 128 + mf * 16 + r15, kc);
        if (rem >= 3)
            stage2(Ab, Bb, m0, n0, (t + 3) * 32, nxt, wave, lane);
        __builtin_amdgcn_sched_barrier(0);
        __builtin_amdgcn_s_barrier();
        __builtin_amdgcn_sched_barrier(0);
        __builtin_amdgcn_s_setprio(1);
        #pragma unroll
        for (int mf = 0; mf < 4; ++mf)
            #pragma unroll
            for (int nf = 0; nf < 4; ++nf)
                acc[mf][nf] = __builtin_amdgcn_mfma_f32_16x16x32_bf16(afr[mf], bfr[nf], acc[mf][nf], 0, 0, 0);
        __builtin_amdgcn_s_setprio(0);
        __builtin_amdgcn_sched_barrier(0);
        __builtin_amdgcn_s_barrier();
        __builtin_amdgcn_sched_barrier(0);

        // ---- P1: read A-frags 4-7; counted vmcnt at close ----
        s16x8 afr2[4];
        #pragma unroll
        for (int mf = 0; mf < 4; ++mf)
            afr2[mf] = frag(cur, wr * 128 + (mf + 4) * 16 + r15, kc);
        __builtin_amdgcn_sched_barrier(0);
        __builtin_amdgcn_s_barrier();
        __builtin_amdgcn_sched_barrier(0);
        __builtin_amdgcn_s_setprio(1);
        #pragma unroll
        for (int mf = 0; mf < 4; ++mf)
            #pragma unroll
            for (int nf = 0; nf < 4; ++nf)
                acc[mf + 4][nf] = __builtin_amdgcn_mfma_f32_16x16x32_bf16(afr2[mf], bfr[nf], acc[mf + 4][nf], 0, 0, 0);
        __builtin_amdgcn_s_setprio(0);
        __builtin_amdgcn_sched_barrier(0);
        if (rem >= 3)      { asm volatile("s_waitcnt vmcnt(8)" ::: "memory"); }
        else if (rem == 2) { asm volatile("s_waitcnt vmcnt(4)" ::: "memory"); }
        else if (rem == 1) { asm volatile("s_waitcnt vmcnt(0)" ::: "memory"); }
        __builtin_amdgcn_s_barrier();
        __builtin_amdgcn_sched_barrier(0);
    }
}

// ---------------- data GEMM (batched; TOEP variant) ----------------
template<int OUTM, bool TOEP>      // OUTM: 0 = f32 out, 1 = bf16 out
__global__ __launch_bounds__(512, 2) void gemm_big(
    const unsigned short* __restrict__ A, size_t sA,
    const unsigned short* __restrict__ B, size_t sB,
    float* __restrict__ outF, unsigned short* __restrict__ outH, size_t sO,
    const int* __restrict__ idxp, const float* __restrict__ ks)
{
    __shared__ __align__(16) unsigned short lds[4 * 16384];

    const int tid  = threadIdx.x;
    const int lane = tid & 63, wave = tid >> 6;
    const int wr = wave >> 2, wc = wave & 3;        // 2 x 4 wave grid
    const int bz = blockIdx.z;
    int bx = blockIdx.x, by = blockIdx.y;
    if constexpr (TOEP) { int tswap = bx; bx = by; by = tswap; }  // causal balance
    const int m0 = by * 256, n0 = bx * 256;
    const int r15 = lane & 15, kc = lane >> 4;

    const unsigned short* Ab = A + (size_t)bz * sA;
    const unsigned short* Bb = B + (size_t)bz * sB;
    const int NKB = TOEP ? 8 * (bx + 1) : 64;

    f32x4 acc[8][4];
    const f32x4 zf = {0.f, 0.f, 0.f, 0.f};
    #pragma unroll
    for (int i = 0; i < 8; ++i)
        #pragma unroll
        for (int j = 0; j < 4; ++j) acc[i][j] = zf;

    kloop(Ab, Bb, m0, n0, NKB, lds, wave, lane, wr, wc, acc);

    float csc[4];
    if constexpr (TOEP) {
        #pragma unroll
        for (int nf = 0; nf < 4; ++nf) {
            int gcol = n0 + wc * 64 + nf * 16 + r15;
            csc[nf] = ks[idxp[bz * L + gcol]];
        }
    }
    #pragma unroll
    for (int mf = 0; mf < 8; ++mf) {
        #pragma unroll
        for (int r = 0; r < 4; ++r) {
            int grow = m0 + wr * 128 + mf * 16 + kc * 4 + r;
            #pragma unroll
            for (int nf = 0; nf < 4; ++nf) {
                float v = acc[mf][nf][r];
                if constexpr (TOEP) v *= csc[nf];
                int gcol = n0 + wc * 64 + nf * 16 + r15;
                size_t o = (size_t)bz * sO + (size_t)grow * 2048 + gcol;
                if constexpr (OUTM == 0) outF[o] = v;
                else                     outH[o] = f2bf(v);
            }
        }
    }
}

// ---------------- precompute GEMMs: up to 3 independent [V,V] per launch ----------------
struct PDesc { const unsigned short* A; const unsigned short* B; float* oF; unsigned short* oH; };

__global__ __launch_bounds__(512, 2) void gemm_pre_big(PDesc d0, PDesc d1, PDesc d2) {
    PDesc d = (blockIdx.z == 0) ? d0 : (blockIdx.z == 1) ? d1 : d2;
    __shared__ __align__(16) unsigned short lds[4 * 16384];

    const int tid  = threadIdx.x;
    const int lane = tid & 63, wave = tid >> 6;
    const int wr = wave >> 2, wc = wave & 3;
    const int m0 = blockIdx.y * 256, n0 = blockIdx.x * 256;
    const int r15 = lane & 15, kc = lane >> 4;

    f32x4 acc[8][4];
    const f32x4 zf = {0.f, 0.f, 0.f, 0.f};
    #pragma unroll
    for (int i = 0; i < 8; ++i)
        #pragma unroll
        for (int j = 0; j < 4; ++j) acc[i][j] = zf;

    kloop(d.A, d.B, m0, n0, 64, lds, wave, lane, wr, wc, acc);

    const bool isF = (d.oF != nullptr);
    #pragma unroll
    for (int mf = 0; mf < 8; ++mf) {
        #pragma unroll
        for (int r = 0; r < 4; ++r) {
            int grow = m0 + wr * 128 + mf * 16 + kc * 4 + r;
            #pragma unroll
            for (int nf = 0; nf < 4; ++nf) {
                float v = acc[mf][nf][r];
                int gcol = n0 + wc * 64 + nf * 16 + r15;
                size_t o = (size_t)grow * 2048 + gcol;
                if (isF) d.oF[o] = v;
                else     d.oH[o] = f2bf(v);
            }
        }
    }
}

// ---- split-K precompute: z-th K=512 chunk of OUT = A . B^Trows -> f32 partial ----
__global__ __launch_bounds__(512, 2) void gemm_preK(const unsigned short* __restrict__ A,
                                                    const unsigned short* __restrict__ B,
                                                    float* __restrict__ outP) {
    __shared__ __align__(16) unsigned short lds[4 * 16384];

    const int tid  = threadIdx.x;
    const int lane = tid & 63, wave = tid >> 6;
    const int wr = wave >> 2, wc = wave & 3;
    const int m0 = blockIdx.y * 256, n0 = blockIdx.x * 256;
    const int r15 = lane & 15, kc = lane >> 4;
    const int z = blockIdx.z;

    const unsigned short* Ab = A + z * 512;
    const unsigned short* Bb = B + z * 512;
    float* outF = outP + (size_t)z * VV;

    f32x4 acc[8][4];
    const f32x4 zf = {0.f, 0.f, 0.f, 0.f};
    #pragma unroll
    for (int i = 0; i < 8; ++i)
        #pragma unroll
        for (int j = 0; j < 4; ++j) acc[i][j] = zf;

    kloop(Ab, Bb, m0, n0, 16, lds, wave, lane, wr, wc, acc);

    #pragma unroll
    for (int mf = 0; mf < 8; ++mf) {
        #pragma unroll
        for (int r = 0; r < 4; ++r) {
            int grow = m0 + wr * 128 + mf * 16 + kc * 4 + r;
            #pragma unroll
            for (int nf = 0; nf < 4; ++nf) {
                int gcol = n0 + wc * 64 + nf * 16 + r15;
                outF[(size_t)grow * 2048 + gcol] = acc[mf][nf][r];
            }
        }
    }
}

// reduce 4 f32 partials -> bf16
__global__ __launch_bounds__(256) void reduce4_cast(const float* __restrict__ P,
                                                    unsigned short* __restrict__ H) {
    int i = blockIdx.x * 256 + threadIdx.x;          // float4 index, < VV/4
    const float4* p0 = (const float4*)P;
    const float4* p1 = (const float4*)(P + VV);
    const float4* p2 = (const float4*)(P + 2 * VV);
    const float4* p3 = (const float4*)(P + 3 * VV);
    float4 a = p0[i], b = p1[i], c = p2[i], d = p3[i];
    ushort4 h;
    h.x = f2bf(a.x + b.x + c.x + d.x);
    h.y = f2bf(a.y + b.y + c.y + d.y);
    h.z = f2bf(a.z + b.z + c.z + d.z);
    h.w = f2bf(a.w + b.w + c.w + d.w);
    ((ushort4*)H)[i] = h;
}

// ---------------- prep kernels ----------------

__global__ __launch_bounds__(256) void colsum_atomic(const float* __restrict__ W,
                                                     float* __restrict__ out) {
    int r0 = blockIdx.x * 8;
    int c = threadIdx.x;
    float s[8];
    #pragma unroll
    for (int i = 0; i < 8; ++i) s[i] = 0.f;
    for (int r = 0; r < 8; ++r) {
        const float* row = W + (size_t)(r0 + r) * V;
        #pragma unroll
        for (int i = 0; i < 8; ++i) s[i] += row[c + i * 256];
    }
    #pragma unroll
    for (int i = 0; i < 8; ++i) atomicAdd(&out[c + i * 256], s[i]);
}

__global__ void init_kernel(float* __restrict__ ks0, float* __restrict__ ks1) {
    int i = blockIdx.x * 256 + threadIdx.x;
    if (i < 2048) { ks0[i] = 0.f; ks1[i] = 0.f; }
}

// materialize Toeplitz: TB[n][k] = (k<=n) ? v1[n-k] : 0 (bf16); grid 2048 x 256 thr
__global__ __launch_bounds__(256) void tb_fill(const float* __restrict__ v1,
                                               unsigned short* __restrict__ TBh) {
    int n = blockIdx.x;
    int c0 = threadIdx.x * 8;
    s16x8 hv;
    #pragma unroll
    for (int i = 0; i < 8; ++i) {
        int k = c0 + i;
        float f = (k <= n) ? v1[n - k] : 0.f;
        hv[i] = (short)f2bf(f);
    }
    *(s16x8*)&TBh[(size_t)n * 2048 + c0] = hv;
}

struct TDesc { const float* A; unsigned short* Th; };

// 5 fused transpose+cast: Th[i][j] = bf16(A[j][i]); grid (64,64,5), block (32,8)
__global__ void transpose_cast_multi(TDesc d0, TDesc d1, TDesc d2, TDesc d3, TDesc d4) {
    TDesc d;
    switch (blockIdx.z) {
        case 0: d = d0; break;
        case 1: d = d1; break;
        case 2: d = d2; break;
        case 3: d = d3; break;
        default: d = d4; break;
    }
    __shared__ float tile[32][33];
    int x = blockIdx.x * 32 + threadIdx.x;
    int y0 = blockIdx.y * 32;
    for (int r = threadIdx.y; r < 32; r += 8)
        tile[r][threadIdx.x] = d.A[(size_t)(y0 + r) * V + x];
    __syncthreads();
    int xo = blockIdx.y * 32 + threadIdx.x;
    int yo0 = blockIdx.x * 32;
    for (int r = threadIdx.y; r < 32; r += 8)
        d.Th[(size_t)(yo0 + r) * V + xo] = f2bf(tile[threadIdx.x][r]);
}

// plain cast f32 -> bf16
__global__ __launch_bounds__(256) void cast_kernel(const float* __restrict__ A,
                                                   unsigned short* __restrict__ H,
                                                   int n4) {
    int i = blockIdx.x * 256 + threadIdx.x;
    if (i >= n4) return;
    float4 f = ((const float4*)A)[i];
    ushort4 h;
    h.x = f2bf(f.x); h.y = f2bf(f.y); h.z = f2bf(f.z); h.w = f2bf(f.w);
    ((ushort4*)H)[i] = h;
}

// ---------------- scatter kernels (4 q-rows/block, 64 lanes/row, 4x unrolled) ----------------

__global__ __launch_bounds__(256) void scatterA_kernel(const int* __restrict__ idx,
                                                       const float* __restrict__ G0,
                                                       const float* __restrict__ ks0,
                                                       const float* __restrict__ v0,
                                                       unsigned short* __restrict__ Th) {
    __shared__ float buck[4 * 2048];
    int tid = threadIdx.x;
    const float4 z4 = make_float4(0.f, 0.f, 0.f, 0.f);
    #pragma unroll
    for (int i = 0; i < 8; ++i) ((float4*)buck)[tid + i * 256] = z4;
    __syncthreads();

    int b = blockIdx.y, q0 = blockIdx.x * 4;
    int qr = tid >> 6, lane = tid & 63;
    int q = q0 + qr;
    const int* idxb = idx + b * L;
    int iq = idxb[q];
    float kq = ks0[iq];
    const float* Grow = G0 + (size_t)iq * V;
    float* brow = buck + qr * 2048;

    int k = lane;
    for (; k + 192 <= q; k += 256) {
        int i0 = idxb[k], i1 = idxb[k + 64], i2 = idxb[k + 128], i3 = idxb[k + 192];
        float g0 = Grow[i0], g1 = Grow[i1], g2 = Grow[i2], g3 = Grow[i3];
        float w0 = v0[q - k], w1 = v0[q - k - 64], w2 = v0[q - k - 128], w3 = v0[q - k - 192];
        atomicAdd(&brow[i0], g0 + kq * w0);
        atomicAdd(&brow[i1], g1 + kq * w1);
        atomicAdd(&brow[i2], g2 + kq * w2);
        atomicAdd(&brow[i3], g3 + kq * w3);
    }
    for (; k <= q; k += 64) {
        int ik = idxb[k];
        atomicAdd(&brow[ik], Grow[ik] + kq * v0[q - k]);
    }
    __syncthreads();
    size_t base = ((size_t)b * L + q0) * V;
    #pragma unroll
    for (int it = 0; it < 4; ++it) {
        int i = tid + it * 256;                      // s16x8 index < 1024
        s16x8 hv;
        #pragma unroll
        for (int j = 0; j < 8; ++j) hv[j] = (short)f2bf(buck[i * 8 + j]);
        *(s16x8*)&Th[base + (size_t)i * 8] = hv;
    }
}

// T2 is bf16; row reads coalesced
__global__ __launch_bounds__(256) void scatterC_kernel(const int* __restrict__ idx,
                                                       const unsigned short* __restrict__ T2h,
                                                       unsigned short* __restrict__ Th) {
    __shared__ float buck[4 * 2048];
    int tid = threadIdx.x;
    const float4 z4 = make_float4(0.f, 0.f, 0.f, 0.f);
    #pragma unroll
    for (int i = 0; i < 8; ++i) ((float4*)buck)[tid + i * 256] = z4;
    __syncthreads();

    int b = blockIdx.y, q0 = blockIdx.x * 4;
    int qr = tid >> 6, lane = tid & 63;
    int q = q0 + qr;
    const int* idxb = idx + b * L;
    int iq = idxb[q];
    const unsigned short* Trow = T2h + ((size_t)b * V + iq) * L;
    float* brow = buck + qr * 2048;

    int k = lane;
    for (; k + 192 <= q; k += 256) {
        int i0 = idxb[k], i1 = idxb[k + 64], i2 = idxb[k + 128], i3 = idxb[k + 192];
        float t0 = bf2f(Trow[k]), t1 = bf2f(Trow[k + 64]);
        float t2 = bf2f(Trow[k + 128]), t3 = bf2f(Trow[k + 192]);
        atomicAdd(&brow[i0], t0);
        atomicAdd(&brow[i1], t1);
        atomicAdd(&brow[i2], t2);
        atomicAdd(&brow[i3], t3);
    }
    for (; k <= q; k += 64)
        atomicAdd(&brow[idxb[k]], bf2f(Trow[k]));
    __syncthreads();
    size_t base = ((size_t)b * L + q0) * V;
    #pragma unroll
    for (int it = 0; it < 4; ++it) {
        int i = tid + it * 256;
        s16x8 hv;
        #pragma unroll
        for (int j = 0; j < 8; ++j) hv[j] = (short)f2bf(buck[i * 8 + j]);
        *(s16x8*)&Th[base + (size_t)i * 8] = hv;
    }
}

// ---------------- launcher ----------------

extern "C" void kernel_launch(void* const* d_in, const int* in_sizes, int n_in,
                              void* d_out, int out_size, void* d_ws, size_t ws_size,
                              hipStream_t stream) {
    (void)in_sizes; (void)n_in; (void)out_size; (void)ws_size;
    const int*   idx = (const int*)d_in[0];
    const float* Wq0 = (const float*)d_in[1];
    const float* Wk0 = (const float*)d_in[2];
    const float* Wv0 = (const float*)d_in[3];
    const float* Wk1 = (const float*)d_in[4];
    const float* Wv1 = (const float*)d_in[5];
    const float* Wq2 = (const float*)d_in[6];
    const float* Wk2 = (const float*)d_in[7];
    const float* Wv2 = (const float*)d_in[8];
    const float* v0  = (const float*)d_in[9];
    const float* v1  = (const float*)d_in[10];
    float* out = (float*)d_out;

    char* W = (char*)d_ws;
    const size_t MiB = 1024 * 1024;

    // [0, 64 MiB): PPT (8 MiB) early -> TAh (32 MiB) -> T2h (32 MiB)
    unsigned short* PPT = (unsigned short*)W;
    unsigned short* TAh = (unsigned short*)W;
    unsigned short* T2h = (unsigned short*)W;
    // [8, 72 MiB): R split-K f32 partials (64 MiB, live only between pre1 and reduce)
    float* Rp = (float*)(W + 8 * MiB);
    // [64, 96 MiB): Y1 (Wv0T) + Y2 (Wv1 bf16) early -> Uh -> TCh
    unsigned short* Y1 = (unsigned short*)(W + 64 * MiB);
    unsigned short* Y2 = (unsigned short*)(W + 72 * MiB);
    unsigned short* Uh  = (unsigned short*)(W + 64 * MiB);
    unsigned short* TCh = Uh;
    // [96, 112 MiB): G0 f32
    float* Gf = (float*)(W + 96 * MiB);
    // [112, 120): Y4 = M bf16
    unsigned short* Y4 = (unsigned short*)(W + 112 * MiB);
    // [128+): X slots, 8 MiB each (bf16 [V,V])
    unsigned short* X1 = (unsigned short*)(W + 128 * MiB);  // Wq0T, then R bf16
    unsigned short* X2 = (unsigned short*)(W + 136 * MiB);  // Wk0T, then Wv2 bf16
    unsigned short* X3 = (unsigned short*)(W + 144 * MiB);  // Wq2T, then TBh
    unsigned short* X4 = (unsigned short*)(W + 152 * MiB);  // Wk2T
    unsigned short* TBh = X3;
    float* ks0 = (float*)(W + 192 * MiB);
    float* ks1 = (float*)(W + 192 * MiB + 16 * 1024);

    dim3 blk(256);

    // prep: transposes/casts, column sums
    {
        TDesc t0{Wq0, X1}, t1{Wk0, X2}, t2{Wq2, X3}, t3{Wk2, X4}, t4{Wv0, Y1};
        transpose_cast_multi<<<dim3(64, 64, 5), dim3(32, 8), 0, stream>>>(t0, t1, t2, t3, t4);
    }
    cast_kernel<<<dim3((int)(VV / 4 / 256)), blk, 0, stream>>>(Wv1, Y2, (int)(VV / 4));
    init_kernel<<<dim3(8), blk, 0, stream>>>(ks0, ks1);
    colsum_atomic<<<dim3(256), blk, 0, stream>>>(Wk0, ks0);
    colsum_atomic<<<dim3(256), blk, 0, stream>>>(Wk1, ks1);

    // fused precomputes: G0 = Wq0^T Wk0 (f32), M = Wq2^T Wk2 (bf16), PPT (bf16)
    {
        PDesc dG{X1, X2, Gf, nullptr};
        PDesc dM{X3, X4, nullptr, Y4};
        PDesc dP{Y1, Y2, nullptr, PPT};
        gemm_pre_big<<<dim3(8, 8, 3), dim3(512), 0, stream>>>(dG, dM, dP);
    }
    // TB materialization (X3's Wq2T dead after pre)
    tb_fill<<<dim3(2048), blk, 0, stream>>>(v1, TBh);
    // R = M . PPT via split-K (4 x K=512 f32 partials) -> reduce to X1 bf16
    gemm_preK<<<dim3(8, 8, 4), dim3(512), 0, stream>>>(Y4, PPT, Rp);
    reduce4_cast<<<dim3((int)(VV / 4 / 256)), blk, 0, stream>>>(Rp, X1);

    // scatter A -> TAh (overwrites PPT/Rp head; both dead)
    scatterA_kernel<<<dim3(L / 4, NB), blk, 0, stream>>>(idx, Gf, ks0, v0, TAh);

    // U[b] = R . TA[b]^T -> bf16 Uh
    gemm_big<1, false><<<dim3(8, 8, NB), dim3(512), 0, stream>>>(
        X1, 0, TAh, LV, nullptr, Uh, LV, nullptr, nullptr);

    // T2[b][v,q] = ks1[iq_q] * sum_{k<=q} v1[q-k] * U[b][v,k] -> bf16 T2h (TAh dead)
    gemm_big<1, true><<<dim3(8, 8, NB), dim3(512), 0, stream>>>(
        Uh, LV, TBh, 0, nullptr, T2h, LV, idx, ks1);

    // scatter C -> TCh (overwrites Uh; Uh dead after TOEP)
    scatterC_kernel<<<dim3(L / 4, NB), blk, 0, stream>>>(idx, T2h, TCh);

    // Wv2 -> bf16 X2 (Wk0T dead after pre)
    cast_kernel<<<dim3((int)(VV / 4 / 256)), blk, 0, stream>>>(Wv2, X2, (int)(VV / 4));

    // logits = TC . Wv2rows -> d_out (M = 8192)
    gemm_big<0, false><<<dim3(8, 32, 1), dim3(512), 0, stream>>>(
        TCh, 0, X2, 0, out, nullptr, 0, nullptr, nullptr);
}